// Round 20
// baseline (949.228 us; speedup 1.0000x reference)
//
#include <hip/hip_runtime.h>
#include <hip/hip_bf16.h>

#define TPB 256
#define TPA 512

constexpr int Bx = 8, Cc = 64, Nn = 207, Tin = 54, Kb = 8;
constexpr int LP = 52, NP = Nn * LP;     // time padded 50->52, flattened node*time positions
constexpr int NPa = 10816;               // NP rounded up to 169*64 for MFMA tiles
constexpr int L50 = 50, Tout = 48;
constexpr int Ee = 512, Pn = 12;
constexpr float EPSF = 1e-5f;
constexpr int SRDF = 516;                // padded row stride for 512-wide f32 LDS rows (2-way bank pattern)

// ---------------- workspace layout (floats) ----------------
constexpr size_t O_RESID = 0;                                   // [B][64][207][54]
constexpr size_t O_LNTM  = O_RESID + (size_t)Bx*Cc*Nn*Tin;
constexpr size_t O_LNTR  = O_LNTM  + (size_t)Bx*Cc*Nn;
constexpr size_t O_LNSM  = O_LNTR  + (size_t)Bx*Cc*Nn;
constexpr size_t O_LNSR  = O_LNSM  + (size_t)Bx*Cc*Tin;
constexpr size_t O_XCAT  = O_LNSR  + (size_t)Bx*Cc*Tin;         // scratch region: RA f32 + bf16 tail
constexpr size_t O_RB    = O_XCAT  + (size_t)Bx*192*Nn*Tin;     // f32 [B][128][NP] agg outputs
constexpr size_t O_H     = O_RB    + (size_t)Bx*128*NP;         // HT bf16 [Bx][NPa][64]
constexpr size_t O_GACC  = O_H     + (size_t)Bx*64*NP;          // [B][n][48][128] (relaid out)
constexpr size_t O_GG    = O_GACC  + (size_t)Bx*128*Nn*Tout;    // [B][64][207][48] gg (attn input; must NOT alias Y!)
constexpr size_t O_XE    = O_GG    + (size_t)Bx*64*Nn*Tout;     // Y lives here (XE no longer materialized)
constexpr size_t O_WTT   = O_XE    + (size_t)Bx*Nn*Pn*Ee;       // (unused) 128*192*3
constexpr size_t O_WTM   = O_WTT   + (size_t)128*192*3;         // ushort[3*8*12*512] W_mlp frag bf16
constexpr size_t O_BNST  = O_WTM   + (size_t)128*384*3;         // 128
constexpr size_t O_WTB   = O_BNST + 128;                        // ushort[8*18*512] time-conv bf16 frag weights
constexpr size_t O_ADJT  = O_WTB  + (size_t)128*576/2;          // ushort[3][13*7*512] adj frag bf16
constexpr size_t O_HT    = O_H;                                 // ushort[Bx][NPa][64] in dead H region
constexpr size_t O_TAIL  = O_XCAT + (size_t)Bx*128*NP;          // tail anchor (after RA region)
constexpr size_t O_WQ1B  = O_TAIL + (size_t)Bx*NPa*64/2;        // ushort[24*4*2*512]
constexpr size_t O_WV1B  = O_WQ1B + (size_t)24*64*64/2;
constexpr size_t O_WQ2B  = O_WV1B + (size_t)24*64*64/2;         // ushort[24*8*2*512]
constexpr size_t O_WV2B  = O_WQ2B + (size_t)24*128*64/2;
constexpr size_t O_RBT   = O_WV2B + (size_t)24*128*64/2;        // ushort[Bx][NPa][64] layer-1 bf16 transpose
constexpr size_t O_WQT   = O_RBT  + (size_t)Bx*NPa*64/2;        // ushort[4*2*512]
constexpr size_t O_WKT   = O_WQT  + 2048;
constexpr size_t O_WVT   = O_WKT  + 2048;
constexpr size_t O_WFCT  = O_WVT  + 2048;                       // ushort[32*16*512]
constexpr size_t O_WF1T  = O_WFCT + 131072;                     // ushort[16*16*512]
constexpr size_t O_WF2T  = O_WF1T + 65536;                      // ushort[32*8*512]

#define FMA4(acc, sA_, vB_) { (acc).x += (sA_)*(vB_).x; (acc).y += (sA_)*(vB_).y; (acc).z += (sA_)*(vB_).z; (acc).w += (sA_)*(vB_).w; }

typedef __attribute__((ext_vector_type(8))) short bf16x8;
typedef __attribute__((ext_vector_type(4))) float f32x4;

__device__ __forceinline__ float sigm(float x){ return 1.0f/(1.0f+__expf(-x)); }
__device__ __forceinline__ ushort f2bf(float x){ __hip_bfloat16 h = __float2bfloat16(x); return *(ushort*)&h; }

// xe on the fly: xe[b, n2*6144 + p2*512 + e] = gg_scramble + emb  (bit-identical to old k_xe)
__device__ __forceinline__ float xe_val(const float* __restrict__ gg, const float* __restrict__ emb,
                                        int b, int n2, int p2, int e){
  int flat = n2*6144 + p2*512 + e;
  int c = flat / 19872; int rem = flat - c*19872;
  int ns = rem / 96;    int r2  = rem - ns*96;
  int t = (r2>>3)*4 + (r2&7);
  float v = (t < Tout) ? gg[(((size_t)b*Cc + c)*Nn + ns)*(size_t)Tout + t] : 0.f;
  return v + emb[(size_t)p2*Ee + e];
}

// ---------------- residual = W_conv1 @ x + b, fused lnT stats ----------------
__global__ __launch_bounds__(TPB) void k_residual(const float* __restrict__ x, const float* __restrict__ W,
                                                  const float* __restrict__ bias, float* __restrict__ out,
                                                  float* __restrict__ lnm, float* __restrict__ lnr){
  int n = blockIdx.x, b = blockIdx.y;
  __shared__ __align__(16) float sX[Cc][Tin];
  __shared__ __align__(16) float sW[Cc*Cc];
  __shared__ __align__(16) float sO[Cc][Tin];
  int tid = threadIdx.x;
  for(int i=tid;i<Cc*Tin;i+=TPB){ int c=i/Tin, l=i%Tin; sX[c][l] = x[((size_t)(b*Cc+c)*Nn+n)*Tin+l]; }
  for(int i=tid;i<Cc*Cc;i+=TPB) sW[i]=W[i];
  __syncthreads();
  for(int i=tid;i<Cc*Tin;i+=TPB){
    int o=i/Tin, l=i%Tin; float acc=bias[o];
    #pragma unroll 8
    for(int c=0;c<Cc;c++) acc += sW[o*Cc+c]*sX[c][l];
    out[((size_t)(b*Cc+o)*Nn+n)*Tin+l]=acc;
    sO[o][l]=acc;
  }
  __syncthreads();
  if(tid < Cc){
    float s=0.f,s2=0.f;
    for(int l=0;l<Tin;l++){ float v=sO[tid][l]; s+=v; s2+=v*v; }
    float m=s*(1.f/Tin); float var=s2*(1.f/Tin)-m*m;
    int row = (b*Cc+tid)*Nn + n;
    lnm[row]=m; lnr[row]=rsqrtf(fmaxf(var,0.f)+EPSF);
  }
}

// ---------------- lnS stats ----------------
__global__ __launch_bounds__(TPB) void k_lnS(const float* __restrict__ r, float* __restrict__ mean, float* __restrict__ rstd){
  int row = blockIdx.x*TPB + threadIdx.x;       // (b*Cc+c)*Tin + l
  if(row >= Bx*Cc*Tin) return;
  int l = row % Tin; int bc = row / Tin;
  const float* p = r + (size_t)bc*Nn*Tin + l;
  float s=0.f,s2=0.f;
  for(int n=0;n<Nn;n++){ float v=p[(size_t)n*Tin]; s+=v; s2+=v*v; }
  float m=s*(1.f/Nn); float var=s2*(1.f/Nn)-m*m;
  mean[row]=m; rstd[row]=rsqrtf(fmaxf(var,0.f)+EPSF);
}

// ---------------- merged fragment-order weight converter (10 jobs + adj) ----------------
struct WJob { const float* W; ushort* F; int K, N, KS, NT, sStride, total; };
struct WJobs { WJob j[11]; };

__global__ __launch_bounds__(TPB) void k_wfrag_all(WJobs jobs){
  int gi = blockIdx.x*TPB + threadIdx.x;
  for(int seg=0; seg<11; seg++){
    const WJob J = jobs.j[seg];
    if(gi < J.total){
      int i = gi;
      int j = i & 7; int lane = (i>>3) & 63;
      int t = i >> 9;
      int ks = t % J.KS; int r = t / J.KS; int colTile = r % J.NT; int s = r / J.NT;
      int r15 = lane & 15, hi = lane >> 4;
      int k = ks*32 + hi*8 + j, col = colTile*16 + r15;
      float v = (k < J.K && col < J.N) ? J.W[(size_t)s*J.sStride + (size_t)k*J.N + col] : 0.f;
      J.F[i] = f2bf(v);
      return;
    }
    gi -= J.total;
  }
}

// ---------------- time-conv weight frag convert ----------------
__global__ __launch_bounds__(TPB) void k_wtbF(const float* __restrict__ W, ushort* __restrict__ F){
  int i = blockIdx.x*TPB + threadIdx.x;
  if(i >= 8*18*512) return;
  int j = i & 7; int lane = (i>>3) & 63;
  int t = i >> 9;
  int ks = t % 18; int colTile = t / 18;
  int r15 = lane & 15, hi = lane >> 4;
  int k = ks*32 + hi*8 + j, o = colTile*16 + r15;
  int kt = k/192, ci = k - kt*192;
  F[i] = f2bf(W[(size_t)(o*192+ci)*3 + kt]);
}

// ---------------- mlp-conv weight frag convert ----------------
__global__ __launch_bounds__(TPB) void k_wmlpF(const float* __restrict__ W, ushort* __restrict__ F){
  int i = blockIdx.x*TPB + threadIdx.x;
  if(i >= 3*8*12*512) return;
  int j = i & 7; int lane = (i>>3) & 63;
  int t = i >> 9;
  int ks = t % 12; int r = t / 12; int colTile = r & 7; int layer = r >> 3;
  int r15 = lane & 15, hi = lane >> 4;
  int k = ks*32 + hi*8 + j;
  int kt = k >> 7, ci = k & 127;
  int o = colTile*16 + r15;
  F[i] = f2bf(W[(size_t)(o*384 + layer*128 + ci)*3 + kt]);
}

// ---------------- activation transpose+convert: X f32 [b][C][NP] -> XT bf16 [b][NPa][C] ----------------
template<int C>
__global__ __launch_bounds__(TPB) void k_t2bf(const float* __restrict__ X, ushort* __restrict__ XT){
  int p0 = blockIdx.x*64, b = blockIdx.y;
  int tid = threadIdx.x;
  __shared__ __align__(16) float sT[64][65];
  for(int cc=0; cc<C; cc+=64){
    if(cc) __syncthreads();
    for(int i=tid;i<4096;i+=TPB){ int c=i>>6, col=i&63; int p=p0+col;
      sT[c][col] = (p<NP) ? X[((size_t)(b*C+cc+c))*NP + p] : 0.f; }
    __syncthreads();
    for(int i=tid;i<512;i+=TPB){
      int row=i>>3, c8=(i&7)<<3;
      ushort u[8];
      #pragma unroll
      for(int j=0;j<8;j++) u[j] = f2bf(sT[c8+j][row]);
      *(uint4*)&XT[((size_t)b*NPa + p0 + row)*C + cc + c8] = *(uint4*)u;
    }
  }
}

// ---------------- fused xcat+dilated time conv (dil=2) + GLU via MFMA -> HT bf16 [b][p][64] ----------------
__global__ __launch_bounds__(TPB) void k_timeconv_mfma(const float* __restrict__ resid,
    const float* __restrict__ tm, const float* __restrict__ tr,
    const float* __restrict__ sm, const float* __restrict__ sr,
    const float* __restrict__ gT, const float* __restrict__ bT,
    const float* __restrict__ gS, const float* __restrict__ bS,
    const ushort* __restrict__ WF, const float* __restrict__ bias, ushort* __restrict__ HT){
  int n = blockIdx.x, b = blockIdx.y;
  constexpr int XS = 200;
  __shared__ __align__(16) ushort sXT[68*XS];
  int tid = threadIdx.x;
  for(int i=tid; i<14*XS; i+=TPB) sXT[54*XS + i] = 0;
  float gSn = gS[n], bSn = bS[n];
  for(int i=tid; i<64*54; i+=TPB){
    int cm = i/54, l = i%54;
    int rowT = (b*Cc+cm)*Nn + n;
    float r = resid[(size_t)rowT*Tin + l];
    float v1 = (r - tm[rowT]) * tr[rowT] * gT[l] + bT[l];
    int rowS = (b*Cc+cm)*Tin + l;
    float v2 = (r - sm[rowS]) * sr[rowS] * gSn + bSn;
    sXT[l*XS + cm]        = f2bf(r);
    sXT[l*XS + 64 + cm]   = f2bf(v1);
    sXT[l*XS + 128 + cm]  = f2bf(v2);
  }
  __syncthreads();
  int lane = tid & 63, w = tid >> 6;
  int r15 = lane & 15, hi = lane >> 4;
  float b0 = bias[w*16 + r15], b1 = bias[w*16 + 64 + r15];
  f32x4 acc0[4], acc1[4];
  #pragma unroll
  for(int tt=0;tt<4;tt++){
    acc0[tt][0]=b0; acc0[tt][1]=b0; acc0[tt][2]=b0; acc0[tt][3]=b0;
    acc1[tt][0]=b1; acc1[tt][1]=b1; acc1[tt][2]=b1; acc1[tt][3]=b1;
  }
  const ushort* wp0 = WF + ((size_t)w*18)*512 + lane*8;
  const ushort* wp1 = WF + ((size_t)(w+4)*18)*512 + lane*8;
  #pragma unroll 2
  for(int ks=0; ks<18; ks++){
    int k0 = ks*32 + hi*8;
    int kt = k0/192, ci0 = k0 - kt*192;
    bf16x8 bw0 = *(const bf16x8*)&wp0[(size_t)ks*512];
    bf16x8 bw1 = *(const bf16x8*)&wp1[(size_t)ks*512];
    #pragma unroll
    for(int tt=0;tt<4;tt++){
      bf16x8 ax = *(const bf16x8*)&sXT[(tt*16 + r15 + 2*kt)*XS + ci0];
      acc0[tt] = __builtin_amdgcn_mfma_f32_16x16x32_bf16(ax, bw0, acc0[tt], 0,0,0);
      acc1[tt] = __builtin_amdgcn_mfma_f32_16x16x32_bf16(ax, bw1, acc1[tt], 0,0,0);
    }
  }
  ushort* htp = HT + ((size_t)b*NPa + (size_t)n*LP)*64;
  int c = w*16 + r15;
  #pragma unroll
  for(int tt=0;tt<4;tt++){
    int t0 = tt*16 + hi*4;
    #pragma unroll
    for(int i=0;i<4;i++){
      int t = t0 + i;
      if(t < L50) htp[(size_t)t*64 + c] = f2bf(tanhf(acc0[tt][i])*sigm(acc1[tt][i]));
    }
  }
  if(tid < 128){ int cz = tid >> 1, tz = 50 + (tid & 1); htp[(size_t)tz*64 + cz] = 0; }
}

// ---------------- zero HT padding rows p in [NP, NPa) ----------------
__global__ __launch_bounds__(TPB) void k_htpad(ushort* __restrict__ HT){
  int i = blockIdx.x*TPB + threadIdx.x;
  int per = (NPa-NP)*8;                           // 8 uint4 per row of 64 ushorts
  if(i >= Bx*per) return;
  int b = i / per, r = i % per;
  uint4 z; z.x=0;z.y=0;z.z=0;z.w=0;
  *(uint4*)&HT[((size_t)b*NPa + NP)*64 + (size_t)r*8] = z;
}

// ---------------- gated multi-basis GCN einsum via MFMA ----------------
template<int D>
__global__ __launch_bounds__(TPB) void k_gcs_mfma(const ushort* __restrict__ XT,
    const ushort* __restrict__ wqF, const ushort* __restrict__ wvF,
    float* __restrict__ S){
  constexpr int Dt = D/16;
  int p0 = blockIdx.x*64;
  int b = blockIdx.z;
  int tid = threadIdx.x;
  int lane = tid & 63, w = tid >> 6;
  int d0 = blockIdx.y*64 + (w<<4);
  int dTile = blockIdx.y*4 + w;
  __shared__ __align__(16) ushort sX[64*64];
  for(int i=tid;i<512;i+=TPB){
    int row=i>>3, c8=(i&7)<<3;
    uint4 v = *(const uint4*)&XT[((size_t)b*NPa + p0 + row)*64 + c8];
    *(uint4*)&sX[row*64 + (c8 ^ ((row&7)<<3))] = v;
  }
  __syncthreads();
  int r15 = lane & 15, hi = lane >> 4;
  bf16x8 bf[4][2];
  #pragma unroll
  for(int pt=0;pt<4;pt++){
    int row = pt*16 + r15;
    int sw = (row&7)<<3;
    int cu0 = hi*8;
    bf[pt][0] = *(const bf16x8*)&sX[row*64 + (cu0 ^ sw)];
    bf[pt][1] = *(const bf16x8*)&sX[row*64 + ((cu0+32) ^ sw)];
  }
  f32x4 acc[4];
  #pragma unroll
  for(int pt=0;pt<4;pt++){ acc[pt][0]=0.f; acc[pt][1]=0.f; acc[pt][2]=0.f; acc[pt][3]=0.f; }
  const ushort* wqp = wqF + ((size_t)dTile*2)*512 + lane*8;
  const ushort* wvp = wvF + ((size_t)dTile*2)*512 + lane*8;
  for(int k=0;k<Kb;k++){
    bf16x8 aq0 = *(const bf16x8*)&wqp[0];
    bf16x8 aq1 = *(const bf16x8*)&wqp[512];
    bf16x8 av0 = *(const bf16x8*)&wvp[0];
    bf16x8 av1 = *(const bf16x8*)&wvp[512];
    wqp += (size_t)Dt*2*512; wvp += (size_t)Dt*2*512;
    #pragma unroll
    for(int pt=0;pt<4;pt++){
      f32x4 q; q[0]=0.f;q[1]=0.f;q[2]=0.f;q[3]=0.f;
      f32x4 v; v[0]=0.f;v[1]=0.f;v[2]=0.f;v[3]=0.f;
      q = __builtin_amdgcn_mfma_f32_16x16x32_bf16(aq0, bf[pt][0], q, 0,0,0);
      q = __builtin_amdgcn_mfma_f32_16x16x32_bf16(aq1, bf[pt][1], q, 0,0,0);
      v = __builtin_amdgcn_mfma_f32_16x16x32_bf16(av0, bf[pt][0], v, 0,0,0);
      v = __builtin_amdgcn_mfma_f32_16x16x32_bf16(av1, bf[pt][1], v, 0,0,0);
      #pragma unroll
      for(int i=0;i<4;i++) acc[pt][i] += v[i]*sigm(q[i]);
    }
  }
  #pragma unroll
  for(int pt=0;pt<4;pt++){
    int p = p0 + pt*16 + r15;
    if(p < NP){
      #pragma unroll
      for(int i=0;i<4;i++){
        int d = d0 + hi*4 + i;
        S[((size_t)b*D + d)*NP + p] = acc[pt][i];
      }
    }
  }
}

// ---------------- adjacency aggregation via MFMA (fused S transpose in; coalesced f32 out) ----------------
template<int RELU>
__global__ __launch_bounds__(TPB) void k_agg_mfma(const float* __restrict__ S, const ushort* __restrict__ adjF,
                                                  const float* __restrict__ bias, float* __restrict__ Out, int D){
  int d = blockIdx.x, b = blockIdx.y;
  int bd = b*D + d;
  constexpr int SST = 232;
  __shared__ __align__(16) ushort sB[64*SST];
  int tid = threadIdx.x;
  for(int i=tid*8; i<64*SST; i+=TPB*8){ uint4 z; z.x=0;z.y=0;z.z=0;z.w=0; *(uint4*)&sB[i]=z; }
  __syncthreads();
  const float* Sp = S + (size_t)bd*NP;
  for(int i=tid; i<NP; i+=TPB){
    int nn = i/52, l = i - nn*52;
    sB[l*SST + nn] = f2bf(Sp[i]);
  }
  __syncthreads();
  int lane = tid & 63, w = tid >> 6;
  int r15 = lane & 15, hi = lane >> 4;
  float bb = bias[d];
  float* Op = Out + (size_t)bd*NP;
  for(int k2t = w; k2t < 13; k2t += 4){
    f32x4 acc[4];
    #pragma unroll
    for(int lt=0;lt<4;lt++){ acc[lt][0]=0;acc[lt][1]=0;acc[lt][2]=0;acc[lt][3]=0; }
    #pragma unroll
    for(int ks=0; ks<7; ks++){
      bf16x8 a = *(const bf16x8*)&adjF[((size_t)(k2t*7 + ks))*512 + lane*8];
      #pragma unroll
      for(int lt=0;lt<4;lt++){
        bf16x8 bfr = *(const bf16x8*)&sB[(lt*16+r15)*SST + ks*32 + hi*8];
        acc[lt] = __builtin_amdgcn_mfma_f32_16x16x32_bf16(a, bfr, acc[lt], 0,0,0);
      }
    }
    #pragma unroll
    for(int lt=0;lt<4;lt++){
      #pragma unroll
      for(int i2=0;i2<4;i2++){
        int k2 = k2t*16 + hi*4 + i2;
        int l  = lt*16 + r15;
        if(k2 < Nn && l < LP){
          float v = acc[lt][i2] + bb;
          if(RELU) v = fmaxf(v, 0.f);
          Op[(size_t)k2*LP + l] = v;
        }
      }
    }
  }
}

// ---------------- MLP conv (dil=1) via MFMA, per layer; input RB f32 [b][128][NP] ----------------
template<int MODE>
__global__ __launch_bounds__(TPB) void k_mlpacc_mfma(const float* __restrict__ RB, const ushort* __restrict__ WF,
                                                     float* __restrict__ gacc, const float* __restrict__ bm,
                                                     float* __restrict__ gg){
  int n = blockIdx.x, b = blockIdx.y;
  constexpr int CS = 136;
  __shared__ __align__(16) ushort sLT[52*CS];
  int tid = threadIdx.x;
  for(int i=tid;i<6656;i+=TPB){
    int c = i/52, l = i%52;
    sLT[l*CS + c] = f2bf(RB[(((size_t)b*128+c)*Nn + n)*LP + l]);
  }
  __syncthreads();
  int lane = tid & 63, w = tid >> 6;
  int r15 = lane & 15, hi = lane >> 4;
  f32x4 acc0[3], acc1[3];
  #pragma unroll
  for(int tt=0;tt<3;tt++){
    acc0[tt][0]=0;acc0[tt][1]=0;acc0[tt][2]=0;acc0[tt][3]=0;
    acc1[tt][0]=0;acc1[tt][1]=0;acc1[tt][2]=0;acc1[tt][3]=0;
  }
  const ushort* wp0 = WF + ((size_t)w*12)*512 + lane*8;
  const ushort* wp1 = WF + ((size_t)(w+4)*12)*512 + lane*8;
  #pragma unroll 3
  for(int ks=0; ks<12; ks++){
    int kt = ks>>2, ci0 = (ks&3)*32 + hi*8;
    bf16x8 bw0 = *(const bf16x8*)&wp0[(size_t)ks*512];
    bf16x8 bw1 = *(const bf16x8*)&wp1[(size_t)ks*512];
    #pragma unroll
    for(int tt=0;tt<3;tt++){
      bf16x8 ax = *(const bf16x8*)&sLT[(tt*16 + r15 + kt)*CS + ci0];
      acc0[tt] = __builtin_amdgcn_mfma_f32_16x16x32_bf16(ax, bw0, acc0[tt], 0,0,0);
      acc1[tt] = __builtin_amdgcn_mfma_f32_16x16x32_bf16(ax, bw1, acc1[tt], 0,0,0);
    }
  }
  int o = w*16 + r15;
  if(MODE < 2){
    float* gp = gacc + ((size_t)b*Nn + n)*48*128;
    #pragma unroll
    for(int tt=0;tt<3;tt++){
      #pragma unroll
      for(int i2=0;i2<4;i2++){
        int tq = tt*16 + hi*4 + i2;
        size_t a0 = (size_t)tq*128 + o;
        if(MODE==0){ gp[a0] = acc0[tt][i2]; gp[a0+64] = acc1[tt][i2]; }
        else       { gp[a0] += acc0[tt][i2]; gp[a0+64] += acc1[tt][i2]; }
      }
    }
  } else {
    const float* gp = gacc + ((size_t)b*Nn + n)*48*128;
    float b0 = bm[o], b1 = bm[o+64];
    float* ggp = gg + (((size_t)b*Cc + o)*Nn + n)*(size_t)Tout;
    #pragma unroll
    for(int tt=0;tt<3;tt++){
      #pragma unroll
      for(int i2=0;i2<4;i2++){
        int tq = tt*16 + hi*4 + i2;
        size_t a0 = (size_t)tq*128 + o;
        float a  = gp[a0]    + acc0[tt][i2] + b0;
        float g2 = gp[a0+64] + acc1[tt][i2] + b1;
        ggp[tq] = tanhf(a)*sigm(g2);
      }
    }
  }
}

// ---------------- per-row LN helper (rows of 512, stride SRDF, in LDS); NW waves ----------------
template<int NW>
__device__ __forceinline__ void ln_rows(float* buf, const float* __restrict__ g, const float* __restrict__ be, int tid){
  int lane = tid & 63, wv = tid >> 6;
  for(int r = wv; r < 12; r += NW){
    float s=0.f, s2=0.f;
    #pragma unroll
    for(int j=0;j<8;j++){ float v = buf[r*SRDF + j*64 + lane]; s+=v; s2+=v*v; }
    #pragma unroll
    for(int off=32; off; off>>=1){ s += __shfl_xor(s,off); s2 += __shfl_xor(s2,off); }
    float m = s*(1.f/512.f);
    float rstd = rsqrtf(fmaxf(s2*(1.f/512.f)-m*m, 0.f)+EPSF);
    #pragma unroll
    for(int j=0;j<8;j++){ int e = j*64+lane; float v = buf[r*SRDF+e];
      buf[r*SRDF+e] = (v-m)*rstd*g[e] + be[e]; }
  }
}

// ---------------- fused per-(b,n) transformer; xe on the fly, hoisted to phase 1 ----------------
__global__ __launch_bounds__(TPA,2) void k_attn(
    const float* __restrict__ gg, const float* __restrict__ emb, const float* __restrict__ resid,
    const ushort* __restrict__ WqF, const float* __restrict__ bq,
    const ushort* __restrict__ WkF, const float* __restrict__ bk,
    const ushort* __restrict__ WvF, const float* __restrict__ bv,
    const ushort* __restrict__ WfcF, const float* __restrict__ bfc,
    const float* __restrict__ g1, const float* __restrict__ b1n,
    const float* __restrict__ g2, const float* __restrict__ b2n,
    const ushort* __restrict__ Wff1F, const float* __restrict__ bff1,
    const ushort* __restrict__ Wff2F, const float* __restrict__ bff2,
    const float* __restrict__ Wrp, const float* __restrict__ brp,
    float* __restrict__ y)
{
  int n = blockIdx.x, b = blockIdx.y;
  __shared__ __align__(16) ushort SbX[16*512];
  __shared__ __align__(16) ushort Mb[16*256];
  __shared__ __align__(16) float U0[12*SRDF];
  __shared__ __align__(16) float U1[12*SRDF];
  __shared__ __align__(16) float sS[1160];
  int tid = threadIdx.x;
  int lane = tid & 63, w = tid >> 6;          // w in [0,8)
  int r15 = lane & 15, hi = lane >> 4;

  // phase 1: build SbX (bf16 xe); run-batched — (c,ns,P) constant per 8-run since 19872%8==0, 96%8==0
  for(int i=tid;i<1024;i+=TPA){
    int r = i>>6, ch = i&63;
    ushort u[8];
    if(r<12){
      int flat = n*6144 + r*512 + ch*8;
      int c = flat / 19872; int rem = flat - c*19872;
      int ns = rem / 96;    int r2  = rem - ns*96;
      int P = r2>>3;
      const float* gp = &gg[(((size_t)b*Cc + c)*Nn + ns)*(size_t)Tout + P*4];
      const float* ep = &emb[(size_t)r*Ee + ch*8];
      #pragma unroll
      for(int j=0;j<8;j++){
        int t = P*4 + j;
        float v = (t < Tout) ? gp[j] : 0.f;
        u[j] = f2bf(v + ep[j]);
      }
    } else {
      #pragma unroll
      for(int j=0;j<8;j++) u[j] = 0;
    }
    *(uint4*)&SbX[r*512 + ((ch ^ (r&7))<<3)] = *(uint4*)u;
  }
  for(int i=tid;i<128;i+=TPA){
    int r = 12 + (i>>5), ch = i&31;
    uint4 z; z.x=0;z.y=0;z.z=0;z.w=0;
    *(uint4*)&Mb[r*256 + ch*8] = z;
  }

  // hoisted xe registers: fc-add needs (p=hi*4+i2, col=(w*4+nt)*16+r15); final needs (r=0..11, col=tid)
  float xeF[16];
  #pragma unroll
  for(int nt=0;nt<4;nt++){
    int col = (w*4+nt)*16 + r15;
    #pragma unroll
    for(int i2=0;i2<4;i2++){
      int p = hi*4 + i2;
      xeF[nt*4+i2] = (p<12) ? xe_val(gg, emb, b, n, p, col) : 0.f;
    }
  }
  float xeU[12];
  #pragma unroll
  for(int r=0;r<12;r++) xeU[r] = xe_val(gg, emb, b, n, r, tid);
  __syncthreads();

  // QKV: one head per wave
  f32x4 vfrag[4];
  {
    int head = w;
    bf16x8 a0, a1;
    { int ch0 = head*8 + hi, ch1 = head*8 + 4 + hi;
      a0 = *(const bf16x8*)&SbX[r15*512 + ((ch0 ^ (r15&7))<<3)];
      a1 = *(const bf16x8*)&SbX[r15*512 + ((ch1 ^ (r15&7))<<3)]; }
    #pragma unroll
    for(int nt=0;nt<4;nt++){
      int col = nt*16 + r15;
      float bb = bq[col];
      f32x4 acc; acc[0]=bb;acc[1]=bb;acc[2]=bb;acc[3]=bb;
      acc = __builtin_amdgcn_mfma_f32_16x16x32_bf16(a0, *(const bf16x8*)&WqF[(size_t)(nt*2+0)*512 + lane*8], acc, 0,0,0);
      acc = __builtin_amdgcn_mfma_f32_16x16x32_bf16(a1, *(const bf16x8*)&WqF[(size_t)(nt*2+1)*512 + lane*8], acc, 0,0,0);
      #pragma unroll
      for(int i2=0;i2<4;i2++){ int p = hi*4+i2; if(p<12) U0[p*SRDF + head*64 + col] = acc[i2]; }
    }
    #pragma unroll
    for(int nt=0;nt<4;nt++){
      int col = nt*16 + r15;
      float bb = bk[col];
      f32x4 acc; acc[0]=bb;acc[1]=bb;acc[2]=bb;acc[3]=bb;
      acc = __builtin_amdgcn_mfma_f32_16x16x32_bf16(a0, *(const bf16x8*)&WkF[(size_t)(nt*2+0)*512 + lane*8], acc, 0,0,0);
      acc = __builtin_amdgcn_mfma_f32_16x16x32_bf16(a1, *(const bf16x8*)&WkF[(size_t)(nt*2+1)*512 + lane*8], acc, 0,0,0);
      #pragma unroll
      for(int i2=0;i2<4;i2++){ int p = hi*4+i2; if(p<12) U1[p*SRDF + head*64 + col] = acc[i2]; }
    }
    #pragma unroll
    for(int nt=0;nt<4;nt++){
      int col = nt*16 + r15;
      float bb = bv[col];
      f32x4 acc; acc[0]=bb;acc[1]=bb;acc[2]=bb;acc[3]=bb;
      acc = __builtin_amdgcn_mfma_f32_16x16x32_bf16(a0, *(const bf16x8*)&WvF[(size_t)(nt*2+0)*512 + lane*8], acc, 0,0,0);
      acc = __builtin_amdgcn_mfma_f32_16x16x32_bf16(a1, *(const bf16x8*)&WvF[(size_t)(nt*2+1)*512 + lane*8], acc, 0,0,0);
      vfrag[nt] = acc;
    }
  }
  __syncthreads();

  const float scale = 0.04419417382415922f;   // 1/sqrt(512)
  for(int i=tid;i<1152;i+=TPA){
    int q = i%12, kh = i/12; int h2 = kh&7, k2 = kh>>3;
    const float* qp = &U0[q*SRDF + h2*64];
    const float* kp = &U1[k2*SRDF + h2*64];
    float s=0.f;
    #pragma unroll
    for(int d4=0; d4<16; d4++){
      float4 a4 = *(const float4*)&qp[d4*4];
      float4 b4 = *(const float4*)&kp[d4*4];
      s += a4.x*b4.x + a4.y*b4.y + a4.z*b4.z + a4.w*b4.w;
    }
    sS[i] = s*scale;
  }
  __syncthreads();
  {
    int head = w;
    #pragma unroll
    for(int nt=0;nt<4;nt++){
      int col = nt*16 + r15;
      #pragma unroll
      for(int i2=0;i2<4;i2++){ int p = hi*4+i2; if(p<12) U0[p*SRDF + head*64 + col] = vfrag[nt][i2]; }
    }
  }
  if(tid<96){
    float mx=-1e30f;
    for(int q=0;q<12;q++) mx = fmaxf(mx, sS[tid*12+q]);
    float sm=0.f;
    for(int q=0;q<12;q++){ float e = __expf(sS[tid*12+q]-mx); sS[tid*12+q]=e; sm+=e; }
    float inv = 1.f/sm;
    for(int q=0;q<12;q++) sS[tid*12+q] *= inv;
  }
  __syncthreads();

  for(int i=tid;i<6144;i+=TPA){
    int q=i>>9, h2=(i>>6)&7, d=i&63;
    float s=0.f;
    #pragma unroll
    for(int k2=0;k2<12;k2++) s += sS[(k2*8+h2)*12+q]*U0[k2*SRDF+h2*64+d];
    int kk = i & 511;
    SbX[q*512 + (((kk>>3) ^ (q&7))<<3) + (kk&7)] = f2bf(s);
  }
  __syncthreads();

  // fc: 32 col-tiles, 4 per wave; xe from registers
  {
    f32x4 acc[4];
    #pragma unroll
    for(int nt=0;nt<4;nt++){ float bb = bfc[(w*4+nt)*16 + r15]; acc[nt][0]=bb;acc[nt][1]=bb;acc[nt][2]=bb;acc[nt][3]=bb; }
    for(int ks=0;ks<16;ks++){
      int ch = ks*4 + hi;
      bf16x8 a = *(const bf16x8*)&SbX[r15*512 + ((ch ^ (r15&7))<<3)];
      #pragma unroll
      for(int nt=0;nt<4;nt++){
        acc[nt] = __builtin_amdgcn_mfma_f32_16x16x32_bf16(a, *(const bf16x8*)&WfcF[(size_t)((w*4+nt)*16 + ks)*512 + lane*8], acc[nt], 0,0,0);
      }
    }
    #pragma unroll
    for(int nt=0;nt<4;nt++){
      int col = (w*4+nt)*16 + r15;
      #pragma unroll
      for(int i2=0;i2<4;i2++){ int p = hi*4+i2; if(p<12) U1[p*SRDF + col] = acc[nt][i2] + xeF[nt*4+i2]; }
    }
  }
  __syncthreads();
  ln_rows<8>(U1, g1, b1n, tid);     // M in U1
  __syncthreads();

  for(int i=tid;i<6144;i+=TPA){
    int r=i>>9, kk=i&511;
    SbX[r*512 + (((kk>>3) ^ (r&7))<<3) + (kk&7)] = f2bf(U1[r*SRDF + kk]);
  }
  __syncthreads();

  // ff1: 16 col-tiles, 2 per wave
  {
    f32x4 acc[2];
    #pragma unroll
    for(int nt=0;nt<2;nt++){ float bb = bff1[(w*2+nt)*16 + r15]; acc[nt][0]=bb;acc[nt][1]=bb;acc[nt][2]=bb;acc[nt][3]=bb; }
    for(int ks=0;ks<16;ks++){
      int ch = ks*4 + hi;
      bf16x8 a = *(const bf16x8*)&SbX[r15*512 + ((ch ^ (r15&7))<<3)];
      #pragma unroll
      for(int nt=0;nt<2;nt++){
        acc[nt] = __builtin_amdgcn_mfma_f32_16x16x32_bf16(a, *(const bf16x8*)&Wff1F[(size_t)((w*2+nt)*16 + ks)*512 + lane*8], acc[nt], 0,0,0);
      }
    }
    #pragma unroll
    for(int nt=0;nt<2;nt++){
      int u = (w*2+nt)*16 + r15;
      #pragma unroll
      for(int i2=0;i2<4;i2++){
        int p = hi*4+i2;
        if(p<12) Mb[p*256 + (((u>>3) ^ (p&7))<<3) + (u&7)] = f2bf(fmaxf(acc[nt][i2], 0.f));
      }
    }
  }
  __syncthreads();

  // ff2: 32 col-tiles, 4 per wave
  {
    f32x4 acc[4];
    #pragma unroll
    for(int nt=0;nt<4;nt++){ float bb = bff2[(w*4+nt)*16 + r15]; acc[nt][0]=bb;acc[nt][1]=bb;acc[nt][2]=bb;acc[nt][3]=bb; }
    for(int ks=0;ks<8;ks++){
      int ch = ks*4 + hi;
      bf16x8 a = *(const bf16x8*)&Mb[r15*256 + ((ch ^ (r15&7))<<3)];
      #pragma unroll
      for(int nt=0;nt<4;nt++){
        acc[nt] = __builtin_amdgcn_mfma_f32_16x16x32_bf16(a, *(const bf16x8*)&Wff2F[(size_t)((w*4+nt)*8 + ks)*512 + lane*8], acc[nt], 0,0,0);
      }
    }
    #pragma unroll
    for(int nt=0;nt<4;nt++){
      int col = (w*4+nt)*16 + r15;
      #pragma unroll
      for(int i2=0;i2<4;i2++){ int p = hi*4+i2; if(p<12) U0[p*SRDF + col] = acc[nt][i2] + U1[p*SRDF + col]; }
    }
  }
  __syncthreads();
  ln_rows<8>(U0, g2, b2n, tid);     // U in U0
  __syncthreads();

  // final: xe from registers (col = tid, fixed per thread)
  #pragma unroll
  for(int k=0;k<12;k++){
    U1[k*SRDF+tid] = U0[k*SRDF+tid] + U1[k*SRDF+tid] + xeU[k];
  }
  __syncthreads();
  for(int i=tid;i<4608;i+=TPA) U0[i] = Wrp[i];
  __syncthreads();
  #pragma unroll
  for(int j=0;j<2;j++){
    int i4 = tid + j*TPA;
    if(i4 < 768){
      int c = i4/12, tq = i4%12; int t0 = tq*4;
      float4 acc = *(const float4*)&brp[t0];
      for(int t96=0;t96<96;t96++){
        int f = c*96 + t96;
        float a = U1[(f>>9)*SRDF + (f&511)];
        float4 w4 = *(const float4*)&U0[t96*48 + t0];
        FMA4(acc, a, w4);
      }
      size_t rb = (((size_t)b*Cc+c)*Nn + n)*Tin + 6 + t0;
      acc.x += resid[rb+0]; acc.y += resid[rb+1]; acc.z += resid[rb+2]; acc.w += resid[rb+3];
      *(float4*)&y[(((size_t)b*Cc+c)*Nn + n)*Tout + t0] = acc;
    }
  }
}

// ---------------- batchnorm ----------------
__global__ __launch_bounds__(TPB) void k_bnstats(const float* __restrict__ y, float* __restrict__ stats){
  int c = blockIdx.x; int tid = threadIdx.x;
  float s=0.f,s2=0.f;
  const int per = Nn*Tout;   // 9936
  for(int idx=tid; idx<Bx*per; idx+=TPB){
    int b = idx/per, r = idx%per;
    float v = y[((size_t)b*Cc+c)*per + r];
    s+=v; s2+=v*v;
  }
  __shared__ float rs[TPB], rs2[TPB];
  rs[tid]=s; rs2[tid]=s2; __syncthreads();
  for(int off=TPB/2; off; off>>=1){ if(tid<off){ rs[tid]+=rs[tid+off]; rs2[tid]+=rs2[tid+off]; } __syncthreads(); }
  if(tid==0){
    float m = rs[0]/(float)(Bx*per);
    float var = rs2[0]/(float)(Bx*per) - m*m;
    stats[c]=m; stats[64+c]=rsqrtf(fmaxf(var,0.f)+EPSF);
  }
}
__global__ __launch_bounds__(TPB) void k_bnout(const float* __restrict__ y, const float* __restrict__ stats,
                                               const float* __restrict__ gbn, const float* __restrict__ bbn,
                                               float* __restrict__ out){
  size_t i = (size_t)blockIdx.x*TPB + threadIdx.x;
  if(i >= (size_t)Bx*Cc*Nn*Tout) return;
  int c = (int)((i/(Nn*Tout))%Cc);
  out[i] = (y[i]-stats[c])*stats[64+c]*gbn[c] + bbn[c];
}

// ---------------- launch ----------------
extern "C" void kernel_launch(void* const* d_in, const int* in_sizes, int n_in,
                              void* d_out, int out_size, void* d_ws, size_t ws_size,
                              hipStream_t stream) {
  const float* x      = (const float*)d_in[0];
  const float* adj    = (const float*)d_in[1];
  const float* Wconv1 = (const float*)d_in[2];
  const float* bconv1 = (const float*)d_in[3];
  const float* gT     = (const float*)d_in[4];
  const float* bT     = (const float*)d_in[5];
  const float* gS     = (const float*)d_in[6];
  const float* bS     = (const float*)d_in[7];
  const float* Wtime  = (const float*)d_in[8];
  const float* btime  = (const float*)d_in[9];
  const float* wq1    = (const float*)d_in[10];
  const float* wv1    = (const float*)d_in[11];
  const float* bias1  = (const float*)d_in[12];
  const float* wq2    = (const float*)d_in[13];
  const float* wv2    = (const float*)d_in[14];
  const float* bias2  = (const float*)d_in[15];
  const float* Wmlp   = (const float*)d_in[16];
  const float* bmlp   = (const float*)d_in[17];
  const float* embT   = (const float*)d_in[18];
  const float* Wq     = (const float*)d_in[19];
  const float* bq     = (const float*)d_in[20];
  const float* Wk     = (const float*)d_in[21];
  const float* bk     = (const float*)d_in[22];
  const float* Wv     = (const float*)d_in[23];
  const float* bv     = (const float*)d_in[24];
  const float* Wfc    = (const float*)d_in[25];
  const float* bfc    = (const float*)d_in[26];
  const float* g1     = (const float*)d_in[27];
  const float* b1n    = (const float*)d_in[28];
  const float* g2     = (const float*)d_in[29];
  const float* b2n    = (const float*)d_in[30];
  const float* Wff1   = (const float*)d_in[31];
  const float* bff1   = (const float*)d_in[32];
  const float* Wff2   = (const float*)d_in[33];
  const float* bff2   = (const float*)d_in[34];
  const float* Wrp    = (const float*)d_in[35];
  const float* brp    = (const float*)d_in[36];
  const float* gbn    = (const float*)d_in[37];
  const float* bbn    = (const float*)d_in[38];

  float* ws = (float*)d_ws;
  float* RESID = ws + O_RESID;
  float* LNTM  = ws + O_LNTM;
  float* LNTR  = ws + O_LNTR;
  float* LNSM  = ws + O_LNSM;
  float* LNSR  = ws + O_LNSR;
  float* RA    = ws + O_XCAT;
  float* RB    = ws + O_RB;
  float* GACC  = ws + O_GACC;
  float* GG    = ws + O_GG;
  float* Y     = ws + O_XE;      // Y in dead XE region (must NOT alias GG: attn reads gg while writing Y)
  float* BNST  = ws + O_BNST;
  ushort* WTMF = (ushort*)(ws + O_WTM);
  ushort* WTB  = (ushort*)(ws + O_WTB);
  ushort* ADJT = (ushort*)(ws + O_ADJT);
  ushort* HT   = (ushort*)(ws + O_HT);   // in dead H region
  ushort* WQ1B = (ushort*)(ws + O_WQ1B);
  ushort* WV1B = (ushort*)(ws + O_WV1B);
  ushort* WQ2B = (ushort*)(ws + O_WQ2B);
  ushort* WV2B = (ushort*)(ws + O_WV2B);
  ushort* RBT  = (ushort*)(ws + O_RBT);
  ushort* WQT  = (ushort*)(ws + O_WQT);
  ushort* WKT  = (ushort*)(ws + O_WKT);
  ushort* WVT  = (ushort*)(ws + O_WVT);
  ushort* WFCT = (ushort*)(ws + O_WFCT);
  ushort* WF1T = (ushort*)(ws + O_WF1T);
  ushort* WF2T = (ushort*)(ws + O_WF2T);

  k_residual<<<dim3(Nn,Bx),TPB,0,stream>>>(x, Wconv1, bconv1, RESID, LNTM, LNTR);
  k_lnS<<<(Bx*Cc*Tin)/TPB,TPB,0,stream>>>(RESID, LNSM, LNSR);
  k_wtbF<<<(8*18*512+TPB-1)/TPB,TPB,0,stream>>>(Wtime, WTB);
  k_wmlpF<<<(3*8*12*512+TPB-1)/TPB,TPB,0,stream>>>(Wmlp, WTMF);
  k_htpad<<<(Bx*(NPa-NP)*8+TPB-1)/TPB,TPB,0,stream>>>(HT);
  // fused xcat + timeconv (reads RESID + LN stats directly)
  k_timeconv_mfma<<<dim3(Nn,Bx),TPB,0,stream>>>(RESID, LNTM, LNTR, LNSM, LNSR, gT, bT, gS, bS,
                                                WTB, btime, HT);

  // merged fragment-order weight converts (11 jobs, one dispatch)
  WJobs jobs;
  jobs.j[0]  = { wq1,  WQ1B, 64,  64,  2,  4,  64*64,   24*4*2*512 };
  jobs.j[1]  = { wv1,  WV1B, 64,  64,  2,  4,  64*64,   24*4*2*512 };
  jobs.j[2]  = { wq2,  WQ2B, 64,  128, 2,  8,  64*128,  24*8*2*512 };
  jobs.j[3]  = { wv2,  WV2B, 64,  128, 2,  8,  64*128,  24*8*2*512 };
  jobs.j[4]  = { Wq,   WQT,  64,  64,  2,  4,  64*64,   4*2*512 };
  jobs.j[5]  = { Wk,   WKT,  64,  64,  2,  4,  64*64,   4*2*512 };
  jobs.j[6]  = { Wv,   WVT,  64,  64,  2,  4,  64*64,   4*2*512 };
  jobs.j[7]  = { Wfc,  WFCT, 512, 512, 16, 32, 512*512, 32*16*512 };
  jobs.j[8]  = { Wff1, WF1T, 512, 256, 16, 16, 512*256, 16*16*512 };
  jobs.j[9]  = { Wff2, WF2T, 256, 512, 8,  32, 256*512, 32*8*512 };
  jobs.j[10] = { adj,  ADJT, 207, 207, 7,  13, Nn*Nn,   3*13*7*512 };
  int totalW = 2*(24*4*2*512) + 2*(24*8*2*512) + 3*(4*2*512) + 32*16*512 + 16*16*512 + 32*8*512 + 3*13*7*512;
  k_wfrag_all<<<(totalW+TPB-1)/TPB,TPB,0,stream>>>(jobs);

  for(int i=0;i<3;i++){
    k_gcs_mfma<64><<<dim3(169,1,Bx),TPB,0,stream>>>(HT, WQ1B+(size_t)i*8*4*2*512, WV1B+(size_t)i*8*4*2*512, RA);
    k_agg_mfma<1><<<dim3(64,Bx),TPB,0,stream>>>(RA, ADJT+(size_t)i*13*7*512, bias1+(size_t)i*64, RB, 64);
    k_t2bf<64><<<dim3(169,Bx),TPB,0,stream>>>(RB, RBT);
    k_gcs_mfma<128><<<dim3(169,2,Bx),TPB,0,stream>>>(RBT, WQ2B+(size_t)i*8*8*2*512, WV2B+(size_t)i*8*8*2*512, RA);
    k_agg_mfma<0><<<dim3(128,Bx),TPB,0,stream>>>(RA, ADJT+(size_t)i*13*7*512, bias2+(size_t)i*128, RB, 128);
    if(i==0)      k_mlpacc_mfma<0><<<dim3(Nn,Bx),TPB,0,stream>>>(RB, WTMF+(size_t)i*8*12*512, GACC, bmlp, GG);
    else if(i==1) k_mlpacc_mfma<1><<<dim3(Nn,Bx),TPB,0,stream>>>(RB, WTMF+(size_t)i*8*12*512, GACC, bmlp, GG);
    else          k_mlpacc_mfma<2><<<dim3(Nn,Bx),TPB,0,stream>>>(RB, WTMF+(size_t)i*8*12*512, GACC, bmlp, GG);
  }
  k_attn<<<dim3(Nn,Bx),TPA,0,stream>>>(GG, embT, RESID, WQT,bq, WKT,bk, WVT,bv, WFCT,bfc,
                                       g1,b1n,g2,b2n, WF1T,bff1, WF2T,bff2, Wrp,brp, Y);
  k_bnstats<<<64,TPB,0,stream>>>(Y, BNST);
  k_bnout<<<(Bx*Cc*Nn*Tout)/TPB,TPB,0,stream>>>(Y, BNST, gbn, bbn, (float*)d_out);
}

// Round 21
// 901.353 us; speedup vs baseline: 1.0531x; 1.0531x over previous
//
#include <hip/hip_runtime.h>
#include <hip/hip_bf16.h>

#define TPB 256
#define TPA 512

constexpr int Bx = 8, Cc = 64, Nn = 207, Tin = 54, Kb = 8;
constexpr int LP = 52, NP = Nn * LP;     // time padded 50->52, flattened node*time positions
constexpr int NPa = 10816;               // NP rounded up to 169*64 for MFMA tiles
constexpr int L50 = 50, Tout = 48;
constexpr int Ee = 512, Pn = 12;
constexpr float EPSF = 1e-5f;
constexpr int SRDF = 516;                // padded row stride for 512-wide f32 LDS rows (2-way bank pattern)

// ---------------- workspace layout (floats) ----------------
constexpr size_t O_RESID = 0;                                   // [B][64][207][54]
constexpr size_t O_LNTM  = O_RESID + (size_t)Bx*Cc*Nn*Tin;
constexpr size_t O_LNTR  = O_LNTM  + (size_t)Bx*Cc*Nn;
constexpr size_t O_LNSM  = O_LNTR  + (size_t)Bx*Cc*Nn;
constexpr size_t O_LNSR  = O_LNSM  + (size_t)Bx*Cc*Tin;
constexpr size_t O_XCAT  = O_LNSR  + (size_t)Bx*Cc*Tin;         // scratch region: RA f32 + bf16 tail
constexpr size_t O_RB    = O_XCAT  + (size_t)Bx*192*Nn*Tin;     // f32 [B][128][NP] agg outputs
constexpr size_t O_H     = O_RB    + (size_t)Bx*128*NP;         // HT bf16 [Bx][NPa][64]
constexpr size_t O_GACC  = O_H     + (size_t)Bx*64*NP;          // [B][n][48][128] (relaid out)
constexpr size_t O_GG    = O_GACC  + (size_t)Bx*128*Nn*Tout;    // [B][64][207][48]; reused as Y after xe built
constexpr size_t O_XE    = O_GG    + (size_t)Bx*64*Nn*Tout;     // [B][207][12][512]
constexpr size_t O_WTT   = O_XE    + (size_t)Bx*Nn*Pn*Ee;       // (unused) 128*192*3
constexpr size_t O_WTM   = O_WTT   + (size_t)128*192*3;         // ushort[3*8*12*512] W_mlp frag bf16
constexpr size_t O_BNST  = O_WTM   + (size_t)128*384*3;         // 128
constexpr size_t O_WTB   = O_BNST + 128;                        // ushort[8*18*512] time-conv bf16 frag weights
constexpr size_t O_ADJT  = O_WTB  + (size_t)128*576/2;          // ushort[3][13*7*512] adj frag bf16
constexpr size_t O_HT    = O_H;                                 // ushort[Bx][NPa][64] in dead H region
constexpr size_t O_TAIL  = O_XCAT + (size_t)Bx*128*NP;          // tail anchor (after RA region)
constexpr size_t O_WQ1B  = O_TAIL + (size_t)Bx*NPa*64/2;        // ushort[24*4*2*512]
constexpr size_t O_WV1B  = O_WQ1B + (size_t)24*64*64/2;
constexpr size_t O_WQ2B  = O_WV1B + (size_t)24*64*64/2;         // ushort[24*8*2*512]
constexpr size_t O_WV2B  = O_WQ2B + (size_t)24*128*64/2;
constexpr size_t O_RBT   = O_WV2B + (size_t)24*128*64/2;        // ushort[Bx][NPa][64] layer-1 bf16 transpose
constexpr size_t O_WQT   = O_RBT  + (size_t)Bx*NPa*64/2;        // ushort[4*2*512]
constexpr size_t O_WKT   = O_WQT  + 2048;
constexpr size_t O_WVT   = O_WKT  + 2048;
constexpr size_t O_WFCT  = O_WVT  + 2048;                       // ushort[32*16*512]
constexpr size_t O_WF1T  = O_WFCT + 131072;                     // ushort[16*16*512]
constexpr size_t O_WF2T  = O_WF1T + 65536;                      // ushort[32*8*512]

#define FMA4(acc, sA_, vB_) { (acc).x += (sA_)*(vB_).x; (acc).y += (sA_)*(vB_).y; (acc).z += (sA_)*(vB_).z; (acc).w += (sA_)*(vB_).w; }

typedef __attribute__((ext_vector_type(8))) short bf16x8;
typedef __attribute__((ext_vector_type(4))) float f32x4;

__device__ __forceinline__ float sigm(float x){ return 1.0f/(1.0f+__expf(-x)); }
__device__ __forceinline__ ushort f2bf(float x){ __hip_bfloat16 h = __float2bfloat16(x); return *(ushort*)&h; }

// ---------------- residual = W_conv1 @ x + b, fused lnT stats ----------------
__global__ __launch_bounds__(TPB) void k_residual(const float* __restrict__ x, const float* __restrict__ W,
                                                  const float* __restrict__ bias, float* __restrict__ out,
                                                  float* __restrict__ lnm, float* __restrict__ lnr){
  int n = blockIdx.x, b = blockIdx.y;
  __shared__ __align__(16) float sX[Cc][Tin];
  __shared__ __align__(16) float sW[Cc*Cc];
  __shared__ __align__(16) float sO[Cc][Tin];
  int tid = threadIdx.x;
  for(int i=tid;i<Cc*Tin;i+=TPB){ int c=i/Tin, l=i%Tin; sX[c][l] = x[((size_t)(b*Cc+c)*Nn+n)*Tin+l]; }
  for(int i=tid;i<Cc*Cc;i+=TPB) sW[i]=W[i];
  __syncthreads();
  for(int i=tid;i<Cc*Tin;i+=TPB){
    int o=i/Tin, l=i%Tin; float acc=bias[o];
    #pragma unroll 8
    for(int c=0;c<Cc;c++) acc += sW[o*Cc+c]*sX[c][l];
    out[((size_t)(b*Cc+o)*Nn+n)*Tin+l]=acc;
    sO[o][l]=acc;
  }
  __syncthreads();
  if(tid < Cc){
    float s=0.f,s2=0.f;
    for(int l=0;l<Tin;l++){ float v=sO[tid][l]; s+=v; s2+=v*v; }
    float m=s*(1.f/Tin); float var=s2*(1.f/Tin)-m*m;
    int row = (b*Cc+tid)*Nn + n;
    lnm[row]=m; lnr[row]=rsqrtf(fmaxf(var,0.f)+EPSF);
  }
}

// ---------------- lnS stats ----------------
__global__ __launch_bounds__(TPB) void k_lnS(const float* __restrict__ r, float* __restrict__ mean, float* __restrict__ rstd){
  int row = blockIdx.x*TPB + threadIdx.x;       // (b*Cc+c)*Tin + l
  if(row >= Bx*Cc*Tin) return;
  int l = row % Tin; int bc = row / Tin;
  const float* p = r + (size_t)bc*Nn*Tin + l;
  float s=0.f,s2=0.f;
  for(int n=0;n<Nn;n++){ float v=p[(size_t)n*Tin]; s+=v; s2+=v*v; }
  float m=s*(1.f/Nn); float var=s2*(1.f/Nn)-m*m;
  mean[row]=m; rstd[row]=rsqrtf(fmaxf(var,0.f)+EPSF);
}

// ---------------- merged fragment-order weight converter (10 jobs + adj) ----------------
struct WJob { const float* W; ushort* F; int K, N, KS, NT, sStride, total; };
struct WJobs { WJob j[11]; };

__global__ __launch_bounds__(TPB) void k_wfrag_all(WJobs jobs){
  int gi = blockIdx.x*TPB + threadIdx.x;
  for(int seg=0; seg<11; seg++){
    const WJob J = jobs.j[seg];
    if(gi < J.total){
      int i = gi;
      int j = i & 7; int lane = (i>>3) & 63;
      int t = i >> 9;
      int ks = t % J.KS; int r = t / J.KS; int colTile = r % J.NT; int s = r / J.NT;
      int r15 = lane & 15, hi = lane >> 4;
      int k = ks*32 + hi*8 + j, col = colTile*16 + r15;
      float v = (k < J.K && col < J.N) ? J.W[(size_t)s*J.sStride + (size_t)k*J.N + col] : 0.f;
      J.F[i] = f2bf(v);
      return;
    }
    gi -= J.total;
  }
}

// ---------------- time-conv weight frag convert ----------------
__global__ __launch_bounds__(TPB) void k_wtbF(const float* __restrict__ W, ushort* __restrict__ F){
  int i = blockIdx.x*TPB + threadIdx.x;
  if(i >= 8*18*512) return;
  int j = i & 7; int lane = (i>>3) & 63;
  int t = i >> 9;
  int ks = t % 18; int colTile = t / 18;
  int r15 = lane & 15, hi = lane >> 4;
  int k = ks*32 + hi*8 + j, o = colTile*16 + r15;
  int kt = k/192, ci = k - kt*192;
  F[i] = f2bf(W[(size_t)(o*192+ci)*3 + kt]);
}

// ---------------- mlp-conv weight frag convert ----------------
__global__ __launch_bounds__(TPB) void k_wmlpF(const float* __restrict__ W, ushort* __restrict__ F){
  int i = blockIdx.x*TPB + threadIdx.x;
  if(i >= 3*8*12*512) return;
  int j = i & 7; int lane = (i>>3) & 63;
  int t = i >> 9;
  int ks = t % 12; int r = t / 12; int colTile = r & 7; int layer = r >> 3;
  int r15 = lane & 15, hi = lane >> 4;
  int k = ks*32 + hi*8 + j;
  int kt = k >> 7, ci = k & 127;
  int o = colTile*16 + r15;
  F[i] = f2bf(W[(size_t)(o*384 + layer*128 + ci)*3 + kt]);
}

// ---------------- activation transpose+convert: X f32 [b][C][NP] -> XT bf16 [b][NPa][C] ----------------
template<int C>
__global__ __launch_bounds__(TPB) void k_t2bf(const float* __restrict__ X, ushort* __restrict__ XT){
  int p0 = blockIdx.x*64, b = blockIdx.y;
  int tid = threadIdx.x;
  __shared__ __align__(16) float sT[64][65];
  for(int cc=0; cc<C; cc+=64){
    if(cc) __syncthreads();
    for(int i=tid;i<4096;i+=TPB){ int c=i>>6, col=i&63; int p=p0+col;
      sT[c][col] = (p<NP) ? X[((size_t)(b*C+cc+c))*NP + p] : 0.f; }
    __syncthreads();
    for(int i=tid;i<512;i+=TPB){
      int row=i>>3, c8=(i&7)<<3;
      ushort u[8];
      #pragma unroll
      for(int j=0;j<8;j++) u[j] = f2bf(sT[c8+j][row]);
      *(uint4*)&XT[((size_t)b*NPa + p0 + row)*C + cc + c8] = *(uint4*)u;
    }
  }
}

// ---------------- fused xcat+dilated time conv (dil=2) + GLU via MFMA -> HT bf16 [b][p][64] ----------------
__global__ __launch_bounds__(TPB) void k_timeconv_mfma(const float* __restrict__ resid,
    const float* __restrict__ tm, const float* __restrict__ tr,
    const float* __restrict__ sm, const float* __restrict__ sr,
    const float* __restrict__ gT, const float* __restrict__ bT,
    const float* __restrict__ gS, const float* __restrict__ bS,
    const ushort* __restrict__ WF, const float* __restrict__ bias, ushort* __restrict__ HT){
  int n = blockIdx.x, b = blockIdx.y;
  constexpr int XS = 200;
  __shared__ __align__(16) ushort sXT[68*XS];
  int tid = threadIdx.x;
  for(int i=tid; i<14*XS; i+=TPB) sXT[54*XS + i] = 0;
  float gSn = gS[n], bSn = bS[n];
  for(int i=tid; i<64*54; i+=TPB){
    int cm = i/54, l = i%54;
    int rowT = (b*Cc+cm)*Nn + n;
    float r = resid[(size_t)rowT*Tin + l];
    float v1 = (r - tm[rowT]) * tr[rowT] * gT[l] + bT[l];
    int rowS = (b*Cc+cm)*Tin + l;
    float v2 = (r - sm[rowS]) * sr[rowS] * gSn + bSn;
    sXT[l*XS + cm]        = f2bf(r);
    sXT[l*XS + 64 + cm]   = f2bf(v1);
    sXT[l*XS + 128 + cm]  = f2bf(v2);
  }
  __syncthreads();
  int lane = tid & 63, w = tid >> 6;
  int r15 = lane & 15, hi = lane >> 4;
  float b0 = bias[w*16 + r15], b1 = bias[w*16 + 64 + r15];
  f32x4 acc0[4], acc1[4];
  #pragma unroll
  for(int tt=0;tt<4;tt++){
    acc0[tt][0]=b0; acc0[tt][1]=b0; acc0[tt][2]=b0; acc0[tt][3]=b0;
    acc1[tt][0]=b1; acc1[tt][1]=b1; acc1[tt][2]=b1; acc1[tt][3]=b1;
  }
  const ushort* wp0 = WF + ((size_t)w*18)*512 + lane*8;
  const ushort* wp1 = WF + ((size_t)(w+4)*18)*512 + lane*8;
  #pragma unroll 2
  for(int ks=0; ks<18; ks++){
    int k0 = ks*32 + hi*8;
    int kt = k0/192, ci0 = k0 - kt*192;
    bf16x8 bw0 = *(const bf16x8*)&wp0[(size_t)ks*512];
    bf16x8 bw1 = *(const bf16x8*)&wp1[(size_t)ks*512];
    #pragma unroll
    for(int tt=0;tt<4;tt++){
      bf16x8 ax = *(const bf16x8*)&sXT[(tt*16 + r15 + 2*kt)*XS + ci0];
      acc0[tt] = __builtin_amdgcn_mfma_f32_16x16x32_bf16(ax, bw0, acc0[tt], 0,0,0);
      acc1[tt] = __builtin_amdgcn_mfma_f32_16x16x32_bf16(ax, bw1, acc1[tt], 0,0,0);
    }
  }
  ushort* htp = HT + ((size_t)b*NPa + (size_t)n*LP)*64;
  int c = w*16 + r15;
  #pragma unroll
  for(int tt=0;tt<4;tt++){
    int t0 = tt*16 + hi*4;
    #pragma unroll
    for(int i=0;i<4;i++){
      int t = t0 + i;
      if(t < L50) htp[(size_t)t*64 + c] = f2bf(tanhf(acc0[tt][i])*sigm(acc1[tt][i]));
    }
  }
  if(tid < 128){ int cz = tid >> 1, tz = 50 + (tid & 1); htp[(size_t)tz*64 + cz] = 0; }
}

// ---------------- zero HT padding rows p in [NP, NPa) ----------------
__global__ __launch_bounds__(TPB) void k_htpad(ushort* __restrict__ HT){
  int i = blockIdx.x*TPB + threadIdx.x;
  int per = (NPa-NP)*8;                           // 8 uint4 per row of 64 ushorts
  if(i >= Bx*per) return;
  int b = i / per, r = i % per;
  uint4 z; z.x=0;z.y=0;z.z=0;z.w=0;
  *(uint4*)&HT[((size_t)b*NPa + NP)*64 + (size_t)r*8] = z;
}

// ---------------- gated multi-basis GCN einsum via MFMA ----------------
template<int D>
__global__ __launch_bounds__(TPB) void k_gcs_mfma(const ushort* __restrict__ XT,
    const ushort* __restrict__ wqF, const ushort* __restrict__ wvF,
    float* __restrict__ S){
  constexpr int Dt = D/16;
  int p0 = blockIdx.x*64;
  int b = blockIdx.z;
  int tid = threadIdx.x;
  int lane = tid & 63, w = tid >> 6;
  int d0 = blockIdx.y*64 + (w<<4);
  int dTile = blockIdx.y*4 + w;
  __shared__ __align__(16) ushort sX[64*64];
  for(int i=tid;i<512;i+=TPB){
    int row=i>>3, c8=(i&7)<<3;
    uint4 v = *(const uint4*)&XT[((size_t)b*NPa + p0 + row)*64 + c8];
    *(uint4*)&sX[row*64 + (c8 ^ ((row&7)<<3))] = v;
  }
  __syncthreads();
  int r15 = lane & 15, hi = lane >> 4;
  bf16x8 bf[4][2];
  #pragma unroll
  for(int pt=0;pt<4;pt++){
    int row = pt*16 + r15;
    int sw = (row&7)<<3;
    int cu0 = hi*8;
    bf[pt][0] = *(const bf16x8*)&sX[row*64 + (cu0 ^ sw)];
    bf[pt][1] = *(const bf16x8*)&sX[row*64 + ((cu0+32) ^ sw)];
  }
  f32x4 acc[4];
  #pragma unroll
  for(int pt=0;pt<4;pt++){ acc[pt][0]=0.f; acc[pt][1]=0.f; acc[pt][2]=0.f; acc[pt][3]=0.f; }
  const ushort* wqp = wqF + ((size_t)dTile*2)*512 + lane*8;
  const ushort* wvp = wvF + ((size_t)dTile*2)*512 + lane*8;
  for(int k=0;k<Kb;k++){
    bf16x8 aq0 = *(const bf16x8*)&wqp[0];
    bf16x8 aq1 = *(const bf16x8*)&wqp[512];
    bf16x8 av0 = *(const bf16x8*)&wvp[0];
    bf16x8 av1 = *(const bf16x8*)&wvp[512];
    wqp += (size_t)Dt*2*512; wvp += (size_t)Dt*2*512;
    #pragma unroll
    for(int pt=0;pt<4;pt++){
      f32x4 q; q[0]=0.f;q[1]=0.f;q[2]=0.f;q[3]=0.f;
      f32x4 v; v[0]=0.f;v[1]=0.f;v[2]=0.f;v[3]=0.f;
      q = __builtin_amdgcn_mfma_f32_16x16x32_bf16(aq0, bf[pt][0], q, 0,0,0);
      q = __builtin_amdgcn_mfma_f32_16x16x32_bf16(aq1, bf[pt][1], q, 0,0,0);
      v = __builtin_amdgcn_mfma_f32_16x16x32_bf16(av0, bf[pt][0], v, 0,0,0);
      v = __builtin_amdgcn_mfma_f32_16x16x32_bf16(av1, bf[pt][1], v, 0,0,0);
      #pragma unroll
      for(int i=0;i<4;i++) acc[pt][i] += v[i]*sigm(q[i]);
    }
  }
  #pragma unroll
  for(int pt=0;pt<4;pt++){
    int p = p0 + pt*16 + r15;
    if(p < NP){
      #pragma unroll
      for(int i=0;i<4;i++){
        int d = d0 + hi*4 + i;
        S[((size_t)b*D + d)*NP + p] = acc[pt][i];
      }
    }
  }
}

// ---------------- adjacency aggregation via MFMA (fused S transpose in; coalesced f32 out) ----------------
template<int RELU>
__global__ __launch_bounds__(TPB) void k_agg_mfma(const float* __restrict__ S, const ushort* __restrict__ adjF,
                                                  const float* __restrict__ bias, float* __restrict__ Out, int D){
  int d = blockIdx.x, b = blockIdx.y;
  int bd = b*D + d;
  constexpr int SST = 232;
  __shared__ __align__(16) ushort sB[64*SST];
  int tid = threadIdx.x;
  for(int i=tid*8; i<64*SST; i+=TPB*8){ uint4 z; z.x=0;z.y=0;z.z=0;z.w=0; *(uint4*)&sB[i]=z; }
  __syncthreads();
  const float* Sp = S + (size_t)bd*NP;
  for(int i=tid; i<NP; i+=TPB){
    int nn = i/52, l = i - nn*52;
    sB[l*SST + nn] = f2bf(Sp[i]);
  }
  __syncthreads();
  int lane = tid & 63, w = tid >> 6;
  int r15 = lane & 15, hi = lane >> 4;
  float bb = bias[d];
  float* Op = Out + (size_t)bd*NP;
  for(int k2t = w; k2t < 13; k2t += 4){
    f32x4 acc[4];
    #pragma unroll
    for(int lt=0;lt<4;lt++){ acc[lt][0]=0;acc[lt][1]=0;acc[lt][2]=0;acc[lt][3]=0; }
    #pragma unroll
    for(int ks=0; ks<7; ks++){
      bf16x8 a = *(const bf16x8*)&adjF[((size_t)(k2t*7 + ks))*512 + lane*8];
      #pragma unroll
      for(int lt=0;lt<4;lt++){
        bf16x8 bfr = *(const bf16x8*)&sB[(lt*16+r15)*SST + ks*32 + hi*8];
        acc[lt] = __builtin_amdgcn_mfma_f32_16x16x32_bf16(a, bfr, acc[lt], 0,0,0);
      }
    }
    #pragma unroll
    for(int lt=0;lt<4;lt++){
      #pragma unroll
      for(int i2=0;i2<4;i2++){
        int k2 = k2t*16 + hi*4 + i2;
        int l  = lt*16 + r15;
        if(k2 < Nn && l < LP){
          float v = acc[lt][i2] + bb;
          if(RELU) v = fmaxf(v, 0.f);
          Op[(size_t)k2*LP + l] = v;
        }
      }
    }
  }
}

// ---------------- MLP conv (dil=1) via MFMA, per layer; input RB f32 [b][128][NP] ----------------
template<int MODE>
__global__ __launch_bounds__(TPB) void k_mlpacc_mfma(const float* __restrict__ RB, const ushort* __restrict__ WF,
                                                     float* __restrict__ gacc, const float* __restrict__ bm,
                                                     float* __restrict__ gg){
  int n = blockIdx.x, b = blockIdx.y;
  constexpr int CS = 136;
  __shared__ __align__(16) ushort sLT[52*CS];
  int tid = threadIdx.x;
  for(int i=tid;i<6656;i+=TPB){
    int c = i/52, l = i%52;
    sLT[l*CS + c] = f2bf(RB[(((size_t)b*128+c)*Nn + n)*LP + l]);
  }
  __syncthreads();
  int lane = tid & 63, w = tid >> 6;
  int r15 = lane & 15, hi = lane >> 4;
  f32x4 acc0[3], acc1[3];
  #pragma unroll
  for(int tt=0;tt<3;tt++){
    acc0[tt][0]=0;acc0[tt][1]=0;acc0[tt][2]=0;acc0[tt][3]=0;
    acc1[tt][0]=0;acc1[tt][1]=0;acc1[tt][2]=0;acc1[tt][3]=0;
  }
  const ushort* wp0 = WF + ((size_t)w*12)*512 + lane*8;
  const ushort* wp1 = WF + ((size_t)(w+4)*12)*512 + lane*8;
  #pragma unroll 3
  for(int ks=0; ks<12; ks++){
    int kt = ks>>2, ci0 = (ks&3)*32 + hi*8;
    bf16x8 bw0 = *(const bf16x8*)&wp0[(size_t)ks*512];
    bf16x8 bw1 = *(const bf16x8*)&wp1[(size_t)ks*512];
    #pragma unroll
    for(int tt=0;tt<3;tt++){
      bf16x8 ax = *(const bf16x8*)&sLT[(tt*16 + r15 + kt)*CS + ci0];
      acc0[tt] = __builtin_amdgcn_mfma_f32_16x16x32_bf16(ax, bw0, acc0[tt], 0,0,0);
      acc1[tt] = __builtin_amdgcn_mfma_f32_16x16x32_bf16(ax, bw1, acc1[tt], 0,0,0);
    }
  }
  int o = w*16 + r15;
  if(MODE < 2){
    float* gp = gacc + ((size_t)b*Nn + n)*48*128;
    #pragma unroll
    for(int tt=0;tt<3;tt++){
      #pragma unroll
      for(int i2=0;i2<4;i2++){
        int tq = tt*16 + hi*4 + i2;
        size_t a0 = (size_t)tq*128 + o;
        if(MODE==0){ gp[a0] = acc0[tt][i2]; gp[a0+64] = acc1[tt][i2]; }
        else       { gp[a0] += acc0[tt][i2]; gp[a0+64] += acc1[tt][i2]; }
      }
    }
  } else {
    const float* gp = gacc + ((size_t)b*Nn + n)*48*128;
    float b0 = bm[o], b1 = bm[o+64];
    float* ggp = gg + (((size_t)b*Cc + o)*Nn + n)*(size_t)Tout;
    #pragma unroll
    for(int tt=0;tt<3;tt++){
      #pragma unroll
      for(int i2=0;i2<4;i2++){
        int tq = tt*16 + hi*4 + i2;
        size_t a0 = (size_t)tq*128 + o;
        float a  = gp[a0]    + acc0[tt][i2] + b0;
        float g2 = gp[a0+64] + acc1[tt][i2] + b1;
        ggp[tq] = tanhf(a)*sigm(g2);
      }
    }
  }
}

// ---------------- patch scramble + emb ----------------
__global__ __launch_bounds__(TPB) void k_xe(const float* __restrict__ gg, const float* __restrict__ emb, float* __restrict__ xe){
  size_t i = (size_t)blockIdx.x*TPB + threadIdx.x;
  if(i >= (size_t)Bx*1271808) return;
  int b = (int)(i / 1271808);
  int off = (int)(i % 1271808);
  int c = off / 19872; int r = off % 19872;
  int n = r / 96; int r2 = r % 96;
  int p = r2 >> 3; int j = r2 & 7;
  int t = p*4 + j;
  float v = 0.f;
  if(t < Tout) v = gg[(((size_t)b*Cc+c)*Nn + n)*Tout + t];
  int e = off & 511; int p2 = (off >> 9) % 12;
  xe[i] = v + emb[(size_t)p2*Ee + e];
}

// ---------------- per-row LN helper (rows of 512, stride SRDF, in LDS); NW waves ----------------
template<int NW>
__device__ __forceinline__ void ln_rows(float* buf, const float* __restrict__ g, const float* __restrict__ be, int tid){
  int lane = tid & 63, wv = tid >> 6;
  for(int r = wv; r < 12; r += NW){
    float s=0.f, s2=0.f;
    #pragma unroll
    for(int j=0;j<8;j++){ float v = buf[r*SRDF + j*64 + lane]; s+=v; s2+=v*v; }
    #pragma unroll
    for(int off=32; off; off>>=1){ s += __shfl_xor(s,off); s2 += __shfl_xor(s2,off); }
    float m = s*(1.f/512.f);
    float rstd = rsqrtf(fmaxf(s2*(1.f/512.f)-m*m, 0.f)+EPSF);
    #pragma unroll
    for(int j=0;j<8;j++){ int e = j*64+lane; float v = buf[r*SRDF+e];
      buf[r*SRDF+e] = (v-m)*rstd*g[e] + be[e]; }
  }
}

// ---------------- fused per-(b,n) transformer, MFMA GEMM phases; 512 threads (8 waves) ----------------
__global__ __launch_bounds__(TPA,2) void k_attn(
    const float* __restrict__ xe, const float* __restrict__ resid,
    const ushort* __restrict__ WqF, const float* __restrict__ bq,
    const ushort* __restrict__ WkF, const float* __restrict__ bk,
    const ushort* __restrict__ WvF, const float* __restrict__ bv,
    const ushort* __restrict__ WfcF, const float* __restrict__ bfc,
    const float* __restrict__ g1, const float* __restrict__ b1n,
    const float* __restrict__ g2, const float* __restrict__ b2n,
    const ushort* __restrict__ Wff1F, const float* __restrict__ bff1,
    const ushort* __restrict__ Wff2F, const float* __restrict__ bff2,
    const float* __restrict__ Wrp, const float* __restrict__ brp,
    float* __restrict__ y)
{
  int n = blockIdx.x, b = blockIdx.y;
  __shared__ __align__(16) ushort SbX[16*512];
  __shared__ __align__(16) ushort Mb[16*256];
  __shared__ __align__(16) float U0[12*SRDF];
  __shared__ __align__(16) float U1[12*SRDF];
  __shared__ __align__(16) float sS[1160];
  int tid = threadIdx.x;
  int lane = tid & 63, w = tid >> 6;          // w in [0,8)
  int r15 = lane & 15, hi = lane >> 4;
  const float* __restrict__ xeg = xe + ((size_t)b*Nn + n)*6144;

  for(int i=tid;i<1024;i+=TPA){
    int r = i>>6, ch = i&63;
    ushort u[8];
    if(r<12){
      const float* s = &xeg[r*512 + ch*8];
      #pragma unroll
      for(int j=0;j<8;j++) u[j] = f2bf(s[j]);
    } else {
      #pragma unroll
      for(int j=0;j<8;j++) u[j] = 0;
    }
    *(uint4*)&SbX[r*512 + ((ch ^ (r&7))<<3)] = *(uint4*)u;
  }
  for(int i=tid;i<128;i+=TPA){
    int r = 12 + (i>>5), ch = i&31;
    uint4 z; z.x=0;z.y=0;z.z=0;z.w=0;
    *(uint4*)&Mb[r*256 + ch*8] = z;
  }
  __syncthreads();

  // QKV: one head per wave
  f32x4 vfrag[4];
  {
    int head = w;
    bf16x8 a0, a1;
    { int ch0 = head*8 + hi, ch1 = head*8 + 4 + hi;
      a0 = *(const bf16x8*)&SbX[r15*512 + ((ch0 ^ (r15&7))<<3)];
      a1 = *(const bf16x8*)&SbX[r15*512 + ((ch1 ^ (r15&7))<<3)]; }
    #pragma unroll
    for(int nt=0;nt<4;nt++){
      int col = nt*16 + r15;
      float bb = bq[col];
      f32x4 acc; acc[0]=bb;acc[1]=bb;acc[2]=bb;acc[3]=bb;
      acc = __builtin_amdgcn_mfma_f32_16x16x32_bf16(a0, *(const bf16x8*)&WqF[(size_t)(nt*2+0)*512 + lane*8], acc, 0,0,0);
      acc = __builtin_amdgcn_mfma_f32_16x16x32_bf16(a1, *(const bf16x8*)&WqF[(size_t)(nt*2+1)*512 + lane*8], acc, 0,0,0);
      #pragma unroll
      for(int i2=0;i2<4;i2++){ int p = hi*4+i2; if(p<12) U0[p*SRDF + head*64 + col] = acc[i2]; }
    }
    #pragma unroll
    for(int nt=0;nt<4;nt++){
      int col = nt*16 + r15;
      float bb = bk[col];
      f32x4 acc; acc[0]=bb;acc[1]=bb;acc[2]=bb;acc[3]=bb;
      acc = __builtin_amdgcn_mfma_f32_16x16x32_bf16(a0, *(const bf16x8*)&WkF[(size_t)(nt*2+0)*512 + lane*8], acc, 0,0,0);
      acc = __builtin_amdgcn_mfma_f32_16x16x32_bf16(a1, *(const bf16x8*)&WkF[(size_t)(nt*2+1)*512 + lane*8], acc, 0,0,0);
      #pragma unroll
      for(int i2=0;i2<4;i2++){ int p = hi*4+i2; if(p<12) U1[p*SRDF + head*64 + col] = acc[i2]; }
    }
    #pragma unroll
    for(int nt=0;nt<4;nt++){
      int col = nt*16 + r15;
      float bb = bv[col];
      f32x4 acc; acc[0]=bb;acc[1]=bb;acc[2]=bb;acc[3]=bb;
      acc = __builtin_amdgcn_mfma_f32_16x16x32_bf16(a0, *(const bf16x8*)&WvF[(size_t)(nt*2+0)*512 + lane*8], acc, 0,0,0);
      acc = __builtin_amdgcn_mfma_f32_16x16x32_bf16(a1, *(const bf16x8*)&WvF[(size_t)(nt*2+1)*512 + lane*8], acc, 0,0,0);
      vfrag[nt] = acc;
    }
  }
  __syncthreads();

  const float scale = 0.04419417382415922f;   // 1/sqrt(512)
  for(int i=tid;i<1152;i+=TPA){
    int q = i%12, kh = i/12; int h2 = kh&7, k2 = kh>>3;
    const float* qp = &U0[q*SRDF + h2*64];
    const float* kp = &U1[k2*SRDF + h2*64];
    float s=0.f;
    #pragma unroll
    for(int d4=0; d4<16; d4++){
      float4 a4 = *(const float4*)&qp[d4*4];
      float4 b4 = *(const float4*)&kp[d4*4];
      s += a4.x*b4.x + a4.y*b4.y + a4.z*b4.z + a4.w*b4.w;
    }
    sS[i] = s*scale;
  }
  __syncthreads();
  {
    int head = w;
    #pragma unroll
    for(int nt=0;nt<4;nt++){
      int col = nt*16 + r15;
      #pragma unroll
      for(int i2=0;i2<4;i2++){ int p = hi*4+i2; if(p<12) U0[p*SRDF + head*64 + col] = vfrag[nt][i2]; }
    }
  }
  if(tid<96){
    float mx=-1e30f;
    for(int q=0;q<12;q++) mx = fmaxf(mx, sS[tid*12+q]);
    float sm=0.f;
    for(int q=0;q<12;q++){ float e = __expf(sS[tid*12+q]-mx); sS[tid*12+q]=e; sm+=e; }
    float inv = 1.f/sm;
    for(int q=0;q<12;q++) sS[tid*12+q] *= inv;
  }
  __syncthreads();

  for(int i=tid;i<6144;i+=TPA){
    int q=i>>9, h2=(i>>6)&7, d=i&63;
    float s=0.f;
    #pragma unroll
    for(int k2=0;k2<12;k2++) s += sS[(k2*8+h2)*12+q]*U0[k2*SRDF+h2*64+d];
    int kk = i & 511;
    SbX[q*512 + (((kk>>3) ^ (q&7))<<3) + (kk&7)] = f2bf(s);
  }
  __syncthreads();

  // fc: 32 col-tiles, 4 per wave
  {
    f32x4 acc[4];
    #pragma unroll
    for(int nt=0;nt<4;nt++){ float bb = bfc[(w*4+nt)*16 + r15]; acc[nt][0]=bb;acc[nt][1]=bb;acc[nt][2]=bb;acc[nt][3]=bb; }
    for(int ks=0;ks<16;ks++){
      int ch = ks*4 + hi;
      bf16x8 a = *(const bf16x8*)&SbX[r15*512 + ((ch ^ (r15&7))<<3)];
      #pragma unroll
      for(int nt=0;nt<4;nt++){
        acc[nt] = __builtin_amdgcn_mfma_f32_16x16x32_bf16(a, *(const bf16x8*)&WfcF[(size_t)((w*4+nt)*16 + ks)*512 + lane*8], acc[nt], 0,0,0);
      }
    }
    #pragma unroll
    for(int nt=0;nt<4;nt++){
      int col = (w*4+nt)*16 + r15;
      #pragma unroll
      for(int i2=0;i2<4;i2++){ int p = hi*4+i2; if(p<12) U1[p*SRDF + col] = acc[nt][i2] + xeg[p*512 + col]; }
    }
  }
  __syncthreads();
  ln_rows<8>(U1, g1, b1n, tid);     // M in U1
  __syncthreads();

  for(int i=tid;i<6144;i+=TPA){
    int r=i>>9, kk=i&511;
    SbX[r*512 + (((kk>>3) ^ (r&7))<<3) + (kk&7)] = f2bf(U1[r*SRDF + kk]);
  }
  __syncthreads();

  // ff1: 16 col-tiles, 2 per wave
  {
    f32x4 acc[2];
    #pragma unroll
    for(int nt=0;nt<2;nt++){ float bb = bff1[(w*2+nt)*16 + r15]; acc[nt][0]=bb;acc[nt][1]=bb;acc[nt][2]=bb;acc[nt][3]=bb; }
    for(int ks=0;ks<16;ks++){
      int ch = ks*4 + hi;
      bf16x8 a = *(const bf16x8*)&SbX[r15*512 + ((ch ^ (r15&7))<<3)];
      #pragma unroll
      for(int nt=0;nt<2;nt++){
        acc[nt] = __builtin_amdgcn_mfma_f32_16x16x32_bf16(a, *(const bf16x8*)&Wff1F[(size_t)((w*2+nt)*16 + ks)*512 + lane*8], acc[nt], 0,0,0);
      }
    }
    #pragma unroll
    for(int nt=0;nt<2;nt++){
      int u = (w*2+nt)*16 + r15;
      #pragma unroll
      for(int i2=0;i2<4;i2++){
        int p = hi*4+i2;
        if(p<12) Mb[p*256 + (((u>>3) ^ (p&7))<<3) + (u&7)] = f2bf(fmaxf(acc[nt][i2], 0.f));
      }
    }
  }
  __syncthreads();

  // ff2: 32 col-tiles, 4 per wave
  {
    f32x4 acc[4];
    #pragma unroll
    for(int nt=0;nt<4;nt++){ float bb = bff2[(w*4+nt)*16 + r15]; acc[nt][0]=bb;acc[nt][1]=bb;acc[nt][2]=bb;acc[nt][3]=bb; }
    for(int ks=0;ks<8;ks++){
      int ch = ks*4 + hi;
      bf16x8 a = *(const bf16x8*)&Mb[r15*256 + ((ch ^ (r15&7))<<3)];
      #pragma unroll
      for(int nt=0;nt<4;nt++){
        acc[nt] = __builtin_amdgcn_mfma_f32_16x16x32_bf16(a, *(const bf16x8*)&Wff2F[(size_t)((w*4+nt)*8 + ks)*512 + lane*8], acc[nt], 0,0,0);
      }
    }
    #pragma unroll
    for(int nt=0;nt<4;nt++){
      int col = (w*4+nt)*16 + r15;
      #pragma unroll
      for(int i2=0;i2<4;i2++){ int p = hi*4+i2; if(p<12) U0[p*SRDF + col] = acc[nt][i2] + U1[p*SRDF + col]; }
    }
  }
  __syncthreads();
  ln_rows<8>(U0, g2, b2n, tid);     // U in U0
  __syncthreads();

  for(int i=tid;i<6144;i+=TPA){
    int r=i>>9, c=i&511;
    U1[r*SRDF+c] = U0[r*SRDF+c] + U1[r*SRDF+c] + xeg[r*512+c];
  }
  __syncthreads();
  for(int i=tid;i<4608;i+=TPA) U0[i] = Wrp[i];
  __syncthreads();
  #pragma unroll
  for(int j=0;j<2;j++){
    int i4 = tid + j*TPA;
    if(i4 < 768){
      int c = i4/12, tq = i4%12; int t0 = tq*4;
      float4 acc = *(const float4*)&brp[t0];
      for(int t96=0;t96<96;t96++){
        int f = c*96 + t96;
        float a = U1[(f>>9)*SRDF + (f&511)];
        float4 w4 = *(const float4*)&U0[t96*48 + t0];
        FMA4(acc, a, w4);
      }
      size_t rb = (((size_t)b*Cc+c)*Nn + n)*Tin + 6 + t0;
      acc.x += resid[rb+0]; acc.y += resid[rb+1]; acc.z += resid[rb+2]; acc.w += resid[rb+3];
      *(float4*)&y[(((size_t)b*Cc+c)*Nn + n)*Tout + t0] = acc;
    }
  }
}

// ---------------- batchnorm ----------------
__global__ __launch_bounds__(TPB) void k_bnstats(const float* __restrict__ y, float* __restrict__ stats){
  int c = blockIdx.x; int tid = threadIdx.x;
  float s=0.f,s2=0.f;
  const int per = Nn*Tout;   // 9936
  for(int idx=tid; idx<Bx*per; idx+=TPB){
    int b = idx/per, r = idx%per;
    float v = y[((size_t)b*Cc+c)*per + r];
    s+=v; s2+=v*v;
  }
  __shared__ float rs[TPB], rs2[TPB];
  rs[tid]=s; rs2[tid]=s2; __syncthreads();
  for(int off=TPB/2; off; off>>=1){ if(tid<off){ rs[tid]+=rs[tid+off]; rs2[tid]+=rs2[tid+off]; } __syncthreads(); }
  if(tid==0){
    float m = rs[0]/(float)(Bx*per);
    float var = rs2[0]/(float)(Bx*per) - m*m;
    stats[c]=m; stats[64+c]=rsqrtf(fmaxf(var,0.f)+EPSF);
  }
}
__global__ __launch_bounds__(TPB) void k_bnout(const float* __restrict__ y, const float* __restrict__ stats,
                                               const float* __restrict__ gbn, const float* __restrict__ bbn,
                                               float* __restrict__ out){
  size_t i = (size_t)blockIdx.x*TPB + threadIdx.x;
  if(i >= (size_t)Bx*Cc*Nn*Tout) return;
  int c = (int)((i/(Nn*Tout))%Cc);
  out[i] = (y[i]-stats[c])*stats[64+c]*gbn[c] + bbn[c];
}

// ---------------- launch ----------------
extern "C" void kernel_launch(void* const* d_in, const int* in_sizes, int n_in,
                              void* d_out, int out_size, void* d_ws, size_t ws_size,
                              hipStream_t stream) {
  const float* x      = (const float*)d_in[0];
  const float* adj    = (const float*)d_in[1];
  const float* Wconv1 = (const float*)d_in[2];
  const float* bconv1 = (const float*)d_in[3];
  const float* gT     = (const float*)d_in[4];
  const float* bT     = (const float*)d_in[5];
  const float* gS     = (const float*)d_in[6];
  const float* bS     = (const float*)d_in[7];
  const float* Wtime  = (const float*)d_in[8];
  const float* btime  = (const float*)d_in[9];
  const float* wq1    = (const float*)d_in[10];
  const float* wv1    = (const float*)d_in[11];
  const float* bias1  = (const float*)d_in[12];
  const float* wq2    = (const float*)d_in[13];
  const float* wv2    = (const float*)d_in[14];
  const float* bias2  = (const float*)d_in[15];
  const float* Wmlp   = (const float*)d_in[16];
  const float* bmlp   = (const float*)d_in[17];
  const float* embT   = (const float*)d_in[18];
  const float* Wq     = (const float*)d_in[19];
  const float* bq     = (const float*)d_in[20];
  const float* Wk     = (const float*)d_in[21];
  const float* bk     = (const float*)d_in[22];
  const float* Wv     = (const float*)d_in[23];
  const float* bv     = (const float*)d_in[24];
  const float* Wfc    = (const float*)d_in[25];
  const float* bfc    = (const float*)d_in[26];
  const float* g1     = (const float*)d_in[27];
  const float* b1n    = (const float*)d_in[28];
  const float* g2     = (const float*)d_in[29];
  const float* b2n    = (const float*)d_in[30];
  const float* Wff1   = (const float*)d_in[31];
  const float* bff1   = (const float*)d_in[32];
  const float* Wff2   = (const float*)d_in[33];
  const float* bff2   = (const float*)d_in[34];
  const float* Wrp    = (const float*)d_in[35];
  const float* brp    = (const float*)d_in[36];
  const float* gbn    = (const float*)d_in[37];
  const float* bbn    = (const float*)d_in[38];

  float* ws = (float*)d_ws;
  float* RESID = ws + O_RESID;
  float* LNTM  = ws + O_LNTM;
  float* LNTR  = ws + O_LNTR;
  float* LNSM  = ws + O_LNSM;
  float* LNSR  = ws + O_LNSR;
  float* RA    = ws + O_XCAT;
  float* RB    = ws + O_RB;
  float* GACC  = ws + O_GACC;
  float* GG    = ws + O_GG;
  float* Y     = ws + O_GG;      // overlays GG (safe: GG dead after k_xe builds XE)
  float* XE    = ws + O_XE;
  float* BNST  = ws + O_BNST;
  ushort* WTMF = (ushort*)(ws + O_WTM);
  ushort* WTB  = (ushort*)(ws + O_WTB);
  ushort* ADJT = (ushort*)(ws + O_ADJT);
  ushort* HT   = (ushort*)(ws + O_HT);   // in dead H region
  ushort* WQ1B = (ushort*)(ws + O_WQ1B);
  ushort* WV1B = (ushort*)(ws + O_WV1B);
  ushort* WQ2B = (ushort*)(ws + O_WQ2B);
  ushort* WV2B = (ushort*)(ws + O_WV2B);
  ushort* RBT  = (ushort*)(ws + O_RBT);
  ushort* WQT  = (ushort*)(ws + O_WQT);
  ushort* WKT  = (ushort*)(ws + O_WKT);
  ushort* WVT  = (ushort*)(ws + O_WVT);
  ushort* WFCT = (ushort*)(ws + O_WFCT);
  ushort* WF1T = (ushort*)(ws + O_WF1T);
  ushort* WF2T = (ushort*)(ws + O_WF2T);

  k_residual<<<dim3(Nn,Bx),TPB,0,stream>>>(x, Wconv1, bconv1, RESID, LNTM, LNTR);
  k_lnS<<<(Bx*Cc*Tin)/TPB,TPB,0,stream>>>(RESID, LNSM, LNSR);
  k_wtbF<<<(8*18*512+TPB-1)/TPB,TPB,0,stream>>>(Wtime, WTB);
  k_wmlpF<<<(3*8*12*512+TPB-1)/TPB,TPB,0,stream>>>(Wmlp, WTMF);
  k_htpad<<<(Bx*(NPa-NP)*8+TPB-1)/TPB,TPB,0,stream>>>(HT);
  // fused xcat + timeconv (reads RESID + LN stats directly)
  k_timeconv_mfma<<<dim3(Nn,Bx),TPB,0,stream>>>(RESID, LNTM, LNTR, LNSM, LNSR, gT, bT, gS, bS,
                                                WTB, btime, HT);

  // merged fragment-order weight converts (11 jobs, one dispatch)
  WJobs jobs;
  jobs.j[0]  = { wq1,  WQ1B, 64,  64,  2,  4,  64*64,   24*4*2*512 };
  jobs.j[1]  = { wv1,  WV1B, 64,  64,  2,  4,  64*64,   24*4*2*512 };
  jobs.j[2]  = { wq2,  WQ2B, 64,  128, 2,  8,  64*128,  24*8*2*512 };
  jobs.j[3]  = { wv2,  WV2B, 64,  128, 2,  8,  64*128,  24*8*2*512 };
  jobs.j[4]  = { Wq,   WQT,  64,  64,  2,  4,  64*64,   4*2*512 };
  jobs.j[5]  = { Wk,   WKT,  64,  64,  2,  4,  64*64,   4*2*512 };
  jobs.j[6]  = { Wv,   WVT,  64,  64,  2,  4,  64*64,   4*2*512 };
  jobs.j[7]  = { Wfc,  WFCT, 512, 512, 16, 32, 512*512, 32*16*512 };
  jobs.j[8]  = { Wff1, WF1T, 512, 256, 16, 16, 512*256, 16*16*512 };
  jobs.j[9]  = { Wff2, WF2T, 256, 512, 8,  32, 256*512, 32*8*512 };
  jobs.j[10] = { adj,  ADJT, 207, 207, 7,  13, Nn*Nn,   3*13*7*512 };
  int totalW = 2*(24*4*2*512) + 2*(24*8*2*512) + 3*(4*2*512) + 32*16*512 + 16*16*512 + 32*8*512 + 3*13*7*512;
  k_wfrag_all<<<(totalW+TPB-1)/TPB,TPB,0,stream>>>(jobs);

  for(int i=0;i<3;i++){
    k_gcs_mfma<64><<<dim3(169,1,Bx),TPB,0,stream>>>(HT, WQ1B+(size_t)i*8*4*2*512, WV1B+(size_t)i*8*4*2*512, RA);
    k_agg_mfma<1><<<dim3(64,Bx),TPB,0,stream>>>(RA, ADJT+(size_t)i*13*7*512, bias1+(size_t)i*64, RB, 64);
    k_t2bf<64><<<dim3(169,Bx),TPB,0,stream>>>(RB, RBT);
    k_gcs_mfma<128><<<dim3(169,2,Bx),TPB,0,stream>>>(RBT, WQ2B+(size_t)i*8*8*2*512, WV2B+(size_t)i*8*8*2*512, RA);
    k_agg_mfma<0><<<dim3(128,Bx),TPB,0,stream>>>(RA, ADJT+(size_t)i*13*7*512, bias2+(size_t)i*128, RB, 128);
    if(i==0)      k_mlpacc_mfma<0><<<dim3(Nn,Bx),TPB,0,stream>>>(RB, WTMF+(size_t)i*8*12*512, GACC, bmlp, GG);
    else if(i==1) k_mlpacc_mfma<1><<<dim3(Nn,Bx),TPB,0,stream>>>(RB, WTMF+(size_t)i*8*12*512, GACC, bmlp, GG);
    else          k_mlpacc_mfma<2><<<dim3(Nn,Bx),TPB,0,stream>>>(RB, WTMF+(size_t)i*8*12*512, GACC, bmlp, GG);
  }
  k_xe<<<(Bx*1271808)/TPB,TPB,0,stream>>>(GG, embT, XE);
  k_attn<<<dim3(Nn,Bx),TPA,0,stream>>>(XE, RESID, WQT,bq, WKT,bk, WVT,bv, WFCT,bfc,
                                       g1,b1n,g2,b2n, WF1T,bff1, WF2T,bff2, Wrp,brp, Y);
  k_bnstats<<<64,TPB,0,stream>>>(Y, BNST);
  k_bnout<<<(Bx*Cc*Nn*Tout)/TPB,TPB,0,stream>>>(Y, BNST, gbn, bbn, (float*)d_out);
}

// Round 22
// 893.179 us; speedup vs baseline: 1.0628x; 1.0092x over previous
//
#include <hip/hip_runtime.h>
#include <hip/hip_bf16.h>

#define TPB 256
#define TPA 512

constexpr int Bx = 8, Cc = 64, Nn = 207, Tin = 54, Kb = 8;
constexpr int LP = 52, NP = Nn * LP;     // time padded 50->52, flattened node*time positions
constexpr int NPa = 10816;               // NP rounded up to 169*64 for MFMA tiles
constexpr int L50 = 50, Tout = 48;
constexpr int Ee = 512, Pn = 12;
constexpr float EPSF = 1e-5f;
constexpr int SRDF = 516;                // padded row stride for 512-wide f32 LDS rows (2-way bank pattern)

// ---------------- workspace layout (floats) ----------------
constexpr size_t O_RESID = 0;                                   // [B][64][207][54]
constexpr size_t O_LNTM  = O_RESID + (size_t)Bx*Cc*Nn*Tin;
constexpr size_t O_LNTR  = O_LNTM  + (size_t)Bx*Cc*Nn;
constexpr size_t O_LNSM  = O_LNTR  + (size_t)Bx*Cc*Nn;
constexpr size_t O_LNSR  = O_LNSM  + (size_t)Bx*Cc*Tin;
constexpr size_t O_XCAT  = O_LNSR  + (size_t)Bx*Cc*Tin;         // scratch region: RA f32 + bf16 tail
constexpr size_t O_RB    = O_XCAT  + (size_t)Bx*192*Nn*Tin;     // f32 [B][128][NP] agg outputs
constexpr size_t O_H     = O_RB    + (size_t)Bx*128*NP;         // HT bf16 [Bx][NPa][64]
constexpr size_t O_GACC  = O_H     + (size_t)Bx*64*NP;          // [B][n][48][128] (relaid out)
constexpr size_t O_GG    = O_GACC  + (size_t)Bx*128*Nn*Tout;    // [B][64][207][48]; reused as Y after xe built
constexpr size_t O_XE    = O_GG    + (size_t)Bx*64*Nn*Tout;     // [B][207][12][512]
constexpr size_t O_WTT   = O_XE    + (size_t)Bx*Nn*Pn*Ee;       // (unused) 128*192*3
constexpr size_t O_WTM   = O_WTT   + (size_t)128*192*3;         // ushort[3*8*12*512] W_mlp frag bf16
constexpr size_t O_BNST  = O_WTM   + (size_t)128*384*3;         // 128
constexpr size_t O_WTB   = O_BNST + 128;                        // ushort[8*18*512] time-conv bf16 frag weights
constexpr size_t O_ADJT  = O_WTB  + (size_t)128*576/2;          // ushort[3][13*7*512] adj frag bf16
constexpr size_t O_HT    = O_H;                                 // ushort[Bx][NPa][64] in dead H region
constexpr size_t O_TAIL  = O_XCAT + (size_t)Bx*128*NP;          // tail anchor (after RA region)
constexpr size_t O_WQ1B  = O_TAIL + (size_t)Bx*NPa*64/2;        // ushort[24*4*2*512]
constexpr size_t O_WV1B  = O_WQ1B + (size_t)24*64*64/2;
constexpr size_t O_WQ2B  = O_WV1B + (size_t)24*64*64/2;         // ushort[24*8*2*512]
constexpr size_t O_WV2B  = O_WQ2B + (size_t)24*128*64/2;
constexpr size_t O_RBT   = O_WV2B + (size_t)24*128*64/2;        // (unused now — t2bf/RBT eliminated)
constexpr size_t O_WQT   = O_RBT  + (size_t)Bx*NPa*64/2;        // ushort[4*2*512]
constexpr size_t O_WKT   = O_WQT  + 2048;
constexpr size_t O_WVT   = O_WKT  + 2048;
constexpr size_t O_WFCT  = O_WVT  + 2048;                       // ushort[32*16*512]
constexpr size_t O_WF1T  = O_WFCT + 131072;                     // ushort[16*16*512]
constexpr size_t O_WF2T  = O_WF1T + 65536;                      // ushort[32*8*512]

#define FMA4(acc, sA_, vB_) { (acc).x += (sA_)*(vB_).x; (acc).y += (sA_)*(vB_).y; (acc).z += (sA_)*(vB_).z; (acc).w += (sA_)*(vB_).w; }

typedef __attribute__((ext_vector_type(8))) short bf16x8;
typedef __attribute__((ext_vector_type(4))) float f32x4;

__device__ __forceinline__ float sigm(float x){ return 1.0f/(1.0f+__expf(-x)); }
__device__ __forceinline__ ushort f2bf(float x){ __hip_bfloat16 h = __float2bfloat16(x); return *(ushort*)&h; }

// ---------------- residual = W_conv1 @ x + b, fused lnT stats ----------------
__global__ __launch_bounds__(TPB) void k_residual(const float* __restrict__ x, const float* __restrict__ W,
                                                  const float* __restrict__ bias, float* __restrict__ out,
                                                  float* __restrict__ lnm, float* __restrict__ lnr){
  int n = blockIdx.x, b = blockIdx.y;
  __shared__ __align__(16) float sX[Cc][Tin];
  __shared__ __align__(16) float sW[Cc*Cc];
  __shared__ __align__(16) float sO[Cc][Tin];
  int tid = threadIdx.x;
  for(int i=tid;i<Cc*Tin;i+=TPB){ int c=i/Tin, l=i%Tin; sX[c][l] = x[((size_t)(b*Cc+c)*Nn+n)*Tin+l]; }
  for(int i=tid;i<Cc*Cc;i+=TPB) sW[i]=W[i];
  __syncthreads();
  for(int i=tid;i<Cc*Tin;i+=TPB){
    int o=i/Tin, l=i%Tin; float acc=bias[o];
    #pragma unroll 8
    for(int c=0;c<Cc;c++) acc += sW[o*Cc+c]*sX[c][l];
    out[((size_t)(b*Cc+o)*Nn+n)*Tin+l]=acc;
    sO[o][l]=acc;
  }
  __syncthreads();
  if(tid < Cc){
    float s=0.f,s2=0.f;
    for(int l=0;l<Tin;l++){ float v=sO[tid][l]; s+=v; s2+=v*v; }
    float m=s*(1.f/Tin); float var=s2*(1.f/Tin)-m*m;
    int row = (b*Cc+tid)*Nn + n;
    lnm[row]=m; lnr[row]=rsqrtf(fmaxf(var,0.f)+EPSF);
  }
}

// ---------------- lnS stats ----------------
__global__ __launch_bounds__(TPB) void k_lnS(const float* __restrict__ r, float* __restrict__ mean, float* __restrict__ rstd){
  int row = blockIdx.x*TPB + threadIdx.x;       // (b*Cc+c)*Tin + l
  if(row >= Bx*Cc*Tin) return;
  int l = row % Tin; int bc = row / Tin;
  const float* p = r + (size_t)bc*Nn*Tin + l;
  float s=0.f,s2=0.f;
  for(int n=0;n<Nn;n++){ float v=p[(size_t)n*Tin]; s+=v; s2+=v*v; }
  float m=s*(1.f/Nn); float var=s2*(1.f/Nn)-m*m;
  mean[row]=m; rstd[row]=rsqrtf(fmaxf(var,0.f)+EPSF);
}

// ---------------- merged fragment-order weight converter (10 jobs + adj) ----------------
struct WJob { const float* W; ushort* F; int K, N, KS, NT, sStride, total; };
struct WJobs { WJob j[11]; };

__global__ __launch_bounds__(TPB) void k_wfrag_all(WJobs jobs){
  int gi = blockIdx.x*TPB + threadIdx.x;
  for(int seg=0; seg<11; seg++){
    const WJob J = jobs.j[seg];
    if(gi < J.total){
      int i = gi;
      int j = i & 7; int lane = (i>>3) & 63;
      int t = i >> 9;
      int ks = t % J.KS; int r = t / J.KS; int colTile = r % J.NT; int s = r / J.NT;
      int r15 = lane & 15, hi = lane >> 4;
      int k = ks*32 + hi*8 + j, col = colTile*16 + r15;
      float v = (k < J.K && col < J.N) ? J.W[(size_t)s*J.sStride + (size_t)k*J.N + col] : 0.f;
      J.F[i] = f2bf(v);
      return;
    }
    gi -= J.total;
  }
}

// ---------------- time-conv weight frag convert ----------------
__global__ __launch_bounds__(TPB) void k_wtbF(const float* __restrict__ W, ushort* __restrict__ F){
  int i = blockIdx.x*TPB + threadIdx.x;
  if(i >= 8*18*512) return;
  int j = i & 7; int lane = (i>>3) & 63;
  int t = i >> 9;
  int ks = t % 18; int colTile = t / 18;
  int r15 = lane & 15, hi = lane >> 4;
  int k = ks*32 + hi*8 + j, o = colTile*16 + r15;
  int kt = k/192, ci = k - kt*192;
  F[i] = f2bf(W[(size_t)(o*192+ci)*3 + kt]);
}

// ---------------- mlp-conv weight frag convert ----------------
__global__ __launch_bounds__(TPB) void k_wmlpF(const float* __restrict__ W, ushort* __restrict__ F){
  int i = blockIdx.x*TPB + threadIdx.x;
  if(i >= 3*8*12*512) return;
  int j = i & 7; int lane = (i>>3) & 63;
  int t = i >> 9;
  int ks = t % 12; int r = t / 12; int colTile = r & 7; int layer = r >> 3;
  int r15 = lane & 15, hi = lane >> 4;
  int k = ks*32 + hi*8 + j;
  int kt = k >> 7, ci = k & 127;
  int o = colTile*16 + r15;
  F[i] = f2bf(W[(size_t)(o*384 + layer*128 + ci)*3 + kt]);
}

// ---------------- fused xcat+dilated time conv (dil=2) + GLU via MFMA -> HT bf16 [b][p][64] ----------------
__global__ __launch_bounds__(TPB) void k_timeconv_mfma(const float* __restrict__ resid,
    const float* __restrict__ tm, const float* __restrict__ tr,
    const float* __restrict__ sm, const float* __restrict__ sr,
    const float* __restrict__ gT, const float* __restrict__ bT,
    const float* __restrict__ gS, const float* __restrict__ bS,
    const ushort* __restrict__ WF, const float* __restrict__ bias, ushort* __restrict__ HT){
  int n = blockIdx.x, b = blockIdx.y;
  constexpr int XS = 200;
  __shared__ __align__(16) ushort sXT[68*XS];
  int tid = threadIdx.x;
  for(int i=tid; i<14*XS; i+=TPB) sXT[54*XS + i] = 0;
  float gSn = gS[n], bSn = bS[n];
  for(int i=tid; i<64*54; i+=TPB){
    int cm = i/54, l = i%54;
    int rowT = (b*Cc+cm)*Nn + n;
    float r = resid[(size_t)rowT*Tin + l];
    float v1 = (r - tm[rowT]) * tr[rowT] * gT[l] + bT[l];
    int rowS = (b*Cc+cm)*Tin + l;
    float v2 = (r - sm[rowS]) * sr[rowS] * gSn + bSn;
    sXT[l*XS + cm]        = f2bf(r);
    sXT[l*XS + 64 + cm]   = f2bf(v1);
    sXT[l*XS + 128 + cm]  = f2bf(v2);
  }
  __syncthreads();
  int lane = tid & 63, w = tid >> 6;
  int r15 = lane & 15, hi = lane >> 4;
  float b0 = bias[w*16 + r15], b1 = bias[w*16 + 64 + r15];
  f32x4 acc0[4], acc1[4];
  #pragma unroll
  for(int tt=0;tt<4;tt++){
    acc0[tt][0]=b0; acc0[tt][1]=b0; acc0[tt][2]=b0; acc0[tt][3]=b0;
    acc1[tt][0]=b1; acc1[tt][1]=b1; acc1[tt][2]=b1; acc1[tt][3]=b1;
  }
  const ushort* wp0 = WF + ((size_t)w*18)*512 + lane*8;
  const ushort* wp1 = WF + ((size_t)(w+4)*18)*512 + lane*8;
  #pragma unroll 2
  for(int ks=0; ks<18; ks++){
    int k0 = ks*32 + hi*8;
    int kt = k0/192, ci0 = k0 - kt*192;
    bf16x8 bw0 = *(const bf16x8*)&wp0[(size_t)ks*512];
    bf16x8 bw1 = *(const bf16x8*)&wp1[(size_t)ks*512];
    #pragma unroll
    for(int tt=0;tt<4;tt++){
      bf16x8 ax = *(const bf16x8*)&sXT[(tt*16 + r15 + 2*kt)*XS + ci0];
      acc0[tt] = __builtin_amdgcn_mfma_f32_16x16x32_bf16(ax, bw0, acc0[tt], 0,0,0);
      acc1[tt] = __builtin_amdgcn_mfma_f32_16x16x32_bf16(ax, bw1, acc1[tt], 0,0,0);
    }
  }
  ushort* htp = HT + ((size_t)b*NPa + (size_t)n*LP)*64;
  int c = w*16 + r15;
  #pragma unroll
  for(int tt=0;tt<4;tt++){
    int t0 = tt*16 + hi*4;
    #pragma unroll
    for(int i=0;i<4;i++){
      int t = t0 + i;
      if(t < L50) htp[(size_t)t*64 + c] = f2bf(tanhf(acc0[tt][i])*sigm(acc1[tt][i]));
    }
  }
  if(tid < 128){ int cz = tid >> 1, tz = 50 + (tid & 1); htp[(size_t)tz*64 + cz] = 0; }
}

// ---------------- zero HT padding rows p in [NP, NPa) ----------------
__global__ __launch_bounds__(TPB) void k_htpad(ushort* __restrict__ HT){
  int i = blockIdx.x*TPB + threadIdx.x;
  int per = (NPa-NP)*8;                           // 8 uint4 per row of 64 ushorts
  if(i >= Bx*per) return;
  int b = i / per, r = i % per;
  uint4 z; z.x=0;z.y=0;z.z=0;z.w=0;
  *(uint4*)&HT[((size_t)b*NPa + NP)*64 + (size_t)r*8] = z;
}

// ---------------- gated multi-basis GCN einsum via MFMA ----------------
// F32=0: input XT bf16 [b][NPa][64]; F32=1: input f32 [b][64][NP], fused transpose+convert (t2bf-identical)
template<int D, int F32>
__global__ __launch_bounds__(TPB) void k_gcs_mfma(const void* __restrict__ XTv,
    const ushort* __restrict__ wqF, const ushort* __restrict__ wvF,
    float* __restrict__ S){
  constexpr int Dt = D/16;
  int p0 = blockIdx.x*64;
  int b = blockIdx.z;
  int tid = threadIdx.x;
  int lane = tid & 63, w = tid >> 6;
  int d0 = blockIdx.y*64 + (w<<4);
  int dTile = blockIdx.y*4 + w;
  __shared__ __align__(16) ushort sX[64*64];
  if constexpr(F32){
    const float* X = (const float*)XTv;
    __shared__ __align__(16) float sT[64][65];
    for(int i=tid;i<4096;i+=TPB){ int c=i>>6, col=i&63; int p=p0+col;
      sT[c][col] = (p<NP) ? X[((size_t)(b*64+c))*NP + p] : 0.f; }
    __syncthreads();
    for(int i=tid;i<512;i+=TPB){
      int row=i>>3, c8=(i&7)<<3;
      ushort u[8];
      #pragma unroll
      for(int j=0;j<8;j++) u[j] = f2bf(sT[c8+j][row]);
      *(uint4*)&sX[row*64 + (c8 ^ ((row&7)<<3))] = *(uint4*)u;
    }
  } else {
    const ushort* XT = (const ushort*)XTv;
    for(int i=tid;i<512;i+=TPB){
      int row=i>>3, c8=(i&7)<<3;
      uint4 v = *(const uint4*)&XT[((size_t)b*NPa + p0 + row)*64 + c8];
      *(uint4*)&sX[row*64 + (c8 ^ ((row&7)<<3))] = v;
    }
  }
  __syncthreads();
  int r15 = lane & 15, hi = lane >> 4;
  bf16x8 bf[4][2];
  #pragma unroll
  for(int pt=0;pt<4;pt++){
    int row = pt*16 + r15;
    int sw = (row&7)<<3;
    int cu0 = hi*8;
    bf[pt][0] = *(const bf16x8*)&sX[row*64 + (cu0 ^ sw)];
    bf[pt][1] = *(const bf16x8*)&sX[row*64 + ((cu0+32) ^ sw)];
  }
  f32x4 acc[4];
  #pragma unroll
  for(int pt=0;pt<4;pt++){ acc[pt][0]=0.f; acc[pt][1]=0.f; acc[pt][2]=0.f; acc[pt][3]=0.f; }
  const ushort* wqp = wqF + ((size_t)dTile*2)*512 + lane*8;
  const ushort* wvp = wvF + ((size_t)dTile*2)*512 + lane*8;
  for(int k=0;k<Kb;k++){
    bf16x8 aq0 = *(const bf16x8*)&wqp[0];
    bf16x8 aq1 = *(const bf16x8*)&wqp[512];
    bf16x8 av0 = *(const bf16x8*)&wvp[0];
    bf16x8 av1 = *(const bf16x8*)&wvp[512];
    wqp += (size_t)Dt*2*512; wvp += (size_t)Dt*2*512;
    #pragma unroll
    for(int pt=0;pt<4;pt++){
      f32x4 q; q[0]=0.f;q[1]=0.f;q[2]=0.f;q[3]=0.f;
      f32x4 v; v[0]=0.f;v[1]=0.f;v[2]=0.f;v[3]=0.f;
      q = __builtin_amdgcn_mfma_f32_16x16x32_bf16(aq0, bf[pt][0], q, 0,0,0);
      q = __builtin_amdgcn_mfma_f32_16x16x32_bf16(aq1, bf[pt][1], q, 0,0,0);
      v = __builtin_amdgcn_mfma_f32_16x16x32_bf16(av0, bf[pt][0], v, 0,0,0);
      v = __builtin_amdgcn_mfma_f32_16x16x32_bf16(av1, bf[pt][1], v, 0,0,0);
      #pragma unroll
      for(int i=0;i<4;i++) acc[pt][i] += v[i]*sigm(q[i]);
    }
  }
  #pragma unroll
  for(int pt=0;pt<4;pt++){
    int p = p0 + pt*16 + r15;
    if(p < NP){
      #pragma unroll
      for(int i=0;i<4;i++){
        int d = d0 + hi*4 + i;
        S[((size_t)b*D + d)*NP + p] = acc[pt][i];
      }
    }
  }
}

// ---------------- adjacency aggregation via MFMA (fused S transpose in; coalesced f32 out) ----------------
template<int RELU>
__global__ __launch_bounds__(TPB) void k_agg_mfma(const float* __restrict__ S, const ushort* __restrict__ adjF,
                                                  const float* __restrict__ bias, float* __restrict__ Out, int D){
  int d = blockIdx.x, b = blockIdx.y;
  int bd = b*D + d;
  constexpr int SST = 232;
  __shared__ __align__(16) ushort sB[64*SST];
  int tid = threadIdx.x;
  for(int i=tid*8; i<64*SST; i+=TPB*8){ uint4 z; z.x=0;z.y=0;z.z=0;z.w=0; *(uint4*)&sB[i]=z; }
  __syncthreads();
  const float* Sp = S + (size_t)bd*NP;
  for(int i=tid; i<NP; i+=TPB){
    int nn = i/52, l = i - nn*52;
    sB[l*SST + nn] = f2bf(Sp[i]);
  }
  __syncthreads();
  int lane = tid & 63, w = tid >> 6;
  int r15 = lane & 15, hi = lane >> 4;
  float bb = bias[d];
  float* Op = Out + (size_t)bd*NP;
  for(int k2t = w; k2t < 13; k2t += 4){
    f32x4 acc[4];
    #pragma unroll
    for(int lt=0;lt<4;lt++){ acc[lt][0]=0;acc[lt][1]=0;acc[lt][2]=0;acc[lt][3]=0; }
    #pragma unroll
    for(int ks=0; ks<7; ks++){
      bf16x8 a = *(const bf16x8*)&adjF[((size_t)(k2t*7 + ks))*512 + lane*8];
      #pragma unroll
      for(int lt=0;lt<4;lt++){
        bf16x8 bfr = *(const bf16x8*)&sB[(lt*16+r15)*SST + ks*32 + hi*8];
        acc[lt] = __builtin_amdgcn_mfma_f32_16x16x32_bf16(a, bfr, acc[lt], 0,0,0);
      }
    }
    #pragma unroll
    for(int lt=0;lt<4;lt++){
      #pragma unroll
      for(int i2=0;i2<4;i2++){
        int k2 = k2t*16 + hi*4 + i2;
        int l  = lt*16 + r15;
        if(k2 < Nn && l < LP){
          float v = acc[lt][i2] + bb;
          if(RELU) v = fmaxf(v, 0.f);
          Op[(size_t)k2*LP + l] = v;
        }
      }
    }
  }
}

// ---------------- MLP conv (dil=1) via MFMA, per layer; input RB f32 [b][128][NP] ----------------
template<int MODE>
__global__ __launch_bounds__(TPB) void k_mlpacc_mfma(const float* __restrict__ RB, const ushort* __restrict__ WF,
                                                     float* __restrict__ gacc, const float* __restrict__ bm,
                                                     float* __restrict__ gg){
  int n = blockIdx.x, b = blockIdx.y;
  constexpr int CS = 136;
  __shared__ __align__(16) ushort sLT[52*CS];
  int tid = threadIdx.x;
  for(int i=tid;i<6656;i+=TPB){
    int c = i/52, l = i%52;
    sLT[l*CS + c] = f2bf(RB[(((size_t)b*128+c)*Nn + n)*LP + l]);
  }
  __syncthreads();
  int lane = tid & 63, w = tid >> 6;
  int r15 = lane & 15, hi = lane >> 4;
  f32x4 acc0[3], acc1[3];
  #pragma unroll
  for(int tt=0;tt<3;tt++){
    acc0[tt][0]=0;acc0[tt][1]=0;acc0[tt][2]=0;acc0[tt][3]=0;
    acc1[tt][0]=0;acc1[tt][1]=0;acc1[tt][2]=0;acc1[tt][3]=0;
  }
  const ushort* wp0 = WF + ((size_t)w*12)*512 + lane*8;
  const ushort* wp1 = WF + ((size_t)(w+4)*12)*512 + lane*8;
  #pragma unroll 3
  for(int ks=0; ks<12; ks++){
    int kt = ks>>2, ci0 = (ks&3)*32 + hi*8;
    bf16x8 bw0 = *(const bf16x8*)&wp0[(size_t)ks*512];
    bf16x8 bw1 = *(const bf16x8*)&wp1[(size_t)ks*512];
    #pragma unroll
    for(int tt=0;tt<3;tt++){
      bf16x8 ax = *(const bf16x8*)&sLT[(tt*16 + r15 + kt)*CS + ci0];
      acc0[tt] = __builtin_amdgcn_mfma_f32_16x16x32_bf16(ax, bw0, acc0[tt], 0,0,0);
      acc1[tt] = __builtin_amdgcn_mfma_f32_16x16x32_bf16(ax, bw1, acc1[tt], 0,0,0);
    }
  }
  int o = w*16 + r15;
  if(MODE < 2){
    float* gp = gacc + ((size_t)b*Nn + n)*48*128;
    #pragma unroll
    for(int tt=0;tt<3;tt++){
      #pragma unroll
      for(int i2=0;i2<4;i2++){
        int tq = tt*16 + hi*4 + i2;
        size_t a0 = (size_t)tq*128 + o;
        if(MODE==0){ gp[a0] = acc0[tt][i2]; gp[a0+64] = acc1[tt][i2]; }
        else       { gp[a0] += acc0[tt][i2]; gp[a0+64] += acc1[tt][i2]; }
      }
    }
  } else {
    const float* gp = gacc + ((size_t)b*Nn + n)*48*128;
    float b0 = bm[o], b1 = bm[o+64];
    float* ggp = gg + (((size_t)b*Cc + o)*Nn + n)*(size_t)Tout;
    #pragma unroll
    for(int tt=0;tt<3;tt++){
      #pragma unroll
      for(int i2=0;i2<4;i2++){
        int tq = tt*16 + hi*4 + i2;
        size_t a0 = (size_t)tq*128 + o;
        float a  = gp[a0]    + acc0[tt][i2] + b0;
        float g2 = gp[a0+64] + acc1[tt][i2] + b1;
        ggp[tq] = tanhf(a)*sigm(g2);
      }
    }
  }
}

// ---------------- patch scramble + emb ----------------
__global__ __launch_bounds__(TPB) void k_xe(const float* __restrict__ gg, const float* __restrict__ emb, float* __restrict__ xe){
  size_t i = (size_t)blockIdx.x*TPB + threadIdx.x;
  if(i >= (size_t)Bx*1271808) return;
  int b = (int)(i / 1271808);
  int off = (int)(i % 1271808);
  int c = off / 19872; int r = off % 19872;
  int n = r / 96; int r2 = r % 96;
  int p = r2 >> 3; int j = r2 & 7;
  int t = p*4 + j;
  float v = 0.f;
  if(t < Tout) v = gg[(((size_t)b*Cc+c)*Nn + n)*Tout + t];
  int e = off & 511; int p2 = (off >> 9) % 12;
  xe[i] = v + emb[(size_t)p2*Ee + e];
}

// ---------------- per-row LN helper (rows of 512, stride SRDF, in LDS); NW waves ----------------
template<int NW>
__device__ __forceinline__ void ln_rows(float* buf, const float* __restrict__ g, const float* __restrict__ be, int tid){
  int lane = tid & 63, wv = tid >> 6;
  for(int r = wv; r < 12; r += NW){
    float s=0.f, s2=0.f;
    #pragma unroll
    for(int j=0;j<8;j++){ float v = buf[r*SRDF + j*64 + lane]; s+=v; s2+=v*v; }
    #pragma unroll
    for(int off=32; off; off>>=1){ s += __shfl_xor(s,off); s2 += __shfl_xor(s2,off); }
    float m = s*(1.f/512.f);
    float rstd = rsqrtf(fmaxf(s2*(1.f/512.f)-m*m, 0.f)+EPSF);
    #pragma unroll
    for(int j=0;j<8;j++){ int e = j*64+lane; float v = buf[r*SRDF+e];
      buf[r*SRDF+e] = (v-m)*rstd*g[e] + be[e]; }
  }
}

// ---------------- fused per-(b,n) transformer, MFMA GEMM phases; 512 threads (8 waves) ----------------
__global__ __launch_bounds__(TPA,2) void k_attn(
    const float* __restrict__ xe, const float* __restrict__ resid,
    const ushort* __restrict__ WqF, const float* __restrict__ bq,
    const ushort* __restrict__ WkF, const float* __restrict__ bk,
    const ushort* __restrict__ WvF, const float* __restrict__ bv,
    const ushort* __restrict__ WfcF, const float* __restrict__ bfc,
    const float* __restrict__ g1, const float* __restrict__ b1n,
    const float* __restrict__ g2, const float* __restrict__ b2n,
    const ushort* __restrict__ Wff1F, const float* __restrict__ bff1,
    const ushort* __restrict__ Wff2F, const float* __restrict__ bff2,
    const float* __restrict__ Wrp, const float* __restrict__ brp,
    float* __restrict__ y)
{
  int n = blockIdx.x, b = blockIdx.y;
  __shared__ __align__(16) ushort SbX[16*512];
  __shared__ __align__(16) ushort Mb[16*256];
  __shared__ __align__(16) float U0[12*SRDF];
  __shared__ __align__(16) float U1[12*SRDF];
  __shared__ __align__(16) float sS[1160];
  int tid = threadIdx.x;
  int lane = tid & 63, w = tid >> 6;          // w in [0,8)
  int r15 = lane & 15, hi = lane >> 4;
  const float* __restrict__ xeg = xe + ((size_t)b*Nn + n)*6144;

  for(int i=tid;i<1024;i+=TPA){
    int r = i>>6, ch = i&63;
    ushort u[8];
    if(r<12){
      const float* s = &xeg[r*512 + ch*8];
      #pragma unroll
      for(int j=0;j<8;j++) u[j] = f2bf(s[j]);
    } else {
      #pragma unroll
      for(int j=0;j<8;j++) u[j] = 0;
    }
    *(uint4*)&SbX[r*512 + ((ch ^ (r&7))<<3)] = *(uint4*)u;
  }
  for(int i=tid;i<128;i+=TPA){
    int r = 12 + (i>>5), ch = i&31;
    uint4 z; z.x=0;z.y=0;z.z=0;z.w=0;
    *(uint4*)&Mb[r*256 + ch*8] = z;
  }
  __syncthreads();

  // QKV: one head per wave
  f32x4 vfrag[4];
  {
    int head = w;
    bf16x8 a0, a1;
    { int ch0 = head*8 + hi, ch1 = head*8 + 4 + hi;
      a0 = *(const bf16x8*)&SbX[r15*512 + ((ch0 ^ (r15&7))<<3)];
      a1 = *(const bf16x8*)&SbX[r15*512 + ((ch1 ^ (r15&7))<<3)]; }
    #pragma unroll
    for(int nt=0;nt<4;nt++){
      int col = nt*16 + r15;
      float bb = bq[col];
      f32x4 acc; acc[0]=bb;acc[1]=bb;acc[2]=bb;acc[3]=bb;
      acc = __builtin_amdgcn_mfma_f32_16x16x32_bf16(a0, *(const bf16x8*)&WqF[(size_t)(nt*2+0)*512 + lane*8], acc, 0,0,0);
      acc = __builtin_amdgcn_mfma_f32_16x16x32_bf16(a1, *(const bf16x8*)&WqF[(size_t)(nt*2+1)*512 + lane*8], acc, 0,0,0);
      #pragma unroll
      for(int i2=0;i2<4;i2++){ int p = hi*4+i2; if(p<12) U0[p*SRDF + head*64 + col] = acc[i2]; }
    }
    #pragma unroll
    for(int nt=0;nt<4;nt++){
      int col = nt*16 + r15;
      float bb = bk[col];
      f32x4 acc; acc[0]=bb;acc[1]=bb;acc[2]=bb;acc[3]=bb;
      acc = __builtin_amdgcn_mfma_f32_16x16x32_bf16(a0, *(const bf16x8*)&WkF[(size_t)(nt*2+0)*512 + lane*8], acc, 0,0,0);
      acc = __builtin_amdgcn_mfma_f32_16x16x32_bf16(a1, *(const bf16x8*)&WkF[(size_t)(nt*2+1)*512 + lane*8], acc, 0,0,0);
      #pragma unroll
      for(int i2=0;i2<4;i2++){ int p = hi*4+i2; if(p<12) U1[p*SRDF + head*64 + col] = acc[i2]; }
    }
    #pragma unroll
    for(int nt=0;nt<4;nt++){
      int col = nt*16 + r15;
      float bb = bv[col];
      f32x4 acc; acc[0]=bb;acc[1]=bb;acc[2]=bb;acc[3]=bb;
      acc = __builtin_amdgcn_mfma_f32_16x16x32_bf16(a0, *(const bf16x8*)&WvF[(size_t)(nt*2+0)*512 + lane*8], acc, 0,0,0);
      acc = __builtin_amdgcn_mfma_f32_16x16x32_bf16(a1, *(const bf16x8*)&WvF[(size_t)(nt*2+1)*512 + lane*8], acc, 0,0,0);
      vfrag[nt] = acc;
    }
  }
  __syncthreads();

  const float scale = 0.04419417382415922f;   // 1/sqrt(512)
  for(int i=tid;i<1152;i+=TPA){
    int q = i%12, kh = i/12; int h2 = kh&7, k2 = kh>>3;
    const float* qp = &U0[q*SRDF + h2*64];
    const float* kp = &U1[k2*SRDF + h2*64];
    float s=0.f;
    #pragma unroll
    for(int d4=0; d4<16; d4++){
      float4 a4 = *(const float4*)&qp[d4*4];
      float4 b4 = *(const float4*)&kp[d4*4];
      s += a4.x*b4.x + a4.y*b4.y + a4.z*b4.z + a4.w*b4.w;
    }
    sS[i] = s*scale;
  }
  __syncthreads();
  {
    int head = w;
    #pragma unroll
    for(int nt=0;nt<4;nt++){
      int col = nt*16 + r15;
      #pragma unroll
      for(int i2=0;i2<4;i2++){ int p = hi*4+i2; if(p<12) U0[p*SRDF + head*64 + col] = vfrag[nt][i2]; }
    }
  }
  if(tid<96){
    float mx=-1e30f;
    for(int q=0;q<12;q++) mx = fmaxf(mx, sS[tid*12+q]);
    float sm=0.f;
    for(int q=0;q<12;q++){ float e = __expf(sS[tid*12+q]-mx); sS[tid*12+q]=e; sm+=e; }
    float inv = 1.f/sm;
    for(int q=0;q<12;q++) sS[tid*12+q] *= inv;
  }
  __syncthreads();

  for(int i=tid;i<6144;i+=TPA){
    int q=i>>9, h2=(i>>6)&7, d=i&63;
    float s=0.f;
    #pragma unroll
    for(int k2=0;k2<12;k2++) s += sS[(k2*8+h2)*12+q]*U0[k2*SRDF+h2*64+d];
    int kk = i & 511;
    SbX[q*512 + (((kk>>3) ^ (q&7))<<3) + (kk&7)] = f2bf(s);
  }
  __syncthreads();

  // fc: 32 col-tiles, 4 per wave
  {
    f32x4 acc[4];
    #pragma unroll
    for(int nt=0;nt<4;nt++){ float bb = bfc[(w*4+nt)*16 + r15]; acc[nt][0]=bb;acc[nt][1]=bb;acc[nt][2]=bb;acc[nt][3]=bb; }
    for(int ks=0;ks<16;ks++){
      int ch = ks*4 + hi;
      bf16x8 a = *(const bf16x8*)&SbX[r15*512 + ((ch ^ (r15&7))<<3)];
      #pragma unroll
      for(int nt=0;nt<4;nt++){
        acc[nt] = __builtin_amdgcn_mfma_f32_16x16x32_bf16(a, *(const bf16x8*)&WfcF[(size_t)((w*4+nt)*16 + ks)*512 + lane*8], acc[nt], 0,0,0);
      }
    }
    #pragma unroll
    for(int nt=0;nt<4;nt++){
      int col = (w*4+nt)*16 + r15;
      #pragma unroll
      for(int i2=0;i2<4;i2++){ int p = hi*4+i2; if(p<12) U1[p*SRDF + col] = acc[nt][i2] + xeg[p*512 + col]; }
    }
  }
  __syncthreads();
  ln_rows<8>(U1, g1, b1n, tid);     // M in U1
  __syncthreads();

  for(int i=tid;i<6144;i+=TPA){
    int r=i>>9, kk=i&511;
    SbX[r*512 + (((kk>>3) ^ (r&7))<<3) + (kk&7)] = f2bf(U1[r*SRDF + kk]);
  }
  __syncthreads();

  // ff1: 16 col-tiles, 2 per wave
  {
    f32x4 acc[2];
    #pragma unroll
    for(int nt=0;nt<2;nt++){ float bb = bff1[(w*2+nt)*16 + r15]; acc[nt][0]=bb;acc[nt][1]=bb;acc[nt][2]=bb;acc[nt][3]=bb; }
    for(int ks=0;ks<16;ks++){
      int ch = ks*4 + hi;
      bf16x8 a = *(const bf16x8*)&SbX[r15*512 + ((ch ^ (r15&7))<<3)];
      #pragma unroll
      for(int nt=0;nt<2;nt++){
        acc[nt] = __builtin_amdgcn_mfma_f32_16x16x32_bf16(a, *(const bf16x8*)&Wff1F[(size_t)((w*2+nt)*16 + ks)*512 + lane*8], acc[nt], 0,0,0);
      }
    }
    #pragma unroll
    for(int nt=0;nt<2;nt++){
      int u = (w*2+nt)*16 + r15;
      #pragma unroll
      for(int i2=0;i2<4;i2++){
        int p = hi*4+i2;
        if(p<12) Mb[p*256 + (((u>>3) ^ (p&7))<<3) + (u&7)] = f2bf(fmaxf(acc[nt][i2], 0.f));
      }
    }
  }
  __syncthreads();

  // ff2: 32 col-tiles, 4 per wave
  {
    f32x4 acc[4];
    #pragma unroll
    for(int nt=0;nt<4;nt++){ float bb = bff2[(w*4+nt)*16 + r15]; acc[nt][0]=bb;acc[nt][1]=bb;acc[nt][2]=bb;acc[nt][3]=bb; }
    for(int ks=0;ks<8;ks++){
      int ch = ks*4 + hi;
      bf16x8 a = *(const bf16x8*)&Mb[r15*256 + ((ch ^ (r15&7))<<3)];
      #pragma unroll
      for(int nt=0;nt<4;nt++){
        acc[nt] = __builtin_amdgcn_mfma_f32_16x16x32_bf16(a, *(const bf16x8*)&Wff2F[(size_t)((w*4+nt)*8 + ks)*512 + lane*8], acc[nt], 0,0,0);
      }
    }
    #pragma unroll
    for(int nt=0;nt<4;nt++){
      int col = (w*4+nt)*16 + r15;
      #pragma unroll
      for(int i2=0;i2<4;i2++){ int p = hi*4+i2; if(p<12) U0[p*SRDF + col] = acc[nt][i2] + U1[p*SRDF + col]; }
    }
  }
  __syncthreads();
  ln_rows<8>(U0, g2, b2n, tid);     // U in U0
  __syncthreads();

  for(int i=tid;i<6144;i+=TPA){
    int r=i>>9, c=i&511;
    U1[r*SRDF+c] = U0[r*SRDF+c] + U1[r*SRDF+c] + xeg[r*512+c];
  }
  __syncthreads();
  for(int i=tid;i<4608;i+=TPA) U0[i] = Wrp[i];
  __syncthreads();
  #pragma unroll
  for(int j=0;j<2;j++){
    int i4 = tid + j*TPA;
    if(i4 < 768){
      int c = i4/12, tq = i4%12; int t0 = tq*4;
      float4 acc = *(const float4*)&brp[t0];
      for(int t96=0;t96<96;t96++){
        int f = c*96 + t96;
        float a = U1[(f>>9)*SRDF + (f&511)];
        float4 w4 = *(const float4*)&U0[t96*48 + t0];
        FMA4(acc, a, w4);
      }
      size_t rb = (((size_t)b*Cc+c)*Nn + n)*Tin + 6 + t0;
      acc.x += resid[rb+0]; acc.y += resid[rb+1]; acc.z += resid[rb+2]; acc.w += resid[rb+3];
      *(float4*)&y[(((size_t)b*Cc+c)*Nn + n)*Tout + t0] = acc;
    }
  }
}

// ---------------- batchnorm ----------------
__global__ __launch_bounds__(TPB) void k_bnstats(const float* __restrict__ y, float* __restrict__ stats){
  int c = blockIdx.x; int tid = threadIdx.x;
  float s=0.f,s2=0.f;
  const int per = Nn*Tout;   // 9936
  for(int idx=tid; idx<Bx*per; idx+=TPB){
    int b = idx/per, r = idx%per;
    float v = y[((size_t)b*Cc+c)*per + r];
    s+=v; s2+=v*v;
  }
  __shared__ float rs[TPB], rs2[TPB];
  rs[tid]=s; rs2[tid]=s2; __syncthreads();
  for(int off=TPB/2; off; off>>=1){ if(tid<off){ rs[tid]+=rs[tid+off]; rs2[tid]+=rs2[tid+off]; } __syncthreads(); }
  if(tid==0){
    float m = rs[0]/(float)(Bx*per);
    float var = rs2[0]/(float)(Bx*per) - m*m;
    stats[c]=m; stats[64+c]=rsqrtf(fmaxf(var,0.f)+EPSF);
  }
}
__global__ __launch_bounds__(TPB) void k_bnout(const float* __restrict__ y, const float* __restrict__ stats,
                                               const float* __restrict__ gbn, const float* __restrict__ bbn,
                                               float* __restrict__ out){
  size_t i = (size_t)blockIdx.x*TPB + threadIdx.x;
  if(i >= (size_t)Bx*Cc*Nn*Tout) return;
  int c = (int)((i/(Nn*Tout))%Cc);
  out[i] = (y[i]-stats[c])*stats[64+c]*gbn[c] + bbn[c];
}

// ---------------- launch ----------------
extern "C" void kernel_launch(void* const* d_in, const int* in_sizes, int n_in,
                              void* d_out, int out_size, void* d_ws, size_t ws_size,
                              hipStream_t stream) {
  const float* x      = (const float*)d_in[0];
  const float* adj    = (const float*)d_in[1];
  const float* Wconv1 = (const float*)d_in[2];
  const float* bconv1 = (const float*)d_in[3];
  const float* gT     = (const float*)d_in[4];
  const float* bT     = (const float*)d_in[5];
  const float* gS     = (const float*)d_in[6];
  const float* bS     = (const float*)d_in[7];
  const float* Wtime  = (const float*)d_in[8];
  const float* btime  = (const float*)d_in[9];
  const float* wq1    = (const float*)d_in[10];
  const float* wv1    = (const float*)d_in[11];
  const float* bias1  = (const float*)d_in[12];
  const float* wq2    = (const float*)d_in[13];
  const float* wv2    = (const float*)d_in[14];
  const float* bias2  = (const float*)d_in[15];
  const float* Wmlp   = (const float*)d_in[16];
  const float* bmlp   = (const float*)d_in[17];
  const float* embT   = (const float*)d_in[18];
  const float* Wq     = (const float*)d_in[19];
  const float* bq     = (const float*)d_in[20];
  const float* Wk     = (const float*)d_in[21];
  const float* bk     = (const float*)d_in[22];
  const float* Wv     = (const float*)d_in[23];
  const float* bv     = (const float*)d_in[24];
  const float* Wfc    = (const float*)d_in[25];
  const float* bfc    = (const float*)d_in[26];
  const float* g1     = (const float*)d_in[27];
  const float* b1n    = (const float*)d_in[28];
  const float* g2     = (const float*)d_in[29];
  const float* b2n    = (const float*)d_in[30];
  const float* Wff1   = (const float*)d_in[31];
  const float* bff1   = (const float*)d_in[32];
  const float* Wff2   = (const float*)d_in[33];
  const float* bff2   = (const float*)d_in[34];
  const float* Wrp    = (const float*)d_in[35];
  const float* brp    = (const float*)d_in[36];
  const float* gbn    = (const float*)d_in[37];
  const float* bbn    = (const float*)d_in[38];

  float* ws = (float*)d_ws;
  float* RESID = ws + O_RESID;
  float* LNTM  = ws + O_LNTM;
  float* LNTR  = ws + O_LNTR;
  float* LNSM  = ws + O_LNSM;
  float* LNSR  = ws + O_LNSR;
  float* RA    = ws + O_XCAT;
  float* RB    = ws + O_RB;
  float* GACC  = ws + O_GACC;
  float* GG    = ws + O_GG;
  float* Y     = ws + O_GG;      // overlays GG (safe: GG dead after k_xe builds XE)
  float* XE    = ws + O_XE;
  float* BNST  = ws + O_BNST;
  ushort* WTMF = (ushort*)(ws + O_WTM);
  ushort* WTB  = (ushort*)(ws + O_WTB);
  ushort* ADJT = (ushort*)(ws + O_ADJT);
  ushort* HT   = (ushort*)(ws + O_HT);   // in dead H region
  ushort* WQ1B = (ushort*)(ws + O_WQ1B);
  ushort* WV1B = (ushort*)(ws + O_WV1B);
  ushort* WQ2B = (ushort*)(ws + O_WQ2B);
  ushort* WV2B = (ushort*)(ws + O_WV2B);
  ushort* WQT  = (ushort*)(ws + O_WQT);
  ushort* WKT  = (ushort*)(ws + O_WKT);
  ushort* WVT  = (ushort*)(ws + O_WVT);
  ushort* WFCT = (ushort*)(ws + O_WFCT);
  ushort* WF1T = (ushort*)(ws + O_WF1T);
  ushort* WF2T = (ushort*)(ws + O_WF2T);

  k_residual<<<dim3(Nn,Bx),TPB,0,stream>>>(x, Wconv1, bconv1, RESID, LNTM, LNTR);
  k_lnS<<<(Bx*Cc*Tin)/TPB,TPB,0,stream>>>(RESID, LNSM, LNSR);
  k_wtbF<<<(8*18*512+TPB-1)/TPB,TPB,0,stream>>>(Wtime, WTB);
  k_wmlpF<<<(3*8*12*512+TPB-1)/TPB,TPB,0,stream>>>(Wmlp, WTMF);
  k_htpad<<<(Bx*(NPa-NP)*8+TPB-1)/TPB,TPB,0,stream>>>(HT);
  // fused xcat + timeconv (reads RESID + LN stats directly)
  k_timeconv_mfma<<<dim3(Nn,Bx),TPB,0,stream>>>(RESID, LNTM, LNTR, LNSM, LNSR, gT, bT, gS, bS,
                                                WTB, btime, HT);

  // merged fragment-order weight converts (11 jobs, one dispatch)
  WJobs jobs;
  jobs.j[0]  = { wq1,  WQ1B, 64,  64,  2,  4,  64*64,   24*4*2*512 };
  jobs.j[1]  = { wv1,  WV1B, 64,  64,  2,  4,  64*64,   24*4*2*512 };
  jobs.j[2]  = { wq2,  WQ2B, 64,  128, 2,  8,  64*128,  24*8*2*512 };
  jobs.j[3]  = { wv2,  WV2B, 64,  128, 2,  8,  64*128,  24*8*2*512 };
  jobs.j[4]  = { Wq,   WQT,  64,  64,  2,  4,  64*64,   4*2*512 };
  jobs.j[5]  = { Wk,   WKT,  64,  64,  2,  4,  64*64,   4*2*512 };
  jobs.j[6]  = { Wv,   WVT,  64,  64,  2,  4,  64*64,   4*2*512 };
  jobs.j[7]  = { Wfc,  WFCT, 512, 512, 16, 32, 512*512, 32*16*512 };
  jobs.j[8]  = { Wff1, WF1T, 512, 256, 16, 16, 512*256, 16*16*512 };
  jobs.j[9]  = { Wff2, WF2T, 256, 512, 8,  32, 256*512, 32*8*512 };
  jobs.j[10] = { adj,  ADJT, 207, 207, 7,  13, Nn*Nn,   3*13*7*512 };
  int totalW = 2*(24*4*2*512) + 2*(24*8*2*512) + 3*(4*2*512) + 32*16*512 + 16*16*512 + 32*8*512 + 3*13*7*512;
  k_wfrag_all<<<(totalW+TPB-1)/TPB,TPB,0,stream>>>(jobs);

  for(int i=0;i<3;i++){
    k_gcs_mfma<64,0><<<dim3(169,1,Bx),TPB,0,stream>>>(HT, WQ1B+(size_t)i*8*4*2*512, WV1B+(size_t)i*8*4*2*512, RA);
    k_agg_mfma<1><<<dim3(64,Bx),TPB,0,stream>>>(RA, ADJT+(size_t)i*13*7*512, bias1+(size_t)i*64, RB, 64);
    k_gcs_mfma<128,1><<<dim3(169,2,Bx),TPB,0,stream>>>(RB, WQ2B+(size_t)i*8*8*2*512, WV2B+(size_t)i*8*8*2*512, RA);
    k_agg_mfma<0><<<dim3(128,Bx),TPB,0,stream>>>(RA, ADJT+(size_t)i*13*7*512, bias2+(size_t)i*128, RB, 128);
    if(i==0)      k_mlpacc_mfma<0><<<dim3(Nn,Bx),TPB,0,stream>>>(RB, WTMF+(size_t)i*8*12*512, GACC, bmlp, GG);
    else if(i==1) k_mlpacc_mfma<1><<<dim3(Nn,Bx),TPB,0,stream>>>(RB, WTMF+(size_t)i*8*12*512, GACC, bmlp, GG);
    else          k_mlpacc_mfma<2><<<dim3(Nn,Bx),TPB,0,stream>>>(RB, WTMF+(size_t)i*8*12*512, GACC, bmlp, GG);
  }
  k_xe<<<(Bx*1271808)/TPB,TPB,0,stream>>>(GG, embT, XE);
  k_attn<<<dim3(Nn,Bx),TPA,0,stream>>>(XE, RESID, WQT,bq, WKT,bk, WVT,bv, WFCT,bfc,
                                       g1,b1n,g2,b2n, WF1T,bff1, WF2T,bff2, Wrp,brp, Y);
  k_bnstats<<<64,TPB,0,stream>>>(Y, BNST);
  k_bnout<<<(Bx*Cc*Nn*Tout)/TPB,TPB,0,stream>>>(Y, BNST, gbn, bbn, (float*)d_out);
}

// Round 23
// 869.564 us; speedup vs baseline: 1.0916x; 1.0272x over previous
//
#include <hip/hip_runtime.h>
#include <hip/hip_bf16.h>

#define TPB 256
#define TPA 512

constexpr int Bx = 8, Cc = 64, Nn = 207, Tin = 54, Kb = 8;
constexpr int LP = 52, NP = Nn * LP;     // time padded 50->52, flattened node*time positions
constexpr int NPa = 10816;               // NP rounded up to 169*64 for MFMA tiles
constexpr int L50 = 50, Tout = 48;
constexpr int Ee = 512, Pn = 12;
constexpr float EPSF = 1e-5f;
constexpr int SRDF = 516;                // padded row stride for 512-wide f32 LDS rows (2-way bank pattern)

// ---------------- workspace layout (floats) ----------------
constexpr size_t O_RESID = 0;                                   // [B][64][207][54]
constexpr size_t O_LNTM  = O_RESID + (size_t)Bx*Cc*Nn*Tin;
constexpr size_t O_LNTR  = O_LNTM  + (size_t)Bx*Cc*Nn;
constexpr size_t O_LNSM  = O_LNTR  + (size_t)Bx*Cc*Nn;
constexpr size_t O_LNSR  = O_LNSM  + (size_t)Bx*Cc*Tin;
constexpr size_t O_XCAT  = O_LNSR  + (size_t)Bx*Cc*Tin;         // RA bf16 [B][128][NP] (uses < half the region)
constexpr size_t O_RB    = O_XCAT  + (size_t)Bx*192*Nn*Tin;     // RB bf16 [B][128][NP]
constexpr size_t O_H     = O_RB    + (size_t)Bx*128*NP;         // HT bf16 [Bx][NPa][64]
constexpr size_t O_GACC  = O_H     + (size_t)Bx*64*NP;          // [B][n][48][128] (relaid out)
constexpr size_t O_GG    = O_GACC  + (size_t)Bx*128*Nn*Tout;    // [B][64][207][48]; reused as Y after xe built
constexpr size_t O_XE    = O_GG    + (size_t)Bx*64*Nn*Tout;     // [B][207][12][512]
constexpr size_t O_WTT   = O_XE    + (size_t)Bx*Nn*Pn*Ee;       // (unused) 128*192*3
constexpr size_t O_WTM   = O_WTT   + (size_t)128*192*3;         // ushort[3*8*12*512] W_mlp frag bf16
constexpr size_t O_BNST  = O_WTM   + (size_t)128*384*3;         // 128
constexpr size_t O_WTB   = O_BNST + 128;                        // ushort[8*18*512] time-conv bf16 frag weights
constexpr size_t O_ADJT  = O_WTB  + (size_t)128*576/2;          // ushort[3][13*7*512] adj frag bf16
constexpr size_t O_HT    = O_H;                                 // ushort[Bx][NPa][64] in dead H region
constexpr size_t O_TAIL  = O_XCAT + (size_t)Bx*128*NP;          // tail anchor (after RA region)
constexpr size_t O_WQ1B  = O_TAIL + (size_t)Bx*NPa*64/2;        // ushort[24*4*2*512]
constexpr size_t O_WV1B  = O_WQ1B + (size_t)24*64*64/2;
constexpr size_t O_WQ2B  = O_WV1B + (size_t)24*64*64/2;         // ushort[24*8*2*512]
constexpr size_t O_WV2B  = O_WQ2B + (size_t)24*128*64/2;
constexpr size_t O_RBT   = O_WV2B + (size_t)24*128*64/2;        // (unused)
constexpr size_t O_WQT   = O_RBT  + (size_t)Bx*NPa*64/2;        // ushort[4*2*512]
constexpr size_t O_WKT   = O_WQT  + 2048;
constexpr size_t O_WVT   = O_WKT  + 2048;
constexpr size_t O_WFCT  = O_WVT  + 2048;                       // ushort[32*16*512]
constexpr size_t O_WF1T  = O_WFCT + 131072;                     // ushort[16*16*512]
constexpr size_t O_WF2T  = O_WF1T + 65536;                      // ushort[32*8*512]

#define FMA4(acc, sA_, vB_) { (acc).x += (sA_)*(vB_).x; (acc).y += (sA_)*(vB_).y; (acc).z += (sA_)*(vB_).z; (acc).w += (sA_)*(vB_).w; }

typedef __attribute__((ext_vector_type(8))) short bf16x8;
typedef __attribute__((ext_vector_type(4))) float f32x4;

__device__ __forceinline__ float sigm(float x){ return 1.0f/(1.0f+__expf(-x)); }
__device__ __forceinline__ ushort f2bf(float x){ __hip_bfloat16 h = __float2bfloat16(x); return *(ushort*)&h; }

// ---------------- residual = W_conv1 @ x + b, fused lnT stats ----------------
__global__ __launch_bounds__(TPB) void k_residual(const float* __restrict__ x, const float* __restrict__ W,
                                                  const float* __restrict__ bias, float* __restrict__ out,
                                                  float* __restrict__ lnm, float* __restrict__ lnr){
  int n = blockIdx.x, b = blockIdx.y;
  __shared__ __align__(16) float sX[Cc][Tin];
  __shared__ __align__(16) float sW[Cc*Cc];
  __shared__ __align__(16) float sO[Cc][Tin];
  int tid = threadIdx.x;
  for(int i=tid;i<Cc*Tin;i+=TPB){ int c=i/Tin, l=i%Tin; sX[c][l] = x[((size_t)(b*Cc+c)*Nn+n)*Tin+l]; }
  for(int i=tid;i<Cc*Cc;i+=TPB) sW[i]=W[i];
  __syncthreads();
  for(int i=tid;i<Cc*Tin;i+=TPB){
    int o=i/Tin, l=i%Tin; float acc=bias[o];
    #pragma unroll 8
    for(int c=0;c<Cc;c++) acc += sW[o*Cc+c]*sX[c][l];
    out[((size_t)(b*Cc+o)*Nn+n)*Tin+l]=acc;
    sO[o][l]=acc;
  }
  __syncthreads();
  if(tid < Cc){
    float s=0.f,s2=0.f;
    for(int l=0;l<Tin;l++){ float v=sO[tid][l]; s+=v; s2+=v*v; }
    float m=s*(1.f/Tin); float var=s2*(1.f/Tin)-m*m;
    int row = (b*Cc+tid)*Nn + n;
    lnm[row]=m; lnr[row]=rsqrtf(fmaxf(var,0.f)+EPSF);
  }
}

// ---------------- lnS stats ----------------
__global__ __launch_bounds__(TPB) void k_lnS(const float* __restrict__ r, float* __restrict__ mean, float* __restrict__ rstd){
  int row = blockIdx.x*TPB + threadIdx.x;       // (b*Cc+c)*Tin + l
  if(row >= Bx*Cc*Tin) return;
  int l = row % Tin; int bc = row / Tin;
  const float* p = r + (size_t)bc*Nn*Tin + l;
  float s=0.f,s2=0.f;
  for(int n=0;n<Nn;n++){ float v=p[(size_t)n*Tin]; s+=v; s2+=v*v; }
  float m=s*(1.f/Nn); float var=s2*(1.f/Nn)-m*m;
  mean[row]=m; rstd[row]=rsqrtf(fmaxf(var,0.f)+EPSF);
}

// ---------------- merged fragment-order weight converter (10 jobs + adj) ----------------
struct WJob { const float* W; ushort* F; int K, N, KS, NT, sStride, total; };
struct WJobs { WJob j[11]; };

__global__ __launch_bounds__(TPB) void k_wfrag_all(WJobs jobs){
  int gi = blockIdx.x*TPB + threadIdx.x;
  for(int seg=0; seg<11; seg++){
    const WJob J = jobs.j[seg];
    if(gi < J.total){
      int i = gi;
      int j = i & 7; int lane = (i>>3) & 63;
      int t = i >> 9;
      int ks = t % J.KS; int r = t / J.KS; int colTile = r % J.NT; int s = r / J.NT;
      int r15 = lane & 15, hi = lane >> 4;
      int k = ks*32 + hi*8 + j, col = colTile*16 + r15;
      float v = (k < J.K && col < J.N) ? J.W[(size_t)s*J.sStride + (size_t)k*J.N + col] : 0.f;
      J.F[i] = f2bf(v);
      return;
    }
    gi -= J.total;
  }
}

// ---------------- time-conv weight frag convert ----------------
__global__ __launch_bounds__(TPB) void k_wtbF(const float* __restrict__ W, ushort* __restrict__ F){
  int i = blockIdx.x*TPB + threadIdx.x;
  if(i >= 8*18*512) return;
  int j = i & 7; int lane = (i>>3) & 63;
  int t = i >> 9;
  int ks = t % 18; int colTile = t / 18;
  int r15 = lane & 15, hi = lane >> 4;
  int k = ks*32 + hi*8 + j, o = colTile*16 + r15;
  int kt = k/192, ci = k - kt*192;
  F[i] = f2bf(W[(size_t)(o*192+ci)*3 + kt]);
}

// ---------------- mlp-conv weight frag convert ----------------
__global__ __launch_bounds__(TPB) void k_wmlpF(const float* __restrict__ W, ushort* __restrict__ F){
  int i = blockIdx.x*TPB + threadIdx.x;
  if(i >= 3*8*12*512) return;
  int j = i & 7; int lane = (i>>3) & 63;
  int t = i >> 9;
  int ks = t % 12; int r = t / 12; int colTile = r & 7; int layer = r >> 3;
  int r15 = lane & 15, hi = lane >> 4;
  int k = ks*32 + hi*8 + j;
  int kt = k >> 7, ci = k & 127;
  int o = colTile*16 + r15;
  F[i] = f2bf(W[(size_t)(o*384 + layer*128 + ci)*3 + kt]);
}

// ---------------- fused xcat+dilated time conv (dil=2) + GLU via MFMA -> HT bf16 [b][p][64] ----------------
__global__ __launch_bounds__(TPB) void k_timeconv_mfma(const float* __restrict__ resid,
    const float* __restrict__ tm, const float* __restrict__ tr,
    const float* __restrict__ sm, const float* __restrict__ sr,
    const float* __restrict__ gT, const float* __restrict__ bT,
    const float* __restrict__ gS, const float* __restrict__ bS,
    const ushort* __restrict__ WF, const float* __restrict__ bias, ushort* __restrict__ HT){
  int n = blockIdx.x, b = blockIdx.y;
  constexpr int XS = 200;
  __shared__ __align__(16) ushort sXT[68*XS];
  int tid = threadIdx.x;
  for(int i=tid; i<14*XS; i+=TPB) sXT[54*XS + i] = 0;
  float gSn = gS[n], bSn = bS[n];
  for(int i=tid; i<64*54; i+=TPB){
    int cm = i/54, l = i%54;
    int rowT = (b*Cc+cm)*Nn + n;
    float r = resid[(size_t)rowT*Tin + l];
    float v1 = (r - tm[rowT]) * tr[rowT] * gT[l] + bT[l];
    int rowS = (b*Cc+cm)*Tin + l;
    float v2 = (r - sm[rowS]) * sr[rowS] * gSn + bSn;
    sXT[l*XS + cm]        = f2bf(r);
    sXT[l*XS + 64 + cm]   = f2bf(v1);
    sXT[l*XS + 128 + cm]  = f2bf(v2);
  }
  __syncthreads();
  int lane = tid & 63, w = tid >> 6;
  int r15 = lane & 15, hi = lane >> 4;
  float b0 = bias[w*16 + r15], b1 = bias[w*16 + 64 + r15];
  f32x4 acc0[4], acc1[4];
  #pragma unroll
  for(int tt=0;tt<4;tt++){
    acc0[tt][0]=b0; acc0[tt][1]=b0; acc0[tt][2]=b0; acc0[tt][3]=b0;
    acc1[tt][0]=b1; acc1[tt][1]=b1; acc1[tt][2]=b1; acc1[tt][3]=b1;
  }
  const ushort* wp0 = WF + ((size_t)w*18)*512 + lane*8;
  const ushort* wp1 = WF + ((size_t)(w+4)*18)*512 + lane*8;
  #pragma unroll 2
  for(int ks=0; ks<18; ks++){
    int k0 = ks*32 + hi*8;
    int kt = k0/192, ci0 = k0 - kt*192;
    bf16x8 bw0 = *(const bf16x8*)&wp0[(size_t)ks*512];
    bf16x8 bw1 = *(const bf16x8*)&wp1[(size_t)ks*512];
    #pragma unroll
    for(int tt=0;tt<4;tt++){
      bf16x8 ax = *(const bf16x8*)&sXT[(tt*16 + r15 + 2*kt)*XS + ci0];
      acc0[tt] = __builtin_amdgcn_mfma_f32_16x16x32_bf16(ax, bw0, acc0[tt], 0,0,0);
      acc1[tt] = __builtin_amdgcn_mfma_f32_16x16x32_bf16(ax, bw1, acc1[tt], 0,0,0);
    }
  }
  ushort* htp = HT + ((size_t)b*NPa + (size_t)n*LP)*64;
  int c = w*16 + r15;
  #pragma unroll
  for(int tt=0;tt<4;tt++){
    int t0 = tt*16 + hi*4;
    #pragma unroll
    for(int i=0;i<4;i++){
      int t = t0 + i;
      if(t < L50) htp[(size_t)t*64 + c] = f2bf(tanhf(acc0[tt][i])*sigm(acc1[tt][i]));
    }
  }
  if(tid < 128){ int cz = tid >> 1, tz = 50 + (tid & 1); htp[(size_t)tz*64 + cz] = 0; }
}

// ---------------- zero HT padding rows p in [NP, NPa) ----------------
__global__ __launch_bounds__(TPB) void k_htpad(ushort* __restrict__ HT){
  int i = blockIdx.x*TPB + threadIdx.x;
  int per = (NPa-NP)*8;                           // 8 uint4 per row of 64 ushorts
  if(i >= Bx*per) return;
  int b = i / per, r = i % per;
  uint4 z; z.x=0;z.y=0;z.z=0;z.w=0;
  *(uint4*)&HT[((size_t)b*NPa + NP)*64 + (size_t)r*8] = z;
}

// ---------------- gated multi-basis GCN einsum via MFMA; bf16 in AND out ----------------
// TR=0: input XT bf16 [b][NPa][64] (p-major, MFMA-ready); TR=1: input bf16 [b][64][NP] (c-major, transpose-stage)
template<int D, int TR>
__global__ __launch_bounds__(TPB) void k_gcs_mfma(const ushort* __restrict__ XT,
    const ushort* __restrict__ wqF, const ushort* __restrict__ wvF,
    ushort* __restrict__ S){
  constexpr int Dt = D/16;
  int p0 = blockIdx.x*64;
  int b = blockIdx.z;
  int tid = threadIdx.x;
  int lane = tid & 63, w = tid >> 6;
  int d0 = blockIdx.y*64 + (w<<4);
  int dTile = blockIdx.y*4 + w;
  __shared__ __align__(16) ushort sX[64*64];
  if constexpr(TR){
    __shared__ __align__(16) ushort sT2[64*66];
    for(int i=tid;i<4096;i+=TPB){ int c=i>>6, col=i&63; int p=p0+col;
      sT2[c*66+col] = (p<NP) ? XT[((size_t)(b*64+c))*NP + p] : (ushort)0; }
    __syncthreads();
    for(int i=tid;i<512;i+=TPB){
      int row=i>>3, c8=(i&7)<<3;
      ushort u[8];
      #pragma unroll
      for(int j=0;j<8;j++) u[j] = sT2[(c8+j)*66 + row];
      *(uint4*)&sX[row*64 + (c8 ^ ((row&7)<<3))] = *(uint4*)u;
    }
  } else {
    for(int i=tid;i<512;i+=TPB){
      int row=i>>3, c8=(i&7)<<3;
      uint4 v = *(const uint4*)&XT[((size_t)b*NPa + p0 + row)*64 + c8];
      *(uint4*)&sX[row*64 + (c8 ^ ((row&7)<<3))] = v;
    }
  }
  __syncthreads();
  int r15 = lane & 15, hi = lane >> 4;
  bf16x8 bf[4][2];
  #pragma unroll
  for(int pt=0;pt<4;pt++){
    int row = pt*16 + r15;
    int sw = (row&7)<<3;
    int cu0 = hi*8;
    bf[pt][0] = *(const bf16x8*)&sX[row*64 + (cu0 ^ sw)];
    bf[pt][1] = *(const bf16x8*)&sX[row*64 + ((cu0+32) ^ sw)];
  }
  f32x4 acc[4];
  #pragma unroll
  for(int pt=0;pt<4;pt++){ acc[pt][0]=0.f; acc[pt][1]=0.f; acc[pt][2]=0.f; acc[pt][3]=0.f; }
  const ushort* wqp = wqF + ((size_t)dTile*2)*512 + lane*8;
  const ushort* wvp = wvF + ((size_t)dTile*2)*512 + lane*8;
  for(int k=0;k<Kb;k++){
    bf16x8 aq0 = *(const bf16x8*)&wqp[0];
    bf16x8 aq1 = *(const bf16x8*)&wqp[512];
    bf16x8 av0 = *(const bf16x8*)&wvp[0];
    bf16x8 av1 = *(const bf16x8*)&wvp[512];
    wqp += (size_t)Dt*2*512; wvp += (size_t)Dt*2*512;
    #pragma unroll
    for(int pt=0;pt<4;pt++){
      f32x4 q; q[0]=0.f;q[1]=0.f;q[2]=0.f;q[3]=0.f;
      f32x4 v; v[0]=0.f;v[1]=0.f;v[2]=0.f;v[3]=0.f;
      q = __builtin_amdgcn_mfma_f32_16x16x32_bf16(aq0, bf[pt][0], q, 0,0,0);
      q = __builtin_amdgcn_mfma_f32_16x16x32_bf16(aq1, bf[pt][1], q, 0,0,0);
      v = __builtin_amdgcn_mfma_f32_16x16x32_bf16(av0, bf[pt][0], v, 0,0,0);
      v = __builtin_amdgcn_mfma_f32_16x16x32_bf16(av1, bf[pt][1], v, 0,0,0);
      #pragma unroll
      for(int i=0;i<4;i++) acc[pt][i] += v[i]*sigm(q[i]);
    }
  }
  #pragma unroll
  for(int pt=0;pt<4;pt++){
    int p = p0 + pt*16 + r15;
    if(p < NP){
      #pragma unroll
      for(int i=0;i<4;i++){
        int d = d0 + hi*4 + i;
        S[((size_t)b*D + d)*NP + p] = f2bf(acc[pt][i]);
      }
    }
  }
}

// ---------------- adjacency aggregation via MFMA; bf16 in AND out ----------------
template<int RELU>
__global__ __launch_bounds__(TPB) void k_agg_mfma(const ushort* __restrict__ S, const ushort* __restrict__ adjF,
                                                  const float* __restrict__ bias, ushort* __restrict__ Out, int D){
  int d = blockIdx.x, b = blockIdx.y;
  int bd = b*D + d;
  constexpr int SST = 232;
  __shared__ __align__(16) ushort sB[64*SST];
  int tid = threadIdx.x;
  for(int i=tid*8; i<64*SST; i+=TPB*8){ uint4 z; z.x=0;z.y=0;z.z=0;z.w=0; *(uint4*)&sB[i]=z; }
  __syncthreads();
  const ushort* Sp = S + (size_t)bd*NP;
  for(int i=tid; i<NP; i+=TPB){
    int nn = i/52, l = i - nn*52;
    sB[l*SST + nn] = Sp[i];
  }
  __syncthreads();
  int lane = tid & 63, w = tid >> 6;
  int r15 = lane & 15, hi = lane >> 4;
  float bb = bias[d];
  ushort* Op = Out + (size_t)bd*NP;
  for(int k2t = w; k2t < 13; k2t += 4){
    f32x4 acc[4];
    #pragma unroll
    for(int lt=0;lt<4;lt++){ acc[lt][0]=0;acc[lt][1]=0;acc[lt][2]=0;acc[lt][3]=0; }
    #pragma unroll
    for(int ks=0; ks<7; ks++){
      bf16x8 a = *(const bf16x8*)&adjF[((size_t)(k2t*7 + ks))*512 + lane*8];
      #pragma unroll
      for(int lt=0;lt<4;lt++){
        bf16x8 bfr = *(const bf16x8*)&sB[(lt*16+r15)*SST + ks*32 + hi*8];
        acc[lt] = __builtin_amdgcn_mfma_f32_16x16x32_bf16(a, bfr, acc[lt], 0,0,0);
      }
    }
    #pragma unroll
    for(int lt=0;lt<4;lt++){
      #pragma unroll
      for(int i2=0;i2<4;i2++){
        int k2 = k2t*16 + hi*4 + i2;
        int l  = lt*16 + r15;
        if(k2 < Nn && l < LP){
          float v = acc[lt][i2] + bb;
          if(RELU) v = fmaxf(v, 0.f);
          Op[(size_t)k2*LP + l] = f2bf(v);
        }
      }
    }
  }
}

// ---------------- MLP conv (dil=1) via MFMA, per layer; input RB bf16 [b][128][NP] ----------------
template<int MODE>
__global__ __launch_bounds__(TPB) void k_mlpacc_mfma(const ushort* __restrict__ RB, const ushort* __restrict__ WF,
                                                     float* __restrict__ gacc, const float* __restrict__ bm,
                                                     float* __restrict__ gg){
  int n = blockIdx.x, b = blockIdx.y;
  constexpr int CS = 136;
  __shared__ __align__(16) ushort sLT[52*CS];
  int tid = threadIdx.x;
  for(int i=tid;i<6656;i+=TPB){
    int c = i/52, l = i%52;
    sLT[l*CS + c] = RB[(((size_t)b*128+c)*Nn + n)*LP + l];
  }
  __syncthreads();
  int lane = tid & 63, w = tid >> 6;
  int r15 = lane & 15, hi = lane >> 4;
  f32x4 acc0[3], acc1[3];
  #pragma unroll
  for(int tt=0;tt<3;tt++){
    acc0[tt][0]=0;acc0[tt][1]=0;acc0[tt][2]=0;acc0[tt][3]=0;
    acc1[tt][0]=0;acc1[tt][1]=0;acc1[tt][2]=0;acc1[tt][3]=0;
  }
  const ushort* wp0 = WF + ((size_t)w*12)*512 + lane*8;
  const ushort* wp1 = WF + ((size_t)(w+4)*12)*512 + lane*8;
  #pragma unroll 3
  for(int ks=0; ks<12; ks++){
    int kt = ks>>2, ci0 = (ks&3)*32 + hi*8;
    bf16x8 bw0 = *(const bf16x8*)&wp0[(size_t)ks*512];
    bf16x8 bw1 = *(const bf16x8*)&wp1[(size_t)ks*512];
    #pragma unroll
    for(int tt=0;tt<3;tt++){
      bf16x8 ax = *(const bf16x8*)&sLT[(tt*16 + r15 + kt)*CS + ci0];
      acc0[tt] = __builtin_amdgcn_mfma_f32_16x16x32_bf16(ax, bw0, acc0[tt], 0,0,0);
      acc1[tt] = __builtin_amdgcn_mfma_f32_16x16x32_bf16(ax, bw1, acc1[tt], 0,0,0);
    }
  }
  int o = w*16 + r15;
  if(MODE < 2){
    float* gp = gacc + ((size_t)b*Nn + n)*48*128;
    #pragma unroll
    for(int tt=0;tt<3;tt++){
      #pragma unroll
      for(int i2=0;i2<4;i2++){
        int tq = tt*16 + hi*4 + i2;
        size_t a0 = (size_t)tq*128 + o;
        if(MODE==0){ gp[a0] = acc0[tt][i2]; gp[a0+64] = acc1[tt][i2]; }
        else       { gp[a0] += acc0[tt][i2]; gp[a0+64] += acc1[tt][i2]; }
      }
    }
  } else {
    const float* gp = gacc + ((size_t)b*Nn + n)*48*128;
    float b0 = bm[o], b1 = bm[o+64];
    float* ggp = gg + (((size_t)b*Cc + o)*Nn + n)*(size_t)Tout;
    #pragma unroll
    for(int tt=0;tt<3;tt++){
      #pragma unroll
      for(int i2=0;i2<4;i2++){
        int tq = tt*16 + hi*4 + i2;
        size_t a0 = (size_t)tq*128 + o;
        float a  = gp[a0]    + acc0[tt][i2] + b0;
        float g2 = gp[a0+64] + acc1[tt][i2] + b1;
        ggp[tq] = tanhf(a)*sigm(g2);
      }
    }
  }
}

// ---------------- patch scramble + emb ----------------
__global__ __launch_bounds__(TPB) void k_xe(const float* __restrict__ gg, const float* __restrict__ emb, float* __restrict__ xe){
  size_t i = (size_t)blockIdx.x*TPB + threadIdx.x;
  if(i >= (size_t)Bx*1271808) return;
  int b = (int)(i / 1271808);
  int off = (int)(i % 1271808);
  int c = off / 19872; int r = off % 19872;
  int n = r / 96; int r2 = r % 96;
  int p = r2 >> 3; int j = r2 & 7;
  int t = p*4 + j;
  float v = 0.f;
  if(t < Tout) v = gg[(((size_t)b*Cc+c)*Nn + n)*Tout + t];
  int e = off & 511; int p2 = (off >> 9) % 12;
  xe[i] = v + emb[(size_t)p2*Ee + e];
}

// ---------------- per-row LN helper (rows of 512, stride SRDF, in LDS); NW waves ----------------
template<int NW>
__device__ __forceinline__ void ln_rows(float* buf, const float* __restrict__ g, const float* __restrict__ be, int tid){
  int lane = tid & 63, wv = tid >> 6;
  for(int r = wv; r < 12; r += NW){
    float s=0.f, s2=0.f;
    #pragma unroll
    for(int j=0;j<8;j++){ float v = buf[r*SRDF + j*64 + lane]; s+=v; s2+=v*v; }
    #pragma unroll
    for(int off=32; off; off>>=1){ s += __shfl_xor(s,off); s2 += __shfl_xor(s2,off); }
    float m = s*(1.f/512.f);
    float rstd = rsqrtf(fmaxf(s2*(1.f/512.f)-m*m, 0.f)+EPSF);
    #pragma unroll
    for(int j=0;j<8;j++){ int e = j*64+lane; float v = buf[r*SRDF+e];
      buf[r*SRDF+e] = (v-m)*rstd*g[e] + be[e]; }
  }
}

// ---------------- fused per-(b,n) transformer, MFMA GEMM phases; 512 threads (8 waves) ----------------
__global__ __launch_bounds__(TPA,2) void k_attn(
    const float* __restrict__ xe, const float* __restrict__ resid,
    const ushort* __restrict__ WqF, const float* __restrict__ bq,
    const ushort* __restrict__ WkF, const float* __restrict__ bk,
    const ushort* __restrict__ WvF, const float* __restrict__ bv,
    const ushort* __restrict__ WfcF, const float* __restrict__ bfc,
    const float* __restrict__ g1, const float* __restrict__ b1n,
    const float* __restrict__ g2, const float* __restrict__ b2n,
    const ushort* __restrict__ Wff1F, const float* __restrict__ bff1,
    const ushort* __restrict__ Wff2F, const float* __restrict__ bff2,
    const float* __restrict__ Wrp, const float* __restrict__ brp,
    float* __restrict__ y)
{
  int n = blockIdx.x, b = blockIdx.y;
  __shared__ __align__(16) ushort SbX[16*512];
  __shared__ __align__(16) ushort Mb[16*256];
  __shared__ __align__(16) float U0[12*SRDF];
  __shared__ __align__(16) float U1[12*SRDF];
  __shared__ __align__(16) float sS[1160];
  int tid = threadIdx.x;
  int lane = tid & 63, w = tid >> 6;          // w in [0,8)
  int r15 = lane & 15, hi = lane >> 4;
  const float* __restrict__ xeg = xe + ((size_t)b*Nn + n)*6144;

  for(int i=tid;i<1024;i+=TPA){
    int r = i>>6, ch = i&63;
    ushort u[8];
    if(r<12){
      const float* s = &xeg[r*512 + ch*8];
      #pragma unroll
      for(int j=0;j<8;j++) u[j] = f2bf(s[j]);
    } else {
      #pragma unroll
      for(int j=0;j<8;j++) u[j] = 0;
    }
    *(uint4*)&SbX[r*512 + ((ch ^ (r&7))<<3)] = *(uint4*)u;
  }
  for(int i=tid;i<128;i+=TPA){
    int r = 12 + (i>>5), ch = i&31;
    uint4 z; z.x=0;z.y=0;z.z=0;z.w=0;
    *(uint4*)&Mb[r*256 + ch*8] = z;
  }
  __syncthreads();

  // QKV: one head per wave
  f32x4 vfrag[4];
  {
    int head = w;
    bf16x8 a0, a1;
    { int ch0 = head*8 + hi, ch1 = head*8 + 4 + hi;
      a0 = *(const bf16x8*)&SbX[r15*512 + ((ch0 ^ (r15&7))<<3)];
      a1 = *(const bf16x8*)&SbX[r15*512 + ((ch1 ^ (r15&7))<<3)]; }
    #pragma unroll
    for(int nt=0;nt<4;nt++){
      int col = nt*16 + r15;
      float bb = bq[col];
      f32x4 acc; acc[0]=bb;acc[1]=bb;acc[2]=bb;acc[3]=bb;
      acc = __builtin_amdgcn_mfma_f32_16x16x32_bf16(a0, *(const bf16x8*)&WqF[(size_t)(nt*2+0)*512 + lane*8], acc, 0,0,0);
      acc = __builtin_amdgcn_mfma_f32_16x16x32_bf16(a1, *(const bf16x8*)&WqF[(size_t)(nt*2+1)*512 + lane*8], acc, 0,0,0);
      #pragma unroll
      for(int i2=0;i2<4;i2++){ int p = hi*4+i2; if(p<12) U0[p*SRDF + head*64 + col] = acc[i2]; }
    }
    #pragma unroll
    for(int nt=0;nt<4;nt++){
      int col = nt*16 + r15;
      float bb = bk[col];
      f32x4 acc; acc[0]=bb;acc[1]=bb;acc[2]=bb;acc[3]=bb;
      acc = __builtin_amdgcn_mfma_f32_16x16x32_bf16(a0, *(const bf16x8*)&WkF[(size_t)(nt*2+0)*512 + lane*8], acc, 0,0,0);
      acc = __builtin_amdgcn_mfma_f32_16x16x32_bf16(a1, *(const bf16x8*)&WkF[(size_t)(nt*2+1)*512 + lane*8], acc, 0,0,0);
      #pragma unroll
      for(int i2=0;i2<4;i2++){ int p = hi*4+i2; if(p<12) U1[p*SRDF + head*64 + col] = acc[i2]; }
    }
    #pragma unroll
    for(int nt=0;nt<4;nt++){
      int col = nt*16 + r15;
      float bb = bv[col];
      f32x4 acc; acc[0]=bb;acc[1]=bb;acc[2]=bb;acc[3]=bb;
      acc = __builtin_amdgcn_mfma_f32_16x16x32_bf16(a0, *(const bf16x8*)&WvF[(size_t)(nt*2+0)*512 + lane*8], acc, 0,0,0);
      acc = __builtin_amdgcn_mfma_f32_16x16x32_bf16(a1, *(const bf16x8*)&WvF[(size_t)(nt*2+1)*512 + lane*8], acc, 0,0,0);
      vfrag[nt] = acc;
    }
  }
  __syncthreads();

  const float scale = 0.04419417382415922f;   // 1/sqrt(512)
  for(int i=tid;i<1152;i+=TPA){
    int q = i%12, kh = i/12; int h2 = kh&7, k2 = kh>>3;
    const float* qp = &U0[q*SRDF + h2*64];
    const float* kp = &U1[k2*SRDF + h2*64];
    float s=0.f;
    #pragma unroll
    for(int d4=0; d4<16; d4++){
      float4 a4 = *(const float4*)&qp[d4*4];
      float4 b4 = *(const float4*)&kp[d4*4];
      s += a4.x*b4.x + a4.y*b4.y + a4.z*b4.z + a4.w*b4.w;
    }
    sS[i] = s*scale;
  }
  __syncthreads();
  {
    int head = w;
    #pragma unroll
    for(int nt=0;nt<4;nt++){
      int col = nt*16 + r15;
      #pragma unroll
      for(int i2=0;i2<4;i2++){ int p = hi*4+i2; if(p<12) U0[p*SRDF + head*64 + col] = vfrag[nt][i2]; }
    }
  }
  if(tid<96){
    float mx=-1e30f;
    for(int q=0;q<12;q++) mx = fmaxf(mx, sS[tid*12+q]);
    float sm=0.f;
    for(int q=0;q<12;q++){ float e = __expf(sS[tid*12+q]-mx); sS[tid*12+q]=e; sm+=e; }
    float inv = 1.f/sm;
    for(int q=0;q<12;q++) sS[tid*12+q] *= inv;
  }
  __syncthreads();

  for(int i=tid;i<6144;i+=TPA){
    int q=i>>9, h2=(i>>6)&7, d=i&63;
    float s=0.f;
    #pragma unroll
    for(int k2=0;k2<12;k2++) s += sS[(k2*8+h2)*12+q]*U0[k2*SRDF+h2*64+d];
    int kk = i & 511;
    SbX[q*512 + (((kk>>3) ^ (q&7))<<3) + (kk&7)] = f2bf(s);
  }
  __syncthreads();

  // fc: 32 col-tiles, 4 per wave
  {
    f32x4 acc[4];
    #pragma unroll
    for(int nt=0;nt<4;nt++){ float bb = bfc[(w*4+nt)*16 + r15]; acc[nt][0]=bb;acc[nt][1]=bb;acc[nt][2]=bb;acc[nt][3]=bb; }
    for(int ks=0;ks<16;ks++){
      int ch = ks*4 + hi;
      bf16x8 a = *(const bf16x8*)&SbX[r15*512 + ((ch ^ (r15&7))<<3)];
      #pragma unroll
      for(int nt=0;nt<4;nt++){
        acc[nt] = __builtin_amdgcn_mfma_f32_16x16x32_bf16(a, *(const bf16x8*)&WfcF[(size_t)((w*4+nt)*16 + ks)*512 + lane*8], acc[nt], 0,0,0);
      }
    }
    #pragma unroll
    for(int nt=0;nt<4;nt++){
      int col = (w*4+nt)*16 + r15;
      #pragma unroll
      for(int i2=0;i2<4;i2++){ int p = hi*4+i2; if(p<12) U1[p*SRDF + col] = acc[nt][i2] + xeg[p*512 + col]; }
    }
  }
  __syncthreads();
  ln_rows<8>(U1, g1, b1n, tid);     // M in U1
  __syncthreads();

  for(int i=tid;i<6144;i+=TPA){
    int r=i>>9, kk=i&511;
    SbX[r*512 + (((kk>>3) ^ (r&7))<<3) + (kk&7)] = f2bf(U1[r*SRDF + kk]);
  }
  __syncthreads();

  // ff1: 16 col-tiles, 2 per wave
  {
    f32x4 acc[2];
    #pragma unroll
    for(int nt=0;nt<2;nt++){ float bb = bff1[(w*2+nt)*16 + r15]; acc[nt][0]=bb;acc[nt][1]=bb;acc[nt][2]=bb;acc[nt][3]=bb; }
    for(int ks=0;ks<16;ks++){
      int ch = ks*4 + hi;
      bf16x8 a = *(const bf16x8*)&SbX[r15*512 + ((ch ^ (r15&7))<<3)];
      #pragma unroll
      for(int nt=0;nt<2;nt++){
        acc[nt] = __builtin_amdgcn_mfma_f32_16x16x32_bf16(a, *(const bf16x8*)&Wff1F[(size_t)((w*2+nt)*16 + ks)*512 + lane*8], acc[nt], 0,0,0);
      }
    }
    #pragma unroll
    for(int nt=0;nt<2;nt++){
      int u = (w*2+nt)*16 + r15;
      #pragma unroll
      for(int i2=0;i2<4;i2++){
        int p = hi*4+i2;
        if(p<12) Mb[p*256 + (((u>>3) ^ (p&7))<<3) + (u&7)] = f2bf(fmaxf(acc[nt][i2], 0.f));
      }
    }
  }
  __syncthreads();

  // ff2: 32 col-tiles, 4 per wave
  {
    f32x4 acc[4];
    #pragma unroll
    for(int nt=0;nt<4;nt++){ float bb = bff2[(w*4+nt)*16 + r15]; acc[nt][0]=bb;acc[nt][1]=bb;acc[nt][2]=bb;acc[nt][3]=bb; }
    for(int ks=0;ks<8;ks++){
      int ch = ks*4 + hi;
      bf16x8 a = *(const bf16x8*)&Mb[r15*256 + ((ch ^ (r15&7))<<3)];
      #pragma unroll
      for(int nt=0;nt<4;nt++){
        acc[nt] = __builtin_amdgcn_mfma_f32_16x16x32_bf16(a, *(const bf16x8*)&Wff2F[(size_t)((w*4+nt)*8 + ks)*512 + lane*8], acc[nt], 0,0,0);
      }
    }
    #pragma unroll
    for(int nt=0;nt<4;nt++){
      int col = (w*4+nt)*16 + r15;
      #pragma unroll
      for(int i2=0;i2<4;i2++){ int p = hi*4+i2; if(p<12) U0[p*SRDF + col] = acc[nt][i2] + U1[p*SRDF + col]; }
    }
  }
  __syncthreads();
  ln_rows<8>(U0, g2, b2n, tid);     // U in U0
  __syncthreads();

  for(int i=tid;i<6144;i+=TPA){
    int r=i>>9, c=i&511;
    U1[r*SRDF+c] = U0[r*SRDF+c] + U1[r*SRDF+c] + xeg[r*512+c];
  }
  __syncthreads();
  for(int i=tid;i<4608;i+=TPA) U0[i] = Wrp[i];
  __syncthreads();
  #pragma unroll
  for(int j=0;j<2;j++){
    int i4 = tid + j*TPA;
    if(i4 < 768){
      int c = i4/12, tq = i4%12; int t0 = tq*4;
      float4 acc = *(const float4*)&brp[t0];
      for(int t96=0;t96<96;t96++){
        int f = c*96 + t96;
        float a = U1[(f>>9)*SRDF + (f&511)];
        float4 w4 = *(const float4*)&U0[t96*48 + t0];
        FMA4(acc, a, w4);
      }
      size_t rb = (((size_t)b*Cc+c)*Nn + n)*Tin + 6 + t0;
      acc.x += resid[rb+0]; acc.y += resid[rb+1]; acc.z += resid[rb+2]; acc.w += resid[rb+3];
      *(float4*)&y[(((size_t)b*Cc+c)*Nn + n)*Tout + t0] = acc;
    }
  }
}

// ---------------- batchnorm ----------------
__global__ __launch_bounds__(TPB) void k_bnstats(const float* __restrict__ y, float* __restrict__ stats){
  int c = blockIdx.x; int tid = threadIdx.x;
  float s=0.f,s2=0.f;
  const int per = Nn*Tout;   // 9936
  for(int idx=tid; idx<Bx*per; idx+=TPB){
    int b = idx/per, r = idx%per;
    float v = y[((size_t)b*Cc+c)*per + r];
    s+=v; s2+=v*v;
  }
  __shared__ float rs[TPB], rs2[TPB];
  rs[tid]=s; rs2[tid]=s2; __syncthreads();
  for(int off=TPB/2; off; off>>=1){ if(tid<off){ rs[tid]+=rs[tid+off]; rs2[tid]+=rs2[tid+off]; } __syncthreads(); }
  if(tid==0){
    float m = rs[0]/(float)(Bx*per);
    float var = rs2[0]/(float)(Bx*per) - m*m;
    stats[c]=m; stats[64+c]=rsqrtf(fmaxf(var,0.f)+EPSF);
  }
}
__global__ __launch_bounds__(TPB) void k_bnout(const float* __restrict__ y, const float* __restrict__ stats,
                                               const float* __restrict__ gbn, const float* __restrict__ bbn,
                                               float* __restrict__ out){
  size_t i = (size_t)blockIdx.x*TPB + threadIdx.x;
  if(i >= (size_t)Bx*Cc*Nn*Tout) return;
  int c = (int)((i/(Nn*Tout))%Cc);
  out[i] = (y[i]-stats[c])*stats[64+c]*gbn[c] + bbn[c];
}

// ---------------- launch ----------------
extern "C" void kernel_launch(void* const* d_in, const int* in_sizes, int n_in,
                              void* d_out, int out_size, void* d_ws, size_t ws_size,
                              hipStream_t stream) {
  const float* x      = (const float*)d_in[0];
  const float* adj    = (const float*)d_in[1];
  const float* Wconv1 = (const float*)d_in[2];
  const float* bconv1 = (const float*)d_in[3];
  const float* gT     = (const float*)d_in[4];
  const float* bT     = (const float*)d_in[5];
  const float* gS     = (const float*)d_in[6];
  const float* bS     = (const float*)d_in[7];
  const float* Wtime  = (const float*)d_in[8];
  const float* btime  = (const float*)d_in[9];
  const float* wq1    = (const float*)d_in[10];
  const float* wv1    = (const float*)d_in[11];
  const float* bias1  = (const float*)d_in[12];
  const float* wq2    = (const float*)d_in[13];
  const float* wv2    = (const float*)d_in[14];
  const float* bias2  = (const float*)d_in[15];
  const float* Wmlp   = (const float*)d_in[16];
  const float* bmlp   = (const float*)d_in[17];
  const float* embT   = (const float*)d_in[18];
  const float* Wq     = (const float*)d_in[19];
  const float* bq     = (const float*)d_in[20];
  const float* Wk     = (const float*)d_in[21];
  const float* bk     = (const float*)d_in[22];
  const float* Wv     = (const float*)d_in[23];
  const float* bv     = (const float*)d_in[24];
  const float* Wfc    = (const float*)d_in[25];
  const float* bfc    = (const float*)d_in[26];
  const float* g1     = (const float*)d_in[27];
  const float* b1n    = (const float*)d_in[28];
  const float* g2     = (const float*)d_in[29];
  const float* b2n    = (const float*)d_in[30];
  const float* Wff1   = (const float*)d_in[31];
  const float* bff1   = (const float*)d_in[32];
  const float* Wff2   = (const float*)d_in[33];
  const float* bff2   = (const float*)d_in[34];
  const float* Wrp    = (const float*)d_in[35];
  const float* brp    = (const float*)d_in[36];
  const float* gbn    = (const float*)d_in[37];
  const float* bbn    = (const float*)d_in[38];

  float* ws = (float*)d_ws;
  float* RESID = ws + O_RESID;
  float* LNTM  = ws + O_LNTM;
  float* LNTR  = ws + O_LNTR;
  float* LNSM  = ws + O_LNSM;
  float* LNSR  = ws + O_LNSR;
  ushort* RA   = (ushort*)(ws + O_XCAT);   // bf16 now (uses half the region)
  ushort* RB   = (ushort*)(ws + O_RB);     // bf16 now
  float* GACC  = ws + O_GACC;
  float* GG    = ws + O_GG;
  float* Y     = ws + O_GG;      // overlays GG (safe: GG dead after k_xe builds XE)
  float* XE    = ws + O_XE;
  float* BNST  = ws + O_BNST;
  ushort* WTMF = (ushort*)(ws + O_WTM);
  ushort* WTB  = (ushort*)(ws + O_WTB);
  ushort* ADJT = (ushort*)(ws + O_ADJT);
  ushort* HT   = (ushort*)(ws + O_HT);   // in dead H region
  ushort* WQ1B = (ushort*)(ws + O_WQ1B);
  ushort* WV1B = (ushort*)(ws + O_WV1B);
  ushort* WQ2B = (ushort*)(ws + O_WQ2B);
  ushort* WV2B = (ushort*)(ws + O_WV2B);
  ushort* WQT  = (ushort*)(ws + O_WQT);
  ushort* WKT  = (ushort*)(ws + O_WKT);
  ushort* WVT  = (ushort*)(ws + O_WVT);
  ushort* WFCT = (ushort*)(ws + O_WFCT);
  ushort* WF1T = (ushort*)(ws + O_WF1T);
  ushort* WF2T = (ushort*)(ws + O_WF2T);

  k_residual<<<dim3(Nn,Bx),TPB,0,stream>>>(x, Wconv1, bconv1, RESID, LNTM, LNTR);
  k_lnS<<<(Bx*Cc*Tin)/TPB,TPB,0,stream>>>(RESID, LNSM, LNSR);
  k_wtbF<<<(8*18*512+TPB-1)/TPB,TPB,0,stream>>>(Wtime, WTB);
  k_wmlpF<<<(3*8*12*512+TPB-1)/TPB,TPB,0,stream>>>(Wmlp, WTMF);
  k_htpad<<<(Bx*(NPa-NP)*8+TPB-1)/TPB,TPB,0,stream>>>(HT);
  // fused xcat + timeconv (reads RESID + LN stats directly)
  k_timeconv_mfma<<<dim3(Nn,Bx),TPB,0,stream>>>(RESID, LNTM, LNTR, LNSM, LNSR, gT, bT, gS, bS,
                                                WTB, btime, HT);

  // merged fragment-order weight converts (11 jobs, one dispatch)
  WJobs jobs;
  jobs.j[0]  = { wq1,  WQ1B, 64,  64,  2,  4,  64*64,   24*4*2*512 };
  jobs.j[1]  = { wv1,  WV1B, 64,  64,  2,  4,  64*64,   24*4*2*512 };
  jobs.j[2]  = { wq2,  WQ2B, 64,  128, 2,  8,  64*128,  24*8*2*512 };
  jobs.j[3]  = { wv2,  WV2B, 64,  128, 2,  8,  64*128,  24*8*2*512 };
  jobs.j[4]  = { Wq,   WQT,  64,  64,  2,  4,  64*64,   4*2*512 };
  jobs.j[5]  = { Wk,   WKT,  64,  64,  2,  4,  64*64,   4*2*512 };
  jobs.j[6]  = { Wv,   WVT,  64,  64,  2,  4,  64*64,   4*2*512 };
  jobs.j[7]  = { Wfc,  WFCT, 512, 512, 16, 32, 512*512, 32*16*512 };
  jobs.j[8]  = { Wff1, WF1T, 512, 256, 16, 16, 512*256, 16*16*512 };
  jobs.j[9]  = { Wff2, WF2T, 256, 512, 8,  32, 256*512, 32*8*512 };
  jobs.j[10] = { adj,  ADJT, 207, 207, 7,  13, Nn*Nn,   3*13*7*512 };
  int totalW = 2*(24*4*2*512) + 2*(24*8*2*512) + 3*(4*2*512) + 32*16*512 + 16*16*512 + 32*8*512 + 3*13*7*512;
  k_wfrag_all<<<(totalW+TPB-1)/TPB,TPB,0,stream>>>(jobs);

  for(int i=0;i<3;i++){
    k_gcs_mfma<64,0><<<dim3(169,1,Bx),TPB,0,stream>>>(HT, WQ1B+(size_t)i*8*4*2*512, WV1B+(size_t)i*8*4*2*512, RA);
    k_agg_mfma<1><<<dim3(64,Bx),TPB,0,stream>>>(RA, ADJT+(size_t)i*13*7*512, bias1+(size_t)i*64, RB, 64);
    k_gcs_mfma<128,1><<<dim3(169,2,Bx),TPB,0,stream>>>(RB, WQ2B+(size_t)i*8*8*2*512, WV2B+(size_t)i*8*8*2*512, RA);
    k_agg_mfma<0><<<dim3(128,Bx),TPB,0,stream>>>(RA, ADJT+(size_t)i*13*7*512, bias2+(size_t)i*128, RB, 128);
    if(i==0)      k_mlpacc_mfma<0><<<dim3(Nn,Bx),TPB,0,stream>>>(RB, WTMF+(size_t)i*8*12*512, GACC, bmlp, GG);
    else if(i==1) k_mlpacc_mfma<1><<<dim3(Nn,Bx),TPB,0,stream>>>(RB, WTMF+(size_t)i*8*12*512, GACC, bmlp, GG);
    else          k_mlpacc_mfma<2><<<dim3(Nn,Bx),TPB,0,stream>>>(RB, WTMF+(size_t)i*8*12*512, GACC, bmlp, GG);
  }
  k_xe<<<(Bx*1271808)/TPB,TPB,0,stream>>>(GG, embT, XE);
  k_attn<<<dim3(Nn,Bx),TPA,0,stream>>>(XE, RESID, WQT,bq, WKT,bk, WVT,bv, WFCT,bfc,
                                       g1,b1n,g2,b2n, WF1T,bff1, WF2T,bff2, Wrp,brp, Y);
  k_bnstats<<<64,TPB,0,stream>>>(Y, BNST);
  k_bnout<<<(Bx*Cc*Nn*Tout)/TPB,TPB,0,stream>>>(Y, BNST, gbn, bbn, (float*)d_out);
}

// Round 24
// 858.453 us; speedup vs baseline: 1.1057x; 1.0129x over previous
//
#include <hip/hip_runtime.h>
#include <hip/hip_bf16.h>

#define TPB 256
#define TPA 512

constexpr int Bx = 8, Cc = 64, Nn = 207, Tin = 54, Kb = 8;
constexpr int LP = 52, NP = Nn * LP;     // time padded 50->52, flattened node*time positions
constexpr int NPa = 10816;               // NP rounded up to 169*64 for MFMA tiles
constexpr int L50 = 50, Tout = 48;
constexpr int Ee = 512, Pn = 12;
constexpr float EPSF = 1e-5f;
constexpr int SRDF = 516;                // padded row stride for 512-wide f32 LDS rows (2-way bank pattern)

// ---------------- workspace layout (floats) ----------------
constexpr size_t O_RESID = 0;                                   // [B][64][207][54]
constexpr size_t O_LNTM  = O_RESID + (size_t)Bx*Cc*Nn*Tin;
constexpr size_t O_LNTR  = O_LNTM  + (size_t)Bx*Cc*Nn;
constexpr size_t O_LNSM  = O_LNTR  + (size_t)Bx*Cc*Nn;
constexpr size_t O_LNSR  = O_LNSM  + (size_t)Bx*Cc*Tin;
constexpr size_t O_XCAT  = O_LNSR  + (size_t)Bx*Cc*Tin;         // RA bf16 (first 5.51M floats) + RB2 bf16 (next 5.51M)
constexpr size_t O_RB    = O_XCAT  + (size_t)Bx*192*Nn*Tin;     // RB0,RB1 bf16 (fills region exactly)
constexpr size_t O_H     = O_RB    + (size_t)Bx*128*NP;         // HT bf16 [Bx][NPa][64]
constexpr size_t O_GACC  = O_H     + (size_t)Bx*64*NP;          // S1 bf16 scratch (2.76M ≤ 5.09M)
constexpr size_t O_GG    = O_GACC  + (size_t)Bx*128*Nn*Tout;    // [B][64][207][48]; reused as Y after xe built
constexpr size_t O_XE    = O_GG    + (size_t)Bx*64*Nn*Tout;     // [B][207][12][512]
constexpr size_t O_WTT   = O_XE    + (size_t)Bx*Nn*Pn*Ee;       // (unused) 128*192*3
constexpr size_t O_WTM   = O_WTT   + (size_t)128*192*3;         // ushort[3*8*12*512] W_mlp frag bf16
constexpr size_t O_BNST  = O_WTM   + (size_t)128*384*3;         // 128
constexpr size_t O_WTB   = O_BNST + 128;                        // ushort[8*18*512] time-conv bf16 frag weights
constexpr size_t O_ADJT  = O_WTB  + (size_t)128*576/2;          // ushort[3][13*7*512] adj frag bf16
constexpr size_t O_HT    = O_H;                                 // ushort[Bx][NPa][64] in dead H region
constexpr size_t O_TAIL  = O_XCAT + (size_t)Bx*128*NP;          // tail anchor (RB2 ends exactly here)
constexpr size_t O_WQ1B  = O_TAIL + (size_t)Bx*NPa*64/2;        // ushort[24*4*2*512]
constexpr size_t O_WV1B  = O_WQ1B + (size_t)24*64*64/2;
constexpr size_t O_WQ2B  = O_WV1B + (size_t)24*64*64/2;         // ushort[24*8*2*512]
constexpr size_t O_WV2B  = O_WQ2B + (size_t)24*128*64/2;
constexpr size_t O_RBT   = O_WV2B + (size_t)24*128*64/2;        // (unused)
constexpr size_t O_WQT   = O_RBT  + (size_t)Bx*NPa*64/2;        // ushort[4*2*512]
constexpr size_t O_WKT   = O_WQT  + 2048;
constexpr size_t O_WVT   = O_WKT  + 2048;
constexpr size_t O_WFCT  = O_WVT  + 2048;                       // ushort[32*16*512]
constexpr size_t O_WF1T  = O_WFCT + 131072;                     // ushort[16*16*512]
constexpr size_t O_WF2T  = O_WF1T + 65536;                      // ushort[32*8*512]

#define FMA4(acc, sA_, vB_) { (acc).x += (sA_)*(vB_).x; (acc).y += (sA_)*(vB_).y; (acc).z += (sA_)*(vB_).z; (acc).w += (sA_)*(vB_).w; }

typedef __attribute__((ext_vector_type(8))) short bf16x8;
typedef __attribute__((ext_vector_type(4))) float f32x4;

__device__ __forceinline__ float sigm(float x){ return 1.0f/(1.0f+__expf(-x)); }
__device__ __forceinline__ ushort f2bf(float x){ __hip_bfloat16 h = __float2bfloat16(x); return *(ushort*)&h; }

// ---------------- residual = W_conv1 @ x + b, fused lnT stats ----------------
__global__ __launch_bounds__(TPB) void k_residual(const float* __restrict__ x, const float* __restrict__ W,
                                                  const float* __restrict__ bias, float* __restrict__ out,
                                                  float* __restrict__ lnm, float* __restrict__ lnr){
  int n = blockIdx.x, b = blockIdx.y;
  __shared__ __align__(16) float sX[Cc][Tin];
  __shared__ __align__(16) float sW[Cc*Cc];
  __shared__ __align__(16) float sO[Cc][Tin];
  int tid = threadIdx.x;
  for(int i=tid;i<Cc*Tin;i+=TPB){ int c=i/Tin, l=i%Tin; sX[c][l] = x[((size_t)(b*Cc+c)*Nn+n)*Tin+l]; }
  for(int i=tid;i<Cc*Cc;i+=TPB) sW[i]=W[i];
  __syncthreads();
  for(int i=tid;i<Cc*Tin;i+=TPB){
    int o=i/Tin, l=i%Tin; float acc=bias[o];
    #pragma unroll 8
    for(int c=0;c<Cc;c++) acc += sW[o*Cc+c]*sX[c][l];
    out[((size_t)(b*Cc+o)*Nn+n)*Tin+l]=acc;
    sO[o][l]=acc;
  }
  __syncthreads();
  if(tid < Cc){
    float s=0.f,s2=0.f;
    for(int l=0;l<Tin;l++){ float v=sO[tid][l]; s+=v; s2+=v*v; }
    float m=s*(1.f/Tin); float var=s2*(1.f/Tin)-m*m;
    int row = (b*Cc+tid)*Nn + n;
    lnm[row]=m; lnr[row]=rsqrtf(fmaxf(var,0.f)+EPSF);
  }
}

// ---------------- lnS stats ----------------
__global__ __launch_bounds__(TPB) void k_lnS(const float* __restrict__ r, float* __restrict__ mean, float* __restrict__ rstd){
  int row = blockIdx.x*TPB + threadIdx.x;       // (b*Cc+c)*Tin + l
  if(row >= Bx*Cc*Tin) return;
  int l = row % Tin; int bc = row / Tin;
  const float* p = r + (size_t)bc*Nn*Tin + l;
  float s=0.f,s2=0.f;
  for(int n=0;n<Nn;n++){ float v=p[(size_t)n*Tin]; s+=v; s2+=v*v; }
  float m=s*(1.f/Nn); float var=s2*(1.f/Nn)-m*m;
  mean[row]=m; rstd[row]=rsqrtf(fmaxf(var,0.f)+EPSF);
}

// ---------------- merged fragment-order weight converter (10 jobs + adj) ----------------
struct WJob { const float* W; ushort* F; int K, N, KS, NT, sStride, total; };
struct WJobs { WJob j[11]; };

__global__ __launch_bounds__(TPB) void k_wfrag_all(WJobs jobs){
  int gi = blockIdx.x*TPB + threadIdx.x;
  for(int seg=0; seg<11; seg++){
    const WJob J = jobs.j[seg];
    if(gi < J.total){
      int i = gi;
      int j = i & 7; int lane = (i>>3) & 63;
      int t = i >> 9;
      int ks = t % J.KS; int r = t / J.KS; int colTile = r % J.NT; int s = r / J.NT;
      int r15 = lane & 15, hi = lane >> 4;
      int k = ks*32 + hi*8 + j, col = colTile*16 + r15;
      float v = (k < J.K && col < J.N) ? J.W[(size_t)s*J.sStride + (size_t)k*J.N + col] : 0.f;
      J.F[i] = f2bf(v);
      return;
    }
    gi -= J.total;
  }
}

// ---------------- time-conv weight frag convert ----------------
__global__ __launch_bounds__(TPB) void k_wtbF(const float* __restrict__ W, ushort* __restrict__ F){
  int i = blockIdx.x*TPB + threadIdx.x;
  if(i >= 8*18*512) return;
  int j = i & 7; int lane = (i>>3) & 63;
  int t = i >> 9;
  int ks = t % 18; int colTile = t / 18;
  int r15 = lane & 15, hi = lane >> 4;
  int k = ks*32 + hi*8 + j, o = colTile*16 + r15;
  int kt = k/192, ci = k - kt*192;
  F[i] = f2bf(W[(size_t)(o*192+ci)*3 + kt]);
}

// ---------------- mlp-conv weight frag convert ----------------
__global__ __launch_bounds__(TPB) void k_wmlpF(const float* __restrict__ W, ushort* __restrict__ F){
  int i = blockIdx.x*TPB + threadIdx.x;
  if(i >= 3*8*12*512) return;
  int j = i & 7; int lane = (i>>3) & 63;
  int t = i >> 9;
  int ks = t % 12; int r = t / 12; int colTile = r & 7; int layer = r >> 3;
  int r15 = lane & 15, hi = lane >> 4;
  int k = ks*32 + hi*8 + j;
  int kt = k >> 7, ci = k & 127;
  int o = colTile*16 + r15;
  F[i] = f2bf(W[(size_t)(o*384 + layer*128 + ci)*3 + kt]);
}

// ---------------- fused xcat+dilated time conv (dil=2) + GLU via MFMA -> HT bf16 [b][p][64] ----------------
__global__ __launch_bounds__(TPB) void k_timeconv_mfma(const float* __restrict__ resid,
    const float* __restrict__ tm, const float* __restrict__ tr,
    const float* __restrict__ sm, const float* __restrict__ sr,
    const float* __restrict__ gT, const float* __restrict__ bT,
    const float* __restrict__ gS, const float* __restrict__ bS,
    const ushort* __restrict__ WF, const float* __restrict__ bias, ushort* __restrict__ HT){
  int n = blockIdx.x, b = blockIdx.y;
  constexpr int XS = 200;
  __shared__ __align__(16) ushort sXT[68*XS];
  int tid = threadIdx.x;
  for(int i=tid; i<14*XS; i+=TPB) sXT[54*XS + i] = 0;
  float gSn = gS[n], bSn = bS[n];
  for(int i=tid; i<64*54; i+=TPB){
    int cm = i/54, l = i%54;
    int rowT = (b*Cc+cm)*Nn + n;
    float r = resid[(size_t)rowT*Tin + l];
    float v1 = (r - tm[rowT]) * tr[rowT] * gT[l] + bT[l];
    int rowS = (b*Cc+cm)*Tin + l;
    float v2 = (r - sm[rowS]) * sr[rowS] * gSn + bSn;
    sXT[l*XS + cm]        = f2bf(r);
    sXT[l*XS + 64 + cm]   = f2bf(v1);
    sXT[l*XS + 128 + cm]  = f2bf(v2);
  }
  __syncthreads();
  int lane = tid & 63, w = tid >> 6;
  int r15 = lane & 15, hi = lane >> 4;
  float b0 = bias[w*16 + r15], b1 = bias[w*16 + 64 + r15];
  f32x4 acc0[4], acc1[4];
  #pragma unroll
  for(int tt=0;tt<4;tt++){
    acc0[tt][0]=b0; acc0[tt][1]=b0; acc0[tt][2]=b0; acc0[tt][3]=b0;
    acc1[tt][0]=b1; acc1[tt][1]=b1; acc1[tt][2]=b1; acc1[tt][3]=b1;
  }
  const ushort* wp0 = WF + ((size_t)w*18)*512 + lane*8;
  const ushort* wp1 = WF + ((size_t)(w+4)*18)*512 + lane*8;
  #pragma unroll 2
  for(int ks=0; ks<18; ks++){
    int k0 = ks*32 + hi*8;
    int kt = k0/192, ci0 = k0 - kt*192;
    bf16x8 bw0 = *(const bf16x8*)&wp0[(size_t)ks*512];
    bf16x8 bw1 = *(const bf16x8*)&wp1[(size_t)ks*512];
    #pragma unroll
    for(int tt=0;tt<4;tt++){
      bf16x8 ax = *(const bf16x8*)&sXT[(tt*16 + r15 + 2*kt)*XS + ci0];
      acc0[tt] = __builtin_amdgcn_mfma_f32_16x16x32_bf16(ax, bw0, acc0[tt], 0,0,0);
      acc1[tt] = __builtin_amdgcn_mfma_f32_16x16x32_bf16(ax, bw1, acc1[tt], 0,0,0);
    }
  }
  ushort* htp = HT + ((size_t)b*NPa + (size_t)n*LP)*64;
  int c = w*16 + r15;
  #pragma unroll
  for(int tt=0;tt<4;tt++){
    int t0 = tt*16 + hi*4;
    #pragma unroll
    for(int i=0;i<4;i++){
      int t = t0 + i;
      if(t < L50) htp[(size_t)t*64 + c] = f2bf(tanhf(acc0[tt][i])*sigm(acc1[tt][i]));
    }
  }
  if(tid < 128){ int cz = tid >> 1, tz = 50 + (tid & 1); htp[(size_t)tz*64 + cz] = 0; }
}

// ---------------- zero HT padding rows p in [NP, NPa) ----------------
__global__ __launch_bounds__(TPB) void k_htpad(ushort* __restrict__ HT){
  int i = blockIdx.x*TPB + threadIdx.x;
  int per = (NPa-NP)*8;                           // 8 uint4 per row of 64 ushorts
  if(i >= Bx*per) return;
  int b = i / per, r = i % per;
  uint4 z; z.x=0;z.y=0;z.z=0;z.w=0;
  *(uint4*)&HT[((size_t)b*NPa + NP)*64 + (size_t)r*8] = z;
}

// ---------------- gated multi-basis GCN einsum via MFMA; bf16 in AND out ----------------
// TR=0: input XT bf16 [b][NPa][64] (p-major, MFMA-ready); TR=1: input bf16 [b][64][NP] (c-major, transpose-stage)
template<int D, int TR>
__global__ __launch_bounds__(TPB) void k_gcs_mfma(const ushort* __restrict__ XT,
    const ushort* __restrict__ wqF, const ushort* __restrict__ wvF,
    ushort* __restrict__ S){
  constexpr int Dt = D/16;
  int p0 = blockIdx.x*64;
  int b = blockIdx.z;
  int tid = threadIdx.x;
  int lane = tid & 63, w = tid >> 6;
  int d0 = blockIdx.y*64 + (w<<4);
  int dTile = blockIdx.y*4 + w;
  __shared__ __align__(16) ushort sX[64*64];
  if constexpr(TR){
    __shared__ __align__(16) ushort sT2[64*66];
    for(int i=tid;i<4096;i+=TPB){ int c=i>>6, col=i&63; int p=p0+col;
      sT2[c*66+col] = (p<NP) ? XT[((size_t)(b*64+c))*NP + p] : (ushort)0; }
    __syncthreads();
    for(int i=tid;i<512;i+=TPB){
      int row=i>>3, c8=(i&7)<<3;
      ushort u[8];
      #pragma unroll
      for(int j=0;j<8;j++) u[j] = sT2[(c8+j)*66 + row];
      *(uint4*)&sX[row*64 + (c8 ^ ((row&7)<<3))] = *(uint4*)u;
    }
  } else {
    for(int i=tid;i<512;i+=TPB){
      int row=i>>3, c8=(i&7)<<3;
      uint4 v = *(const uint4*)&XT[((size_t)b*NPa + p0 + row)*64 + c8];
      *(uint4*)&sX[row*64 + (c8 ^ ((row&7)<<3))] = v;
    }
  }
  __syncthreads();
  int r15 = lane & 15, hi = lane >> 4;
  bf16x8 bf[4][2];
  #pragma unroll
  for(int pt=0;pt<4;pt++){
    int row = pt*16 + r15;
    int sw = (row&7)<<3;
    int cu0 = hi*8;
    bf[pt][0] = *(const bf16x8*)&sX[row*64 + (cu0 ^ sw)];
    bf[pt][1] = *(const bf16x8*)&sX[row*64 + ((cu0+32) ^ sw)];
  }
  f32x4 acc[4];
  #pragma unroll
  for(int pt=0;pt<4;pt++){ acc[pt][0]=0.f; acc[pt][1]=0.f; acc[pt][2]=0.f; acc[pt][3]=0.f; }
  const ushort* wqp = wqF + ((size_t)dTile*2)*512 + lane*8;
  const ushort* wvp = wvF + ((size_t)dTile*2)*512 + lane*8;
  for(int k=0;k<Kb;k++){
    bf16x8 aq0 = *(const bf16x8*)&wqp[0];
    bf16x8 aq1 = *(const bf16x8*)&wqp[512];
    bf16x8 av0 = *(const bf16x8*)&wvp[0];
    bf16x8 av1 = *(const bf16x8*)&wvp[512];
    wqp += (size_t)Dt*2*512; wvp += (size_t)Dt*2*512;
    #pragma unroll
    for(int pt=0;pt<4;pt++){
      f32x4 q; q[0]=0.f;q[1]=0.f;q[2]=0.f;q[3]=0.f;
      f32x4 v; v[0]=0.f;v[1]=0.f;v[2]=0.f;v[3]=0.f;
      q = __builtin_amdgcn_mfma_f32_16x16x32_bf16(aq0, bf[pt][0], q, 0,0,0);
      q = __builtin_amdgcn_mfma_f32_16x16x32_bf16(aq1, bf[pt][1], q, 0,0,0);
      v = __builtin_amdgcn_mfma_f32_16x16x32_bf16(av0, bf[pt][0], v, 0,0,0);
      v = __builtin_amdgcn_mfma_f32_16x16x32_bf16(av1, bf[pt][1], v, 0,0,0);
      #pragma unroll
      for(int i=0;i<4;i++) acc[pt][i] += v[i]*sigm(q[i]);
    }
  }
  #pragma unroll
  for(int pt=0;pt<4;pt++){
    int p = p0 + pt*16 + r15;
    if(p < NP){
      #pragma unroll
      for(int i=0;i<4;i++){
        int d = d0 + hi*4 + i;
        S[((size_t)b*D + d)*NP + p] = f2bf(acc[pt][i]);
      }
    }
  }
}

// ---------------- adjacency aggregation via MFMA; bf16 in AND out ----------------
template<int RELU>
__global__ __launch_bounds__(TPB) void k_agg_mfma(const ushort* __restrict__ S, const ushort* __restrict__ adjF,
                                                  const float* __restrict__ bias, ushort* __restrict__ Out, int D){
  int d = blockIdx.x, b = blockIdx.y;
  int bd = b*D + d;
  constexpr int SST = 232;
  __shared__ __align__(16) ushort sB[64*SST];
  int tid = threadIdx.x;
  for(int i=tid*8; i<64*SST; i+=TPB*8){ uint4 z; z.x=0;z.y=0;z.z=0;z.w=0; *(uint4*)&sB[i]=z; }
  __syncthreads();
  const ushort* Sp = S + (size_t)bd*NP;
  for(int i=tid; i<NP; i+=TPB){
    int nn = i/52, l = i - nn*52;
    sB[l*SST + nn] = Sp[i];
  }
  __syncthreads();
  int lane = tid & 63, w = tid >> 6;
  int r15 = lane & 15, hi = lane >> 4;
  float bb = bias[d];
  ushort* Op = Out + (size_t)bd*NP;
  for(int k2t = w; k2t < 13; k2t += 4){
    f32x4 acc[4];
    #pragma unroll
    for(int lt=0;lt<4;lt++){ acc[lt][0]=0;acc[lt][1]=0;acc[lt][2]=0;acc[lt][3]=0; }
    #pragma unroll
    for(int ks=0; ks<7; ks++){
      bf16x8 a = *(const bf16x8*)&adjF[((size_t)(k2t*7 + ks))*512 + lane*8];
      #pragma unroll
      for(int lt=0;lt<4;lt++){
        bf16x8 bfr = *(const bf16x8*)&sB[(lt*16+r15)*SST + ks*32 + hi*8];
        acc[lt] = __builtin_amdgcn_mfma_f32_16x16x32_bf16(a, bfr, acc[lt], 0,0,0);
      }
    }
    #pragma unroll
    for(int lt=0;lt<4;lt++){
      #pragma unroll
      for(int i2=0;i2<4;i2++){
        int k2 = k2t*16 + hi*4 + i2;
        int l  = lt*16 + r15;
        if(k2 < Nn && l < LP){
          float v = acc[lt][i2] + bb;
          if(RELU) v = fmaxf(v, 0.f);
          Op[(size_t)k2*LP + l] = f2bf(v);
        }
      }
    }
  }
}

// ---------------- fused MLP conv over all 3 layers; inputs RB0/1/2 bf16 [b][128][NP]; no GACC ----------------
__global__ __launch_bounds__(TPB) void k_mlp_all(const ushort* __restrict__ RB0, const ushort* __restrict__ RB1,
                                                 const ushort* __restrict__ RB2, const ushort* __restrict__ WF,
                                                 const float* __restrict__ bm, float* __restrict__ gg){
  int n = blockIdx.x, b = blockIdx.y;
  constexpr int CS = 136;
  __shared__ __align__(16) ushort sLT[3*52*CS];
  int tid = threadIdx.x;
  {
    const ushort* Rp = RB0;
    for(int i=tid;i<6656;i+=TPB){ int c=i/52, l=i%52; sLT[0*52*CS + l*CS + c] = Rp[(((size_t)b*128+c)*Nn + n)*LP + l]; }
    Rp = RB1;
    for(int i=tid;i<6656;i+=TPB){ int c=i/52, l=i%52; sLT[1*52*CS + l*CS + c] = Rp[(((size_t)b*128+c)*Nn + n)*LP + l]; }
    Rp = RB2;
    for(int i=tid;i<6656;i+=TPB){ int c=i/52, l=i%52; sLT[2*52*CS + l*CS + c] = Rp[(((size_t)b*128+c)*Nn + n)*LP + l]; }
  }
  __syncthreads();
  int lane = tid & 63, w = tid >> 6;
  int r15 = lane & 15, hi = lane >> 4;
  f32x4 acc0[3], acc1[3];
  #pragma unroll
  for(int tt=0;tt<3;tt++){
    acc0[tt][0]=0;acc0[tt][1]=0;acc0[tt][2]=0;acc0[tt][3]=0;
    acc1[tt][0]=0;acc1[tt][1]=0;acc1[tt][2]=0;acc1[tt][3]=0;
  }
  #pragma unroll
  for(int layer=0; layer<3; layer++){
    const ushort* wp0 = WF + ((size_t)(layer*8 + w)*12)*512 + lane*8;
    const ushort* wp1 = WF + ((size_t)(layer*8 + w+4)*12)*512 + lane*8;
    const ushort* sL = &sLT[layer*52*CS];
    #pragma unroll 3
    for(int ks=0; ks<12; ks++){
      int kt = ks>>2, ci0 = (ks&3)*32 + hi*8;
      bf16x8 bw0 = *(const bf16x8*)&wp0[(size_t)ks*512];
      bf16x8 bw1 = *(const bf16x8*)&wp1[(size_t)ks*512];
      #pragma unroll
      for(int tt=0;tt<3;tt++){
        bf16x8 ax = *(const bf16x8*)&sL[(tt*16 + r15 + kt)*CS + ci0];
        acc0[tt] = __builtin_amdgcn_mfma_f32_16x16x32_bf16(ax, bw0, acc0[tt], 0,0,0);
        acc1[tt] = __builtin_amdgcn_mfma_f32_16x16x32_bf16(ax, bw1, acc1[tt], 0,0,0);
      }
    }
  }
  int o = w*16 + r15;
  float b0 = bm[o], b1 = bm[o+64];
  float* ggp = gg + (((size_t)b*Cc + o)*Nn + n)*(size_t)Tout;
  #pragma unroll
  for(int tt=0;tt<3;tt++){
    #pragma unroll
    for(int i2=0;i2<4;i2++){
      int tq = tt*16 + hi*4 + i2;
      float a  = acc0[tt][i2] + b0;
      float g2 = acc1[tt][i2] + b1;
      ggp[tq] = tanhf(a)*sigm(g2);
    }
  }
}

// ---------------- patch scramble + emb ----------------
__global__ __launch_bounds__(TPB) void k_xe(const float* __restrict__ gg, const float* __restrict__ emb, float* __restrict__ xe){
  size_t i = (size_t)blockIdx.x*TPB + threadIdx.x;
  if(i >= (size_t)Bx*1271808) return;
  int b = (int)(i / 1271808);
  int off = (int)(i % 1271808);
  int c = off / 19872; int r = off % 19872;
  int n = r / 96; int r2 = r % 96;
  int p = r2 >> 3; int j = r2 & 7;
  int t = p*4 + j;
  float v = 0.f;
  if(t < Tout) v = gg[(((size_t)b*Cc+c)*Nn + n)*Tout + t];
  int e = off & 511; int p2 = (off >> 9) % 12;
  xe[i] = v + emb[(size_t)p2*Ee + e];
}

// ---------------- per-row LN helper (rows of 512, stride SRDF, in LDS); NW waves ----------------
template<int NW>
__device__ __forceinline__ void ln_rows(float* buf, const float* __restrict__ g, const float* __restrict__ be, int tid){
  int lane = tid & 63, wv = tid >> 6;
  for(int r = wv; r < 12; r += NW){
    float s=0.f, s2=0.f;
    #pragma unroll
    for(int j=0;j<8;j++){ float v = buf[r*SRDF + j*64 + lane]; s+=v; s2+=v*v; }
    #pragma unroll
    for(int off=32; off; off>>=1){ s += __shfl_xor(s,off); s2 += __shfl_xor(s2,off); }
    float m = s*(1.f/512.f);
    float rstd = rsqrtf(fmaxf(s2*(1.f/512.f)-m*m, 0.f)+EPSF);
    #pragma unroll
    for(int j=0;j<8;j++){ int e = j*64+lane; float v = buf[r*SRDF+e];
      buf[r*SRDF+e] = (v-m)*rstd*g[e] + be[e]; }
  }
}

// ---------------- fused per-(b,n) transformer, MFMA GEMM phases; 512 threads (8 waves) ----------------
__global__ __launch_bounds__(TPA,2) void k_attn(
    const float* __restrict__ xe, const float* __restrict__ resid,
    const ushort* __restrict__ WqF, const float* __restrict__ bq,
    const ushort* __restrict__ WkF, const float* __restrict__ bk,
    const ushort* __restrict__ WvF, const float* __restrict__ bv,
    const ushort* __restrict__ WfcF, const float* __restrict__ bfc,
    const float* __restrict__ g1, const float* __restrict__ b1n,
    const float* __restrict__ g2, const float* __restrict__ b2n,
    const ushort* __restrict__ Wff1F, const float* __restrict__ bff1,
    const ushort* __restrict__ Wff2F, const float* __restrict__ bff2,
    const float* __restrict__ Wrp, const float* __restrict__ brp,
    float* __restrict__ y)
{
  int n = blockIdx.x, b = blockIdx.y;
  __shared__ __align__(16) ushort SbX[16*512];
  __shared__ __align__(16) ushort Mb[16*256];
  __shared__ __align__(16) float U0[12*SRDF];
  __shared__ __align__(16) float U1[12*SRDF];
  __shared__ __align__(16) float sS[1160];
  int tid = threadIdx.x;
  int lane = tid & 63, w = tid >> 6;          // w in [0,8)
  int r15 = lane & 15, hi = lane >> 4;
  const float* __restrict__ xeg = xe + ((size_t)b*Nn + n)*6144;

  for(int i=tid;i<1024;i+=TPA){
    int r = i>>6, ch = i&63;
    ushort u[8];
    if(r<12){
      const float* s = &xeg[r*512 + ch*8];
      #pragma unroll
      for(int j=0;j<8;j++) u[j] = f2bf(s[j]);
    } else {
      #pragma unroll
      for(int j=0;j<8;j++) u[j] = 0;
    }
    *(uint4*)&SbX[r*512 + ((ch ^ (r&7))<<3)] = *(uint4*)u;
  }
  for(int i=tid;i<128;i+=TPA){
    int r = 12 + (i>>5), ch = i&31;
    uint4 z; z.x=0;z.y=0;z.z=0;z.w=0;
    *(uint4*)&Mb[r*256 + ch*8] = z;
  }
  __syncthreads();

  // QKV: one head per wave
  f32x4 vfrag[4];
  {
    int head = w;
    bf16x8 a0, a1;
    { int ch0 = head*8 + hi, ch1 = head*8 + 4 + hi;
      a0 = *(const bf16x8*)&SbX[r15*512 + ((ch0 ^ (r15&7))<<3)];
      a1 = *(const bf16x8*)&SbX[r15*512 + ((ch1 ^ (r15&7))<<3)]; }
    #pragma unroll
    for(int nt=0;nt<4;nt++){
      int col = nt*16 + r15;
      float bb = bq[col];
      f32x4 acc; acc[0]=bb;acc[1]=bb;acc[2]=bb;acc[3]=bb;
      acc = __builtin_amdgcn_mfma_f32_16x16x32_bf16(a0, *(const bf16x8*)&WqF[(size_t)(nt*2+0)*512 + lane*8], acc, 0,0,0);
      acc = __builtin_amdgcn_mfma_f32_16x16x32_bf16(a1, *(const bf16x8*)&WqF[(size_t)(nt*2+1)*512 + lane*8], acc, 0,0,0);
      #pragma unroll
      for(int i2=0;i2<4;i2++){ int p = hi*4+i2; if(p<12) U0[p*SRDF + head*64 + col] = acc[i2]; }
    }
    #pragma unroll
    for(int nt=0;nt<4;nt++){
      int col = nt*16 + r15;
      float bb = bk[col];
      f32x4 acc; acc[0]=bb;acc[1]=bb;acc[2]=bb;acc[3]=bb;
      acc = __builtin_amdgcn_mfma_f32_16x16x32_bf16(a0, *(const bf16x8*)&WkF[(size_t)(nt*2+0)*512 + lane*8], acc, 0,0,0);
      acc = __builtin_amdgcn_mfma_f32_16x16x32_bf16(a1, *(const bf16x8*)&WkF[(size_t)(nt*2+1)*512 + lane*8], acc, 0,0,0);
      #pragma unroll
      for(int i2=0;i2<4;i2++){ int p = hi*4+i2; if(p<12) U1[p*SRDF + head*64 + col] = acc[i2]; }
    }
    #pragma unroll
    for(int nt=0;nt<4;nt++){
      int col = nt*16 + r15;
      float bb = bv[col];
      f32x4 acc; acc[0]=bb;acc[1]=bb;acc[2]=bb;acc[3]=bb;
      acc = __builtin_amdgcn_mfma_f32_16x16x32_bf16(a0, *(const bf16x8*)&WvF[(size_t)(nt*2+0)*512 + lane*8], acc, 0,0,0);
      acc = __builtin_amdgcn_mfma_f32_16x16x32_bf16(a1, *(const bf16x8*)&WvF[(size_t)(nt*2+1)*512 + lane*8], acc, 0,0,0);
      vfrag[nt] = acc;
    }
  }
  __syncthreads();

  const float scale = 0.04419417382415922f;   // 1/sqrt(512)
  for(int i=tid;i<1152;i+=TPA){
    int q = i%12, kh = i/12; int h2 = kh&7, k2 = kh>>3;
    const float* qp = &U0[q*SRDF + h2*64];
    const float* kp = &U1[k2*SRDF + h2*64];
    float s=0.f;
    #pragma unroll
    for(int d4=0; d4<16; d4++){
      float4 a4 = *(const float4*)&qp[d4*4];
      float4 b4 = *(const float4*)&kp[d4*4];
      s += a4.x*b4.x + a4.y*b4.y + a4.z*b4.z + a4.w*b4.w;
    }
    sS[i] = s*scale;
  }
  __syncthreads();
  {
    int head = w;
    #pragma unroll
    for(int nt=0;nt<4;nt++){
      int col = nt*16 + r15;
      #pragma unroll
      for(int i2=0;i2<4;i2++){ int p = hi*4+i2; if(p<12) U0[p*SRDF + head*64 + col] = vfrag[nt][i2]; }
    }
  }
  if(tid<96){
    float mx=-1e30f;
    for(int q=0;q<12;q++) mx = fmaxf(mx, sS[tid*12+q]);
    float sm=0.f;
    for(int q=0;q<12;q++){ float e = __expf(sS[tid*12+q]-mx); sS[tid*12+q]=e; sm+=e; }
    float inv = 1.f/sm;
    for(int q=0;q<12;q++) sS[tid*12+q] *= inv;
  }
  __syncthreads();

  for(int i=tid;i<6144;i+=TPA){
    int q=i>>9, h2=(i>>6)&7, d=i&63;
    float s=0.f;
    #pragma unroll
    for(int k2=0;k2<12;k2++) s += sS[(k2*8+h2)*12+q]*U0[k2*SRDF+h2*64+d];
    int kk = i & 511;
    SbX[q*512 + (((kk>>3) ^ (q&7))<<3) + (kk&7)] = f2bf(s);
  }
  __syncthreads();

  // fc: 32 col-tiles, 4 per wave
  {
    f32x4 acc[4];
    #pragma unroll
    for(int nt=0;nt<4;nt++){ float bb = bfc[(w*4+nt)*16 + r15]; acc[nt][0]=bb;acc[nt][1]=bb;acc[nt][2]=bb;acc[nt][3]=bb; }
    for(int ks=0;ks<16;ks++){
      int ch = ks*4 + hi;
      bf16x8 a = *(const bf16x8*)&SbX[r15*512 + ((ch ^ (r15&7))<<3)];
      #pragma unroll
      for(int nt=0;nt<4;nt++){
        acc[nt] = __builtin_amdgcn_mfma_f32_16x16x32_bf16(a, *(const bf16x8*)&WfcF[(size_t)((w*4+nt)*16 + ks)*512 + lane*8], acc[nt], 0,0,0);
      }
    }
    #pragma unroll
    for(int nt=0;nt<4;nt++){
      int col = (w*4+nt)*16 + r15;
      #pragma unroll
      for(int i2=0;i2<4;i2++){ int p = hi*4+i2; if(p<12) U1[p*SRDF + col] = acc[nt][i2] + xeg[p*512 + col]; }
    }
  }
  __syncthreads();
  ln_rows<8>(U1, g1, b1n, tid);     // M in U1
  __syncthreads();

  for(int i=tid;i<6144;i+=TPA){
    int r=i>>9, kk=i&511;
    SbX[r*512 + (((kk>>3) ^ (r&7))<<3) + (kk&7)] = f2bf(U1[r*SRDF + kk]);
  }
  __syncthreads();

  // ff1: 16 col-tiles, 2 per wave
  {
    f32x4 acc[2];
    #pragma unroll
    for(int nt=0;nt<2;nt++){ float bb = bff1[(w*2+nt)*16 + r15]; acc[nt][0]=bb;acc[nt][1]=bb;acc[nt][2]=bb;acc[nt][3]=bb; }
    for(int ks=0;ks<16;ks++){
      int ch = ks*4 + hi;
      bf16x8 a = *(const bf16x8*)&SbX[r15*512 + ((ch ^ (r15&7))<<3)];
      #pragma unroll
      for(int nt=0;nt<2;nt++){
        acc[nt] = __builtin_amdgcn_mfma_f32_16x16x32_bf16(a, *(const bf16x8*)&Wff1F[(size_t)((w*2+nt)*16 + ks)*512 + lane*8], acc[nt], 0,0,0);
      }
    }
    #pragma unroll
    for(int nt=0;nt<2;nt++){
      int u = (w*2+nt)*16 + r15;
      #pragma unroll
      for(int i2=0;i2<4;i2++){
        int p = hi*4+i2;
        if(p<12) Mb[p*256 + (((u>>3) ^ (p&7))<<3) + (u&7)] = f2bf(fmaxf(acc[nt][i2], 0.f));
      }
    }
  }
  __syncthreads();

  // ff2: 32 col-tiles, 4 per wave
  {
    f32x4 acc[4];
    #pragma unroll
    for(int nt=0;nt<4;nt++){ float bb = bff2[(w*4+nt)*16 + r15]; acc[nt][0]=bb;acc[nt][1]=bb;acc[nt][2]=bb;acc[nt][3]=bb; }
    for(int ks=0;ks<8;ks++){
      int ch = ks*4 + hi;
      bf16x8 a = *(const bf16x8*)&Mb[r15*256 + ((ch ^ (r15&7))<<3)];
      #pragma unroll
      for(int nt=0;nt<4;nt++){
        acc[nt] = __builtin_amdgcn_mfma_f32_16x16x32_bf16(a, *(const bf16x8*)&Wff2F[(size_t)((w*4+nt)*8 + ks)*512 + lane*8], acc[nt], 0,0,0);
      }
    }
    #pragma unroll
    for(int nt=0;nt<4;nt++){
      int col = (w*4+nt)*16 + r15;
      #pragma unroll
      for(int i2=0;i2<4;i2++){ int p = hi*4+i2; if(p<12) U0[p*SRDF + col] = acc[nt][i2] + U1[p*SRDF + col]; }
    }
  }
  __syncthreads();
  ln_rows<8>(U0, g2, b2n, tid);     // U in U0
  __syncthreads();

  for(int i=tid;i<6144;i+=TPA){
    int r=i>>9, c=i&511;
    U1[r*SRDF+c] = U0[r*SRDF+c] + U1[r*SRDF+c] + xeg[r*512+c];
  }
  __syncthreads();
  for(int i=tid;i<4608;i+=TPA) U0[i] = Wrp[i];
  __syncthreads();
  #pragma unroll
  for(int j=0;j<2;j++){
    int i4 = tid + j*TPA;
    if(i4 < 768){
      int c = i4/12, tq = i4%12; int t0 = tq*4;
      float4 acc = *(const float4*)&brp[t0];
      for(int t96=0;t96<96;t96++){
        int f = c*96 + t96;
        float a = U1[(f>>9)*SRDF + (f&511)];
        float4 w4 = *(const float4*)&U0[t96*48 + t0];
        FMA4(acc, a, w4);
      }
      size_t rb = (((size_t)b*Cc+c)*Nn + n)*Tin + 6 + t0;
      acc.x += resid[rb+0]; acc.y += resid[rb+1]; acc.z += resid[rb+2]; acc.w += resid[rb+3];
      *(float4*)&y[(((size_t)b*Cc+c)*Nn + n)*Tout + t0] = acc;
    }
  }
}

// ---------------- batchnorm ----------------
__global__ __launch_bounds__(TPB) void k_bnstats(const float* __restrict__ y, float* __restrict__ stats){
  int c = blockIdx.x; int tid = threadIdx.x;
  float s=0.f,s2=0.f;
  const int per = Nn*Tout;   // 9936
  for(int idx=tid; idx<Bx*per; idx+=TPB){
    int b = idx/per, r = idx%per;
    float v = y[((size_t)b*Cc+c)*per + r];
    s+=v; s2+=v*v;
  }
  __shared__ float rs[TPB], rs2[TPB];
  rs[tid]=s; rs2[tid]=s2; __syncthreads();
  for(int off=TPB/2; off; off>>=1){ if(tid<off){ rs[tid]+=rs[tid+off]; rs2[tid]+=rs2[tid+off]; } __syncthreads(); }
  if(tid==0){
    float m = rs[0]/(float)(Bx*per);
    float var = rs2[0]/(float)(Bx*per) - m*m;
    stats[c]=m; stats[64+c]=rsqrtf(fmaxf(var,0.f)+EPSF);
  }
}
__global__ __launch_bounds__(TPB) void k_bnout(const float* __restrict__ y, const float* __restrict__ stats,
                                               const float* __restrict__ gbn, const float* __restrict__ bbn,
                                               float* __restrict__ out){
  size_t i = (size_t)blockIdx.x*TPB + threadIdx.x;
  if(i >= (size_t)Bx*Cc*Nn*Tout) return;
  int c = (int)((i/(Nn*Tout))%Cc);
  out[i] = (y[i]-stats[c])*stats[64+c]*gbn[c] + bbn[c];
}

// ---------------- launch ----------------
extern "C" void kernel_launch(void* const* d_in, const int* in_sizes, int n_in,
                              void* d_out, int out_size, void* d_ws, size_t ws_size,
                              hipStream_t stream) {
  const float* x      = (const float*)d_in[0];
  const float* adj    = (const float*)d_in[1];
  const float* Wconv1 = (const float*)d_in[2];
  const float* bconv1 = (const float*)d_in[3];
  const float* gT     = (const float*)d_in[4];
  const float* bT     = (const float*)d_in[5];
  const float* gS     = (const float*)d_in[6];
  const float* bS     = (const float*)d_in[7];
  const float* Wtime  = (const float*)d_in[8];
  const float* btime  = (const float*)d_in[9];
  const float* wq1    = (const float*)d_in[10];
  const float* wv1    = (const float*)d_in[11];
  const float* bias1  = (const float*)d_in[12];
  const float* wq2    = (const float*)d_in[13];
  const float* wv2    = (const float*)d_in[14];
  const float* bias2  = (const float*)d_in[15];
  const float* Wmlp   = (const float*)d_in[16];
  const float* bmlp   = (const float*)d_in[17];
  const float* embT   = (const float*)d_in[18];
  const float* Wq     = (const float*)d_in[19];
  const float* bq     = (const float*)d_in[20];
  const float* Wk     = (const float*)d_in[21];
  const float* bk     = (const float*)d_in[22];
  const float* Wv     = (const float*)d_in[23];
  const float* bv     = (const float*)d_in[24];
  const float* Wfc    = (const float*)d_in[25];
  const float* bfc    = (const float*)d_in[26];
  const float* g1     = (const float*)d_in[27];
  const float* b1n    = (const float*)d_in[28];
  const float* g2     = (const float*)d_in[29];
  const float* b2n    = (const float*)d_in[30];
  const float* Wff1   = (const float*)d_in[31];
  const float* bff1   = (const float*)d_in[32];
  const float* Wff2   = (const float*)d_in[33];
  const float* bff2   = (const float*)d_in[34];
  const float* Wrp    = (const float*)d_in[35];
  const float* brp    = (const float*)d_in[36];
  const float* gbn    = (const float*)d_in[37];
  const float* bbn    = (const float*)d_in[38];

  float* ws = (float*)d_ws;
  float* RESID = ws + O_RESID;
  float* LNTM  = ws + O_LNTM;
  float* LNTR  = ws + O_LNTR;
  float* LNSM  = ws + O_LNSM;
  float* LNSR  = ws + O_LNSR;
  ushort* RA   = (ushort*)(ws + O_XCAT);                 // bf16 [B][128][NP] max (lower half of region)
  ushort* RB2  = RA + (size_t)Bx*128*NP;                 // bf16 [B][128][NP] (upper half; ends at O_TAIL)
  ushort* RB0  = (ushort*)(ws + O_RB);                   // bf16 [B][128][NP]
  ushort* RB1  = RB0 + (size_t)Bx*128*NP;                // bf16 [B][128][NP] (fills O_RB region exactly)
  ushort* S1   = (ushort*)(ws + O_GACC);                 // bf16 [B][64][NP] scratch (agg64 out)
  float* GG    = ws + O_GG;
  float* Y     = ws + O_GG;      // overlays GG (safe: GG dead after k_xe builds XE)
  float* XE    = ws + O_XE;
  float* BNST  = ws + O_BNST;
  ushort* WTMF = (ushort*)(ws + O_WTM);
  ushort* WTB  = (ushort*)(ws + O_WTB);
  ushort* ADJT = (ushort*)(ws + O_ADJT);
  ushort* HT   = (ushort*)(ws + O_HT);   // in dead H region
  ushort* WQ1B = (ushort*)(ws + O_WQ1B);
  ushort* WV1B = (ushort*)(ws + O_WV1B);
  ushort* WQ2B = (ushort*)(ws + O_WQ2B);
  ushort* WV2B = (ushort*)(ws + O_WV2B);
  ushort* WQT  = (ushort*)(ws + O_WQT);
  ushort* WKT  = (ushort*)(ws + O_WKT);
  ushort* WVT  = (ushort*)(ws + O_WVT);
  ushort* WFCT = (ushort*)(ws + O_WFCT);
  ushort* WF1T = (ushort*)(ws + O_WF1T);
  ushort* WF2T = (ushort*)(ws + O_WF2T);

  k_residual<<<dim3(Nn,Bx),TPB,0,stream>>>(x, Wconv1, bconv1, RESID, LNTM, LNTR);
  k_lnS<<<(Bx*Cc*Tin)/TPB,TPB,0,stream>>>(RESID, LNSM, LNSR);
  k_wtbF<<<(8*18*512+TPB-1)/TPB,TPB,0,stream>>>(Wtime, WTB);
  k_wmlpF<<<(3*8*12*512+TPB-1)/TPB,TPB,0,stream>>>(Wmlp, WTMF);
  k_htpad<<<(Bx*(NPa-NP)*8+TPB-1)/TPB,TPB,0,stream>>>(HT);
  // fused xcat + timeconv (reads RESID + LN stats directly)
  k_timeconv_mfma<<<dim3(Nn,Bx),TPB,0,stream>>>(RESID, LNTM, LNTR, LNSM, LNSR, gT, bT, gS, bS,
                                                WTB, btime, HT);

  // merged fragment-order weight converts (11 jobs, one dispatch)
  WJobs jobs;
  jobs.j[0]  = { wq1,  WQ1B, 64,  64,  2,  4,  64*64,   24*4*2*512 };
  jobs.j[1]  = { wv1,  WV1B, 64,  64,  2,  4,  64*64,   24*4*2*512 };
  jobs.j[2]  = { wq2,  WQ2B, 64,  128, 2,  8,  64*128,  24*8*2*512 };
  jobs.j[3]  = { wv2,  WV2B, 64,  128, 2,  8,  64*128,  24*8*2*512 };
  jobs.j[4]  = { Wq,   WQT,  64,  64,  2,  4,  64*64,   4*2*512 };
  jobs.j[5]  = { Wk,   WKT,  64,  64,  2,  4,  64*64,   4*2*512 };
  jobs.j[6]  = { Wv,   WVT,  64,  64,  2,  4,  64*64,   4*2*512 };
  jobs.j[7]  = { Wfc,  WFCT, 512, 512, 16, 32, 512*512, 32*16*512 };
  jobs.j[8]  = { Wff1, WF1T, 512, 256, 16, 16, 512*256, 16*16*512 };
  jobs.j[9]  = { Wff2, WF2T, 256, 512, 8,  32, 256*512, 32*8*512 };
  jobs.j[10] = { adj,  ADJT, 207, 207, 7,  13, Nn*Nn,   3*13*7*512 };
  int totalW = 2*(24*4*2*512) + 2*(24*8*2*512) + 3*(4*2*512) + 32*16*512 + 16*16*512 + 32*8*512 + 3*13*7*512;
  k_wfrag_all<<<(totalW+TPB-1)/TPB,TPB,0,stream>>>(jobs);

  ushort* RBv[3] = { RB0, RB1, RB2 };
  for(int i=0;i<3;i++){
    k_gcs_mfma<64,0><<<dim3(169,1,Bx),TPB,0,stream>>>(HT, WQ1B+(size_t)i*8*4*2*512, WV1B+(size_t)i*8*4*2*512, RA);
    k_agg_mfma<1><<<dim3(64,Bx),TPB,0,stream>>>(RA, ADJT+(size_t)i*13*7*512, bias1+(size_t)i*64, S1, 64);
    k_gcs_mfma<128,1><<<dim3(169,2,Bx),TPB,0,stream>>>(S1, WQ2B+(size_t)i*8*8*2*512, WV2B+(size_t)i*8*8*2*512, RA);
    k_agg_mfma<0><<<dim3(128,Bx),TPB,0,stream>>>(RA, ADJT+(size_t)i*13*7*512, bias2+(size_t)i*128, RBv[i], 128);
  }
  k_mlp_all<<<dim3(Nn,Bx),TPB,0,stream>>>(RB0, RB1, RB2, WTMF, bmlp, GG);
  k_xe<<<(Bx*1271808)/TPB,TPB,0,stream>>>(GG, embT, XE);
  k_attn<<<dim3(Nn,Bx),TPA,0,stream>>>(XE, RESID, WQT,bq, WKT,bk, WVT,bv, WFCT,bfc,
                                       g1,b1n,g2,b2n, WF1T,bff1, WF2T,bff2, Wrp,brp, Y);
  k_bnstats<<<64,TPB,0,stream>>>(Y, BNST);
  k_bnout<<<(Bx*Cc*Nn*Tout)/TPB,TPB,0,stream>>>(Y, BNST, gbn, bbn, (float*)d_out);
}

// Round 25
// 797.665 us; speedup vs baseline: 1.1900x; 1.0762x over previous
//
#include <hip/hip_runtime.h>
#include <hip/hip_bf16.h>

#define TPB 256
#define TPA 512

constexpr int Bx = 8, Cc = 64, Nn = 207, Tin = 54, Kb = 8;
constexpr int LP = 52, NP = Nn * LP;     // time padded 50->52, flattened node*time positions
constexpr int NPa = 10816;               // NP rounded up to 169*64 for MFMA tiles
constexpr int L50 = 50, Tout = 48;
constexpr int Ee = 512, Pn = 12;
constexpr float EPSF = 1e-5f;
constexpr int SRDF = 516;                // padded row stride for 512-wide f32 LDS rows (2-way bank pattern)

// ---------------- workspace layout (floats) ----------------
constexpr size_t O_RESID = 0;                                   // [B][64][207][54]
constexpr size_t O_LNTM  = O_RESID + (size_t)Bx*Cc*Nn*Tin;
constexpr size_t O_LNTR  = O_LNTM  + (size_t)Bx*Cc*Nn;
constexpr size_t O_LNSM  = O_LNTR  + (size_t)Bx*Cc*Nn;
constexpr size_t O_LNSR  = O_LNSM  + (size_t)Bx*Cc*Tin;
constexpr size_t O_XCAT  = O_LNSR  + (size_t)Bx*Cc*Tin;         // RA bf16 x3 slots (16.53M of 17.17M floats)
constexpr size_t O_RB    = O_XCAT  + (size_t)Bx*192*Nn*Tin;     // RB0,RB1 bf16 slots (fills region exactly)
constexpr size_t O_H     = O_RB    + (size_t)Bx*128*NP;         // HT bf16 [Bx][NPa][64]
constexpr size_t O_GACC  = O_H     + (size_t)Bx*64*NP;          // S1 bf16 x3 slots (8.27M of 10.17M)
constexpr size_t O_GG    = O_GACC  + (size_t)Bx*128*Nn*Tout;    // [B][64][207][48]; reused as Y
constexpr size_t O_XE    = O_GG    + (size_t)Bx*64*Nn*Tout;     // RB2 bf16 (first 5.51M), then XE overwrites
constexpr size_t O_WTT   = O_XE    + (size_t)Bx*Nn*Pn*Ee;       // (unused) 128*192*3
constexpr size_t O_WTM   = O_WTT   + (size_t)128*192*3;         // ushort[3*8*12*512] W_mlp frag bf16
constexpr size_t O_BNST  = O_WTM   + (size_t)128*384*3;         // 128
constexpr size_t O_WTB   = O_BNST + 128;                        // ushort[8*18*512] time-conv bf16 frag weights
constexpr size_t O_ADJT  = O_WTB  + (size_t)128*576/2;          // ushort[3][13*7*512] adj frag bf16
constexpr size_t O_HT    = O_H;                                 // ushort[Bx][NPa][64] in dead H region
// weight frag buffers relocated to high free region (after ADJT):
constexpr size_t O_WQ1B  = O_ADJT + (size_t)3*13*7*512/2;       // ushort[24*4*2*512]
constexpr size_t O_WV1B  = O_WQ1B + (size_t)24*4*2*512/2;
constexpr size_t O_WQ2B  = O_WV1B + (size_t)24*4*2*512/2;       // ushort[24*8*2*512]
constexpr size_t O_WV2B  = O_WQ2B + (size_t)24*8*2*512/2;
constexpr size_t O_WQT   = O_WV2B + (size_t)24*8*2*512/2;       // ushort[4*2*512]
constexpr size_t O_WKT   = O_WQT  + 2048;
constexpr size_t O_WVT   = O_WKT  + 2048;
constexpr size_t O_WFCT  = O_WVT  + 2048;                       // ushort[32*16*512]
constexpr size_t O_WF1T  = O_WFCT + 131072;                     // ushort[16*16*512]
constexpr size_t O_WF2T  = O_WF1T + 65536;                      // ushort[32*8*512]; ends ~65.99M < 67.1M

#define FMA4(acc, sA_, vB_) { (acc).x += (sA_)*(vB_).x; (acc).y += (sA_)*(vB_).y; (acc).z += (sA_)*(vB_).z; (acc).w += (sA_)*(vB_).w; }

typedef __attribute__((ext_vector_type(8))) short bf16x8;
typedef __attribute__((ext_vector_type(4))) float f32x4;

__device__ __forceinline__ float sigm(float x){ return 1.0f/(1.0f+__expf(-x)); }
__device__ __forceinline__ ushort f2bf(float x){ __hip_bfloat16 h = __float2bfloat16(x); return *(ushort*)&h; }

// ---------------- residual = W_conv1 @ x + b, fused lnT stats ----------------
__global__ __launch_bounds__(TPB) void k_residual(const float* __restrict__ x, const float* __restrict__ W,
                                                  const float* __restrict__ bias, float* __restrict__ out,
                                                  float* __restrict__ lnm, float* __restrict__ lnr){
  int n = blockIdx.x, b = blockIdx.y;
  __shared__ __align__(16) float sX[Cc][Tin];
  __shared__ __align__(16) float sW[Cc*Cc];
  __shared__ __align__(16) float sO[Cc][Tin];
  int tid = threadIdx.x;
  for(int i=tid;i<Cc*Tin;i+=TPB){ int c=i/Tin, l=i%Tin; sX[c][l] = x[((size_t)(b*Cc+c)*Nn+n)*Tin+l]; }
  for(int i=tid;i<Cc*Cc;i+=TPB) sW[i]=W[i];
  __syncthreads();
  for(int i=tid;i<Cc*Tin;i+=TPB){
    int o=i/Tin, l=i%Tin; float acc=bias[o];
    #pragma unroll 8
    for(int c=0;c<Cc;c++) acc += sW[o*Cc+c]*sX[c][l];
    out[((size_t)(b*Cc+o)*Nn+n)*Tin+l]=acc;
    sO[o][l]=acc;
  }
  __syncthreads();
  if(tid < Cc){
    float s=0.f,s2=0.f;
    for(int l=0;l<Tin;l++){ float v=sO[tid][l]; s+=v; s2+=v*v; }
    float m=s*(1.f/Tin); float var=s2*(1.f/Tin)-m*m;
    int row = (b*Cc+tid)*Nn + n;
    lnm[row]=m; lnr[row]=rsqrtf(fmaxf(var,0.f)+EPSF);
  }
}

// ---------------- lnS stats ----------------
__global__ __launch_bounds__(TPB) void k_lnS(const float* __restrict__ r, float* __restrict__ mean, float* __restrict__ rstd){
  int row = blockIdx.x*TPB + threadIdx.x;       // (b*Cc+c)*Tin + l
  if(row >= Bx*Cc*Tin) return;
  int l = row % Tin; int bc = row / Tin;
  const float* p = r + (size_t)bc*Nn*Tin + l;
  float s=0.f,s2=0.f;
  for(int n=0;n<Nn;n++){ float v=p[(size_t)n*Tin]; s+=v; s2+=v*v; }
  float m=s*(1.f/Nn); float var=s2*(1.f/Nn)-m*m;
  mean[row]=m; rstd[row]=rsqrtf(fmaxf(var,0.f)+EPSF);
}

// ---------------- merged fragment-order weight converter (10 jobs + adj) ----------------
struct WJob { const float* W; ushort* F; int K, N, KS, NT, sStride, total; };
struct WJobs { WJob j[11]; };

__global__ __launch_bounds__(TPB) void k_wfrag_all(WJobs jobs){
  int gi = blockIdx.x*TPB + threadIdx.x;
  for(int seg=0; seg<11; seg++){
    const WJob J = jobs.j[seg];
    if(gi < J.total){
      int i = gi;
      int j = i & 7; int lane = (i>>3) & 63;
      int t = i >> 9;
      int ks = t % J.KS; int r = t / J.KS; int colTile = r % J.NT; int s = r / J.NT;
      int r15 = lane & 15, hi = lane >> 4;
      int k = ks*32 + hi*8 + j, col = colTile*16 + r15;
      float v = (k < J.K && col < J.N) ? J.W[(size_t)s*J.sStride + (size_t)k*J.N + col] : 0.f;
      J.F[i] = f2bf(v);
      return;
    }
    gi -= J.total;
  }
}

// ---------------- time-conv weight frag convert ----------------
__global__ __launch_bounds__(TPB) void k_wtbF(const float* __restrict__ W, ushort* __restrict__ F){
  int i = blockIdx.x*TPB + threadIdx.x;
  if(i >= 8*18*512) return;
  int j = i & 7; int lane = (i>>3) & 63;
  int t = i >> 9;
  int ks = t % 18; int colTile = t / 18;
  int r15 = lane & 15, hi = lane >> 4;
  int k = ks*32 + hi*8 + j, o = colTile*16 + r15;
  int kt = k/192, ci = k - kt*192;
  F[i] = f2bf(W[(size_t)(o*192+ci)*3 + kt]);
}

// ---------------- mlp-conv weight frag convert ----------------
__global__ __launch_bounds__(TPB) void k_wmlpF(const float* __restrict__ W, ushort* __restrict__ F){
  int i = blockIdx.x*TPB + threadIdx.x;
  if(i >= 3*8*12*512) return;
  int j = i & 7; int lane = (i>>3) & 63;
  int t = i >> 9;
  int ks = t % 12; int r = t / 12; int colTile = r & 7; int layer = r >> 3;
  int r15 = lane & 15, hi = lane >> 4;
  int k = ks*32 + hi*8 + j;
  int kt = k >> 7, ci = k & 127;
  int o = colTile*16 + r15;
  F[i] = f2bf(W[(size_t)(o*384 + layer*128 + ci)*3 + kt]);
}

// ---------------- fused xcat+dilated time conv (dil=2) + GLU via MFMA -> HT bf16 [b][p][64] ----------------
__global__ __launch_bounds__(TPB) void k_timeconv_mfma(const float* __restrict__ resid,
    const float* __restrict__ tm, const float* __restrict__ tr,
    const float* __restrict__ sm, const float* __restrict__ sr,
    const float* __restrict__ gT, const float* __restrict__ bT,
    const float* __restrict__ gS, const float* __restrict__ bS,
    const ushort* __restrict__ WF, const float* __restrict__ bias, ushort* __restrict__ HT){
  int n = blockIdx.x, b = blockIdx.y;
  constexpr int XS = 200;
  __shared__ __align__(16) ushort sXT[68*XS];
  int tid = threadIdx.x;
  for(int i=tid; i<14*XS; i+=TPB) sXT[54*XS + i] = 0;
  float gSn = gS[n], bSn = bS[n];
  for(int i=tid; i<64*54; i+=TPB){
    int cm = i/54, l = i%54;
    int rowT = (b*Cc+cm)*Nn + n;
    float r = resid[(size_t)rowT*Tin + l];
    float v1 = (r - tm[rowT]) * tr[rowT] * gT[l] + bT[l];
    int rowS = (b*Cc+cm)*Tin + l;
    float v2 = (r - sm[rowS]) * sr[rowS] * gSn + bSn;
    sXT[l*XS + cm]        = f2bf(r);
    sXT[l*XS + 64 + cm]   = f2bf(v1);
    sXT[l*XS + 128 + cm]  = f2bf(v2);
  }
  __syncthreads();
  int lane = tid & 63, w = tid >> 6;
  int r15 = lane & 15, hi = lane >> 4;
  float b0 = bias[w*16 + r15], b1 = bias[w*16 + 64 + r15];
  f32x4 acc0[4], acc1[4];
  #pragma unroll
  for(int tt=0;tt<4;tt++){
    acc0[tt][0]=b0; acc0[tt][1]=b0; acc0[tt][2]=b0; acc0[tt][3]=b0;
    acc1[tt][0]=b1; acc1[tt][1]=b1; acc1[tt][2]=b1; acc1[tt][3]=b1;
  }
  const ushort* wp0 = WF + ((size_t)w*18)*512 + lane*8;
  const ushort* wp1 = WF + ((size_t)(w+4)*18)*512 + lane*8;
  #pragma unroll 2
  for(int ks=0; ks<18; ks++){
    int k0 = ks*32 + hi*8;
    int kt = k0/192, ci0 = k0 - kt*192;
    bf16x8 bw0 = *(const bf16x8*)&wp0[(size_t)ks*512];
    bf16x8 bw1 = *(const bf16x8*)&wp1[(size_t)ks*512];
    #pragma unroll
    for(int tt=0;tt<4;tt++){
      bf16x8 ax = *(const bf16x8*)&sXT[(tt*16 + r15 + 2*kt)*XS + ci0];
      acc0[tt] = __builtin_amdgcn_mfma_f32_16x16x32_bf16(ax, bw0, acc0[tt], 0,0,0);
      acc1[tt] = __builtin_amdgcn_mfma_f32_16x16x32_bf16(ax, bw1, acc1[tt], 0,0,0);
    }
  }
  ushort* htp = HT + ((size_t)b*NPa + (size_t)n*LP)*64;
  int c = w*16 + r15;
  #pragma unroll
  for(int tt=0;tt<4;tt++){
    int t0 = tt*16 + hi*4;
    #pragma unroll
    for(int i=0;i<4;i++){
      int t = t0 + i;
      if(t < L50) htp[(size_t)t*64 + c] = f2bf(tanhf(acc0[tt][i])*sigm(acc1[tt][i]));
    }
  }
  if(tid < 128){ int cz = tid >> 1, tz = 50 + (tid & 1); htp[(size_t)tz*64 + cz] = 0; }
}

// ---------------- zero HT padding rows p in [NP, NPa) ----------------
__global__ __launch_bounds__(TPB) void k_htpad(ushort* __restrict__ HT){
  int i = blockIdx.x*TPB + threadIdx.x;
  int per = (NPa-NP)*8;                           // 8 uint4 per row of 64 ushorts
  if(i >= Bx*per) return;
  int b = i / per, r = i % per;
  uint4 z; z.x=0;z.y=0;z.z=0;z.w=0;
  *(uint4*)&HT[((size_t)b*NPa + NP)*64 + (size_t)r*8] = z;
}

// ---------------- gated multi-basis GCN einsum via MFMA; all 3 layers in one dispatch ----------------
// TR=0: input XT bf16 [b][NPa][64] shared across i; TR=1: per-i input bf16 [b][64][NP] at XT+i*inSlot
template<int D, int TR>
__global__ __launch_bounds__(TPB) void k_gcs_mfma(const ushort* __restrict__ XT,
    const ushort* __restrict__ wqF, const ushort* __restrict__ wvF,
    ushort* __restrict__ S, size_t inSlot, size_t outSlot){
  constexpr int Dt = D/16;
  constexpr int nY = D/64;
  constexpr size_t WSTR = (size_t)Kb*Dt*2*512;
  int p0 = blockIdx.x*64;
  int b = blockIdx.z;
  int iy = blockIdx.y / nY;          // GCN layer index i in [0,3)
  int dblk = blockIdx.y % nY;
  int tid = threadIdx.x;
  int lane = tid & 63, w = tid >> 6;
  int d0 = dblk*64 + (w<<4);
  int dTile = dblk*4 + w;
  const ushort* wqB = wqF + iy*WSTR;
  const ushort* wvB = wvF + iy*WSTR;
  ushort* Sb = S + iy*outSlot;
  __shared__ __align__(16) ushort sX[64*64];
  if constexpr(TR){
    const ushort* Xp = XT + iy*inSlot;
    __shared__ __align__(16) ushort sT2[64*66];
    for(int i=tid;i<4096;i+=TPB){ int c=i>>6, col=i&63; int p=p0+col;
      sT2[c*66+col] = (p<NP) ? Xp[((size_t)(b*64+c))*NP + p] : (ushort)0; }
    __syncthreads();
    for(int i=tid;i<512;i+=TPB){
      int row=i>>3, c8=(i&7)<<3;
      ushort u[8];
      #pragma unroll
      for(int j=0;j<8;j++) u[j] = sT2[(c8+j)*66 + row];
      *(uint4*)&sX[row*64 + (c8 ^ ((row&7)<<3))] = *(uint4*)u;
    }
  } else {
    for(int i=tid;i<512;i+=TPB){
      int row=i>>3, c8=(i&7)<<3;
      uint4 v = *(const uint4*)&XT[((size_t)b*NPa + p0 + row)*64 + c8];
      *(uint4*)&sX[row*64 + (c8 ^ ((row&7)<<3))] = v;
    }
  }
  __syncthreads();
  int r15 = lane & 15, hi = lane >> 4;
  bf16x8 bf[4][2];
  #pragma unroll
  for(int pt=0;pt<4;pt++){
    int row = pt*16 + r15;
    int sw = (row&7)<<3;
    int cu0 = hi*8;
    bf[pt][0] = *(const bf16x8*)&sX[row*64 + (cu0 ^ sw)];
    bf[pt][1] = *(const bf16x8*)&sX[row*64 + ((cu0+32) ^ sw)];
  }
  f32x4 acc[4];
  #pragma unroll
  for(int pt=0;pt<4;pt++){ acc[pt][0]=0.f; acc[pt][1]=0.f; acc[pt][2]=0.f; acc[pt][3]=0.f; }
  const ushort* wqp = wqB + ((size_t)dTile*2)*512 + lane*8;
  const ushort* wvp = wvB + ((size_t)dTile*2)*512 + lane*8;
  for(int k=0;k<Kb;k++){
    bf16x8 aq0 = *(const bf16x8*)&wqp[0];
    bf16x8 aq1 = *(const bf16x8*)&wqp[512];
    bf16x8 av0 = *(const bf16x8*)&wvp[0];
    bf16x8 av1 = *(const bf16x8*)&wvp[512];
    wqp += (size_t)Dt*2*512; wvp += (size_t)Dt*2*512;
    #pragma unroll
    for(int pt=0;pt<4;pt++){
      f32x4 q; q[0]=0.f;q[1]=0.f;q[2]=0.f;q[3]=0.f;
      f32x4 v; v[0]=0.f;v[1]=0.f;v[2]=0.f;v[3]=0.f;
      q = __builtin_amdgcn_mfma_f32_16x16x32_bf16(aq0, bf[pt][0], q, 0,0,0);
      q = __builtin_amdgcn_mfma_f32_16x16x32_bf16(aq1, bf[pt][1], q, 0,0,0);
      v = __builtin_amdgcn_mfma_f32_16x16x32_bf16(av0, bf[pt][0], v, 0,0,0);
      v = __builtin_amdgcn_mfma_f32_16x16x32_bf16(av1, bf[pt][1], v, 0,0,0);
      #pragma unroll
      for(int i=0;i<4;i++) acc[pt][i] += v[i]*sigm(q[i]);
    }
  }
  #pragma unroll
  for(int pt=0;pt<4;pt++){
    int p = p0 + pt*16 + r15;
    if(p < NP){
      #pragma unroll
      for(int i=0;i<4;i++){
        int d = d0 + hi*4 + i;
        Sb[((size_t)b*D + d)*NP + p] = f2bf(acc[pt][i]);
      }
    }
  }
}

// ---------------- adjacency aggregation via MFMA; all 3 layers in one dispatch ----------------
template<int RELU>
__global__ __launch_bounds__(TPB) void k_agg_mfma(const ushort* __restrict__ S, const ushort* __restrict__ adjF,
                                                  const float* __restrict__ bias,
                                                  ushort* __restrict__ O0, ushort* __restrict__ O1, ushort* __restrict__ O2,
                                                  int D, size_t inSlot){
  int d = blockIdx.x;
  int by = blockIdx.y;
  int b = by / 3, li = by % 3;          // li = GCN layer index
  int bd = b*D + d;
  const ushort* adjL = adjF + (size_t)li*13*7*512;
  constexpr int SST = 232;
  __shared__ __align__(16) ushort sB[64*SST];
  int tid = threadIdx.x;
  for(int i=tid*8; i<64*SST; i+=TPB*8){ uint4 z; z.x=0;z.y=0;z.z=0;z.w=0; *(uint4*)&sB[i]=z; }
  __syncthreads();
  const ushort* Sp = S + li*inSlot + (size_t)bd*NP;
  for(int i=tid; i<NP; i+=TPB){
    int nn = i/52, l = i - nn*52;
    sB[l*SST + nn] = Sp[i];
  }
  __syncthreads();
  int lane = tid & 63, w = tid >> 6;
  int r15 = lane & 15, hi = lane >> 4;
  float bb = bias[li*D + d];
  ushort* Ob = (li==0) ? O0 : (li==1 ? O1 : O2);
  ushort* Op = Ob + (size_t)bd*NP;
  for(int k2t = w; k2t < 13; k2t += 4){
    f32x4 acc[4];
    #pragma unroll
    for(int lt=0;lt<4;lt++){ acc[lt][0]=0;acc[lt][1]=0;acc[lt][2]=0;acc[lt][3]=0; }
    #pragma unroll
    for(int ks=0; ks<7; ks++){
      bf16x8 a = *(const bf16x8*)&adjL[((size_t)(k2t*7 + ks))*512 + lane*8];
      #pragma unroll
      for(int lt=0;lt<4;lt++){
        bf16x8 bfr = *(const bf16x8*)&sB[(lt*16+r15)*SST + ks*32 + hi*8];
        acc[lt] = __builtin_amdgcn_mfma_f32_16x16x32_bf16(a, bfr, acc[lt], 0,0,0);
      }
    }
    #pragma unroll
    for(int lt=0;lt<4;lt++){
      #pragma unroll
      for(int i2=0;i2<4;i2++){
        int k2 = k2t*16 + hi*4 + i2;
        int l  = lt*16 + r15;
        if(k2 < Nn && l < LP){
          float v = acc[lt][i2] + bb;
          if(RELU) v = fmaxf(v, 0.f);
          Op[(size_t)k2*LP + l] = f2bf(v);
        }
      }
    }
  }
}

// ---------------- fused MLP conv over all 3 layers; inputs RB0/1/2 bf16 [b][128][NP]; no GACC ----------------
__global__ __launch_bounds__(TPB) void k_mlp_all(const ushort* __restrict__ RB0, const ushort* __restrict__ RB1,
                                                 const ushort* __restrict__ RB2, const ushort* __restrict__ WF,
                                                 const float* __restrict__ bm, float* __restrict__ gg){
  int n = blockIdx.x, b = blockIdx.y;
  constexpr int CS = 136;
  __shared__ __align__(16) ushort sLT[3*52*CS];
  int tid = threadIdx.x;
  {
    const ushort* Rp = RB0;
    for(int i=tid;i<6656;i+=TPB){ int c=i/52, l=i%52; sLT[0*52*CS + l*CS + c] = Rp[(((size_t)b*128+c)*Nn + n)*LP + l]; }
    Rp = RB1;
    for(int i=tid;i<6656;i+=TPB){ int c=i/52, l=i%52; sLT[1*52*CS + l*CS + c] = Rp[(((size_t)b*128+c)*Nn + n)*LP + l]; }
    Rp = RB2;
    for(int i=tid;i<6656;i+=TPB){ int c=i/52, l=i%52; sLT[2*52*CS + l*CS + c] = Rp[(((size_t)b*128+c)*Nn + n)*LP + l]; }
  }
  __syncthreads();
  int lane = tid & 63, w = tid >> 6;
  int r15 = lane & 15, hi = lane >> 4;
  f32x4 acc0[3], acc1[3];
  #pragma unroll
  for(int tt=0;tt<3;tt++){
    acc0[tt][0]=0;acc0[tt][1]=0;acc0[tt][2]=0;acc0[tt][3]=0;
    acc1[tt][0]=0;acc1[tt][1]=0;acc1[tt][2]=0;acc1[tt][3]=0;
  }
  #pragma unroll
  for(int layer=0; layer<3; layer++){
    const ushort* wp0 = WF + ((size_t)(layer*8 + w)*12)*512 + lane*8;
    const ushort* wp1 = WF + ((size_t)(layer*8 + w+4)*12)*512 + lane*8;
    const ushort* sL = &sLT[layer*52*CS];
    #pragma unroll 3
    for(int ks=0; ks<12; ks++){
      int kt = ks>>2, ci0 = (ks&3)*32 + hi*8;
      bf16x8 bw0 = *(const bf16x8*)&wp0[(size_t)ks*512];
      bf16x8 bw1 = *(const bf16x8*)&wp1[(size_t)ks*512];
      #pragma unroll
      for(int tt=0;tt<3;tt++){
        bf16x8 ax = *(const bf16x8*)&sL[(tt*16 + r15 + kt)*CS + ci0];
        acc0[tt] = __builtin_amdgcn_mfma_f32_16x16x32_bf16(ax, bw0, acc0[tt], 0,0,0);
        acc1[tt] = __builtin_amdgcn_mfma_f32_16x16x32_bf16(ax, bw1, acc1[tt], 0,0,0);
      }
    }
  }
  int o = w*16 + r15;
  float b0 = bm[o], b1 = bm[o+64];
  float* ggp = gg + (((size_t)b*Cc + o)*Nn + n)*(size_t)Tout;
  #pragma unroll
  for(int tt=0;tt<3;tt++){
    #pragma unroll
    for(int i2=0;i2<4;i2++){
      int tq = tt*16 + hi*4 + i2;
      float a  = acc0[tt][i2] + b0;
      float g2 = acc1[tt][i2] + b1;
      ggp[tq] = tanhf(a)*sigm(g2);
    }
  }
}

// ---------------- patch scramble + emb ----------------
__global__ __launch_bounds__(TPB) void k_xe(const float* __restrict__ gg, const float* __restrict__ emb, float* __restrict__ xe){
  size_t i = (size_t)blockIdx.x*TPB + threadIdx.x;
  if(i >= (size_t)Bx*1271808) return;
  int b = (int)(i / 1271808);
  int off = (int)(i % 1271808);
  int c = off / 19872; int r = off % 19872;
  int n = r / 96; int r2 = r % 96;
  int p = r2 >> 3; int j = r2 & 7;
  int t = p*4 + j;
  float v = 0.f;
  if(t < Tout) v = gg[(((size_t)b*Cc+c)*Nn + n)*Tout + t];
  int e = off & 511; int p2 = (off >> 9) % 12;
  xe[i] = v + emb[(size_t)p2*Ee + e];
}

// ---------------- per-row LN helper (rows of 512, stride SRDF, in LDS); NW waves ----------------
template<int NW>
__device__ __forceinline__ void ln_rows(float* buf, const float* __restrict__ g, const float* __restrict__ be, int tid){
  int lane = tid & 63, wv = tid >> 6;
  for(int r = wv; r < 12; r += NW){
    float s=0.f, s2=0.f;
    #pragma unroll
    for(int j=0;j<8;j++){ float v = buf[r*SRDF + j*64 + lane]; s+=v; s2+=v*v; }
    #pragma unroll
    for(int off=32; off; off>>=1){ s += __shfl_xor(s,off); s2 += __shfl_xor(s2,off); }
    float m = s*(1.f/512.f);
    float rstd = rsqrtf(fmaxf(s2*(1.f/512.f)-m*m, 0.f)+EPSF);
    #pragma unroll
    for(int j=0;j<8;j++){ int e = j*64+lane; float v = buf[r*SRDF+e];
      buf[r*SRDF+e] = (v-m)*rstd*g[e] + be[e]; }
  }
}

// ---------------- fused per-(b,n) transformer, MFMA GEMM phases; 512 threads (8 waves) ----------------
__global__ __launch_bounds__(TPA,2) void k_attn(
    const float* __restrict__ xe, const float* __restrict__ resid,
    const ushort* __restrict__ WqF, const float* __restrict__ bq,
    const ushort* __restrict__ WkF, const float* __restrict__ bk,
    const ushort* __restrict__ WvF, const float* __restrict__ bv,
    const ushort* __restrict__ WfcF, const float* __restrict__ bfc,
    const float* __restrict__ g1, const float* __restrict__ b1n,
    const float* __restrict__ g2, const float* __restrict__ b2n,
    const ushort* __restrict__ Wff1F, const float* __restrict__ bff1,
    const ushort* __restrict__ Wff2F, const float* __restrict__ bff2,
    const float* __restrict__ Wrp, const float* __restrict__ brp,
    float* __restrict__ y)
{
  int n = blockIdx.x, b = blockIdx.y;
  __shared__ __align__(16) ushort SbX[16*512];
  __shared__ __align__(16) ushort Mb[16*256];
  __shared__ __align__(16) float U0[12*SRDF];
  __shared__ __align__(16) float U1[12*SRDF];
  __shared__ __align__(16) float sS[1160];
  int tid = threadIdx.x;
  int lane = tid & 63, w = tid >> 6;          // w in [0,8)
  int r15 = lane & 15, hi = lane >> 4;
  const float* __restrict__ xeg = xe + ((size_t)b*Nn + n)*6144;

  for(int i=tid;i<1024;i+=TPA){
    int r = i>>6, ch = i&63;
    ushort u[8];
    if(r<12){
      const float* s = &xeg[r*512 + ch*8];
      #pragma unroll
      for(int j=0;j<8;j++) u[j] = f2bf(s[j]);
    } else {
      #pragma unroll
      for(int j=0;j<8;j++) u[j] = 0;
    }
    *(uint4*)&SbX[r*512 + ((ch ^ (r&7))<<3)] = *(uint4*)u;
  }
  for(int i=tid;i<128;i+=TPA){
    int r = 12 + (i>>5), ch = i&31;
    uint4 z; z.x=0;z.y=0;z.z=0;z.w=0;
    *(uint4*)&Mb[r*256 + ch*8] = z;
  }
  __syncthreads();

  // QKV: one head per wave
  f32x4 vfrag[4];
  {
    int head = w;
    bf16x8 a0, a1;
    { int ch0 = head*8 + hi, ch1 = head*8 + 4 + hi;
      a0 = *(const bf16x8*)&SbX[r15*512 + ((ch0 ^ (r15&7))<<3)];
      a1 = *(const bf16x8*)&SbX[r15*512 + ((ch1 ^ (r15&7))<<3)]; }
    #pragma unroll
    for(int nt=0;nt<4;nt++){
      int col = nt*16 + r15;
      float bb = bq[col];
      f32x4 acc; acc[0]=bb;acc[1]=bb;acc[2]=bb;acc[3]=bb;
      acc = __builtin_amdgcn_mfma_f32_16x16x32_bf16(a0, *(const bf16x8*)&WqF[(size_t)(nt*2+0)*512 + lane*8], acc, 0,0,0);
      acc = __builtin_amdgcn_mfma_f32_16x16x32_bf16(a1, *(const bf16x8*)&WqF[(size_t)(nt*2+1)*512 + lane*8], acc, 0,0,0);
      #pragma unroll
      for(int i2=0;i2<4;i2++){ int p = hi*4+i2; if(p<12) U0[p*SRDF + head*64 + col] = acc[i2]; }
    }
    #pragma unroll
    for(int nt=0;nt<4;nt++){
      int col = nt*16 + r15;
      float bb = bk[col];
      f32x4 acc; acc[0]=bb;acc[1]=bb;acc[2]=bb;acc[3]=bb;
      acc = __builtin_amdgcn_mfma_f32_16x16x32_bf16(a0, *(const bf16x8*)&WkF[(size_t)(nt*2+0)*512 + lane*8], acc, 0,0,0);
      acc = __builtin_amdgcn_mfma_f32_16x16x32_bf16(a1, *(const bf16x8*)&WkF[(size_t)(nt*2+1)*512 + lane*8], acc, 0,0,0);
      #pragma unroll
      for(int i2=0;i2<4;i2++){ int p = hi*4+i2; if(p<12) U1[p*SRDF + head*64 + col] = acc[i2]; }
    }
    #pragma unroll
    for(int nt=0;nt<4;nt++){
      int col = nt*16 + r15;
      float bb = bv[col];
      f32x4 acc; acc[0]=bb;acc[1]=bb;acc[2]=bb;acc[3]=bb;
      acc = __builtin_amdgcn_mfma_f32_16x16x32_bf16(a0, *(const bf16x8*)&WvF[(size_t)(nt*2+0)*512 + lane*8], acc, 0,0,0);
      acc = __builtin_amdgcn_mfma_f32_16x16x32_bf16(a1, *(const bf16x8*)&WvF[(size_t)(nt*2+1)*512 + lane*8], acc, 0,0,0);
      vfrag[nt] = acc;
    }
  }
  __syncthreads();

  const float scale = 0.04419417382415922f;   // 1/sqrt(512)
  for(int i=tid;i<1152;i+=TPA){
    int q = i%12, kh = i/12; int h2 = kh&7, k2 = kh>>3;
    const float* qp = &U0[q*SRDF + h2*64];
    const float* kp = &U1[k2*SRDF + h2*64];
    float s=0.f;
    #pragma unroll
    for(int d4=0; d4<16; d4++){
      float4 a4 = *(const float4*)&qp[d4*4];
      float4 b4 = *(const float4*)&kp[d4*4];
      s += a4.x*b4.x + a4.y*b4.y + a4.z*b4.z + a4.w*b4.w;
    }
    sS[i] = s*scale;
  }
  __syncthreads();
  {
    int head = w;
    #pragma unroll
    for(int nt=0;nt<4;nt++){
      int col = nt*16 + r15;
      #pragma unroll
      for(int i2=0;i2<4;i2++){ int p = hi*4+i2; if(p<12) U0[p*SRDF + head*64 + col] = vfrag[nt][i2]; }
    }
  }
  if(tid<96){
    float mx=-1e30f;
    for(int q=0;q<12;q++) mx = fmaxf(mx, sS[tid*12+q]);
    float sm=0.f;
    for(int q=0;q<12;q++){ float e = __expf(sS[tid*12+q]-mx); sS[tid*12+q]=e; sm+=e; }
    float inv = 1.f/sm;
    for(int q=0;q<12;q++) sS[tid*12+q] *= inv;
  }
  __syncthreads();

  for(int i=tid;i<6144;i+=TPA){
    int q=i>>9, h2=(i>>6)&7, d=i&63;
    float s=0.f;
    #pragma unroll
    for(int k2=0;k2<12;k2++) s += sS[(k2*8+h2)*12+q]*U0[k2*SRDF+h2*64+d];
    int kk = i & 511;
    SbX[q*512 + (((kk>>3) ^ (q&7))<<3) + (kk&7)] = f2bf(s);
  }
  __syncthreads();

  // fc: 32 col-tiles, 4 per wave
  {
    f32x4 acc[4];
    #pragma unroll
    for(int nt=0;nt<4;nt++){ float bb = bfc[(w*4+nt)*16 + r15]; acc[nt][0]=bb;acc[nt][1]=bb;acc[nt][2]=bb;acc[nt][3]=bb; }
    for(int ks=0;ks<16;ks++){
      int ch = ks*4 + hi;
      bf16x8 a = *(const bf16x8*)&SbX[r15*512 + ((ch ^ (r15&7))<<3)];
      #pragma unroll
      for(int nt=0;nt<4;nt++){
        acc[nt] = __builtin_amdgcn_mfma_f32_16x16x32_bf16(a, *(const bf16x8*)&WfcF[(size_t)((w*4+nt)*16 + ks)*512 + lane*8], acc[nt], 0,0,0);
      }
    }
    #pragma unroll
    for(int nt=0;nt<4;nt++){
      int col = (w*4+nt)*16 + r15;
      #pragma unroll
      for(int i2=0;i2<4;i2++){ int p = hi*4+i2; if(p<12) U1[p*SRDF + col] = acc[nt][i2] + xeg[p*512 + col]; }
    }
  }
  __syncthreads();
  ln_rows<8>(U1, g1, b1n, tid);     // M in U1
  __syncthreads();

  for(int i=tid;i<6144;i+=TPA){
    int r=i>>9, kk=i&511;
    SbX[r*512 + (((kk>>3) ^ (r&7))<<3) + (kk&7)] = f2bf(U1[r*SRDF + kk]);
  }
  __syncthreads();

  // ff1: 16 col-tiles, 2 per wave
  {
    f32x4 acc[2];
    #pragma unroll
    for(int nt=0;nt<2;nt++){ float bb = bff1[(w*2+nt)*16 + r15]; acc[nt][0]=bb;acc[nt][1]=bb;acc[nt][2]=bb;acc[nt][3]=bb; }
    for(int ks=0;ks<16;ks++){
      int ch = ks*4 + hi;
      bf16x8 a = *(const bf16x8*)&SbX[r15*512 + ((ch ^ (r15&7))<<3)];
      #pragma unroll
      for(int nt=0;nt<2;nt++){
        acc[nt] = __builtin_amdgcn_mfma_f32_16x16x32_bf16(a, *(const bf16x8*)&Wff1F[(size_t)((w*2+nt)*16 + ks)*512 + lane*8], acc[nt], 0,0,0);
      }
    }
    #pragma unroll
    for(int nt=0;nt<2;nt++){
      int u = (w*2+nt)*16 + r15;
      #pragma unroll
      for(int i2=0;i2<4;i2++){
        int p = hi*4+i2;
        if(p<12) Mb[p*256 + (((u>>3) ^ (p&7))<<3) + (u&7)] = f2bf(fmaxf(acc[nt][i2], 0.f));
      }
    }
  }
  __syncthreads();

  // ff2: 32 col-tiles, 4 per wave
  {
    f32x4 acc[4];
    #pragma unroll
    for(int nt=0;nt<4;nt++){ float bb = bff2[(w*4+nt)*16 + r15]; acc[nt][0]=bb;acc[nt][1]=bb;acc[nt][2]=bb;acc[nt][3]=bb; }
    for(int ks=0;ks<8;ks++){
      int ch = ks*4 + hi;
      bf16x8 a = *(const bf16x8*)&Mb[r15*256 + ((ch ^ (r15&7))<<3)];
      #pragma unroll
      for(int nt=0;nt<4;nt++){
        acc[nt] = __builtin_amdgcn_mfma_f32_16x16x32_bf16(a, *(const bf16x8*)&Wff2F[(size_t)((w*4+nt)*8 + ks)*512 + lane*8], acc[nt], 0,0,0);
      }
    }
    #pragma unroll
    for(int nt=0;nt<4;nt++){
      int col = (w*4+nt)*16 + r15;
      #pragma unroll
      for(int i2=0;i2<4;i2++){ int p = hi*4+i2; if(p<12) U0[p*SRDF + col] = acc[nt][i2] + U1[p*SRDF + col]; }
    }
  }
  __syncthreads();
  ln_rows<8>(U0, g2, b2n, tid);     // U in U0
  __syncthreads();

  for(int i=tid;i<6144;i+=TPA){
    int r=i>>9, c=i&511;
    U1[r*SRDF+c] = U0[r*SRDF+c] + U1[r*SRDF+c] + xeg[r*512+c];
  }
  __syncthreads();
  for(int i=tid;i<4608;i+=TPA) U0[i] = Wrp[i];
  __syncthreads();
  #pragma unroll
  for(int j=0;j<2;j++){
    int i4 = tid + j*TPA;
    if(i4 < 768){
      int c = i4/12, tq = i4%12; int t0 = tq*4;
      float4 acc = *(const float4*)&brp[t0];
      for(int t96=0;t96<96;t96++){
        int f = c*96 + t96;
        float a = U1[(f>>9)*SRDF + (f&511)];
        float4 w4 = *(const float4*)&U0[t96*48 + t0];
        FMA4(acc, a, w4);
      }
      size_t rb = (((size_t)b*Cc+c)*Nn + n)*Tin + 6 + t0;
      acc.x += resid[rb+0]; acc.y += resid[rb+1]; acc.z += resid[rb+2]; acc.w += resid[rb+3];
      *(float4*)&y[(((size_t)b*Cc+c)*Nn + n)*Tout + t0] = acc;
    }
  }
}

// ---------------- batchnorm ----------------
__global__ __launch_bounds__(TPB) void k_bnstats(const float* __restrict__ y, float* __restrict__ stats){
  int c = blockIdx.x; int tid = threadIdx.x;
  float s=0.f,s2=0.f;
  const int per = Nn*Tout;   // 9936
  for(int idx=tid; idx<Bx*per; idx+=TPB){
    int b = idx/per, r = idx%per;
    float v = y[((size_t)b*Cc+c)*per + r];
    s+=v; s2+=v*v;
  }
  __shared__ float rs[TPB], rs2[TPB];
  rs[tid]=s; rs2[tid]=s2; __syncthreads();
  for(int off=TPB/2; off; off>>=1){ if(tid<off){ rs[tid]+=rs[tid+off]; rs2[tid]+=rs2[tid+off]; } __syncthreads(); }
  if(tid==0){
    float m = rs[0]/(float)(Bx*per);
    float var = rs2[0]/(float)(Bx*per) - m*m;
    stats[c]=m; stats[64+c]=rsqrtf(fmaxf(var,0.f)+EPSF);
  }
}
__global__ __launch_bounds__(TPB) void k_bnout(const float* __restrict__ y, const float* __restrict__ stats,
                                               const float* __restrict__ gbn, const float* __restrict__ bbn,
                                               float* __restrict__ out){
  size_t i = (size_t)blockIdx.x*TPB + threadIdx.x;
  if(i >= (size_t)Bx*Cc*Nn*Tout) return;
  int c = (int)((i/(Nn*Tout))%Cc);
  out[i] = (y[i]-stats[c])*stats[64+c]*gbn[c] + bbn[c];
}

// ---------------- launch ----------------
extern "C" void kernel_launch(void* const* d_in, const int* in_sizes, int n_in,
                              void* d_out, int out_size, void* d_ws, size_t ws_size,
                              hipStream_t stream) {
  const float* x      = (const float*)d_in[0];
  const float* adj    = (const float*)d_in[1];
  const float* Wconv1 = (const float*)d_in[2];
  const float* bconv1 = (const float*)d_in[3];
  const float* gT     = (const float*)d_in[4];
  const float* bT     = (const float*)d_in[5];
  const float* gS     = (const float*)d_in[6];
  const float* bS     = (const float*)d_in[7];
  const float* Wtime  = (const float*)d_in[8];
  const float* btime  = (const float*)d_in[9];
  const float* wq1    = (const float*)d_in[10];
  const float* wv1    = (const float*)d_in[11];
  const float* bias1  = (const float*)d_in[12];
  const float* wq2    = (const float*)d_in[13];
  const float* wv2    = (const float*)d_in[14];
  const float* bias2  = (const float*)d_in[15];
  const float* Wmlp   = (const float*)d_in[16];
  const float* bmlp   = (const float*)d_in[17];
  const float* embT   = (const float*)d_in[18];
  const float* Wq     = (const float*)d_in[19];
  const float* bq     = (const float*)d_in[20];
  const float* Wk     = (const float*)d_in[21];
  const float* bk     = (const float*)d_in[22];
  const float* Wv     = (const float*)d_in[23];
  const float* bv     = (const float*)d_in[24];
  const float* Wfc    = (const float*)d_in[25];
  const float* bfc    = (const float*)d_in[26];
  const float* g1     = (const float*)d_in[27];
  const float* b1n    = (const float*)d_in[28];
  const float* g2     = (const float*)d_in[29];
  const float* b2n    = (const float*)d_in[30];
  const float* Wff1   = (const float*)d_in[31];
  const float* bff1   = (const float*)d_in[32];
  const float* Wff2   = (const float*)d_in[33];
  const float* bff2   = (const float*)d_in[34];
  const float* Wrp    = (const float*)d_in[35];
  const float* brp    = (const float*)d_in[36];
  const float* gbn    = (const float*)d_in[37];
  const float* bbn    = (const float*)d_in[38];

  float* ws = (float*)d_ws;
  float* RESID = ws + O_RESID;
  float* LNTM  = ws + O_LNTM;
  float* LNTR  = ws + O_LNTR;
  float* LNSM  = ws + O_LNSM;
  float* LNSR  = ws + O_LNSR;
  const size_t RSLOT  = (size_t)Bx*128*NP;   // ushorts per RA/RB slot
  const size_t S1SLOT = (size_t)Bx*64*NP;    // ushorts per S1 slot
  ushort* RAx  = (ushort*)(ws + O_XCAT);     // 3 slots (16.53M of 17.17M floats)
  ushort* RB0  = (ushort*)(ws + O_RB);
  ushort* RB1  = RB0 + RSLOT;                // fills O_RB region exactly
  ushort* RB2  = (ushort*)(ws + O_XE);       // dead-XE region; k_xe overwrites after mlp_all
  ushort* S1x  = (ushort*)(ws + O_GACC);     // 3 slots (8.27M of 10.17M floats)
  float* GG    = ws + O_GG;
  float* Y     = ws + O_GG;      // overlays GG (safe: GG dead after k_xe builds XE)
  float* XE    = ws + O_XE;
  float* BNST  = ws + O_BNST;
  ushort* WTMF = (ushort*)(ws + O_WTM);
  ushort* WTB  = (ushort*)(ws + O_WTB);
  ushort* ADJT = (ushort*)(ws + O_ADJT);
  ushort* HT   = (ushort*)(ws + O_HT);   // in dead H region
  ushort* WQ1B = (ushort*)(ws + O_WQ1B);
  ushort* WV1B = (ushort*)(ws + O_WV1B);
  ushort* WQ2B = (ushort*)(ws + O_WQ2B);
  ushort* WV2B = (ushort*)(ws + O_WV2B);
  ushort* WQT  = (ushort*)(ws + O_WQT);
  ushort* WKT  = (ushort*)(ws + O_WKT);
  ushort* WVT  = (ushort*)(ws + O_WVT);
  ushort* WFCT = (ushort*)(ws + O_WFCT);
  ushort* WF1T = (ushort*)(ws + O_WF1T);
  ushort* WF2T = (ushort*)(ws + O_WF2T);

  k_residual<<<dim3(Nn,Bx),TPB,0,stream>>>(x, Wconv1, bconv1, RESID, LNTM, LNTR);
  k_lnS<<<(Bx*Cc*Tin)/TPB,TPB,0,stream>>>(RESID, LNSM, LNSR);
  k_wtbF<<<(8*18*512+TPB-1)/TPB,TPB,0,stream>>>(Wtime, WTB);
  k_wmlpF<<<(3*8*12*512+TPB-1)/TPB,TPB,0,stream>>>(Wmlp, WTMF);
  k_htpad<<<(Bx*(NPa-NP)*8+TPB-1)/TPB,TPB,0,stream>>>(HT);
  // fused xcat + timeconv (reads RESID + LN stats directly)
  k_timeconv_mfma<<<dim3(Nn,Bx),TPB,0,stream>>>(RESID, LNTM, LNTR, LNSM, LNSR, gT, bT, gS, bS,
                                                WTB, btime, HT);

  // merged fragment-order weight converts (11 jobs, one dispatch)
  WJobs jobs;
  jobs.j[0]  = { wq1,  WQ1B, 64,  64,  2,  4,  64*64,   24*4*2*512 };
  jobs.j[1]  = { wv1,  WV1B, 64,  64,  2,  4,  64*64,   24*4*2*512 };
  jobs.j[2]  = { wq2,  WQ2B, 64,  128, 2,  8,  64*128,  24*8*2*512 };
  jobs.j[3]  = { wv2,  WV2B, 64,  128, 2,  8,  64*128,  24*8*2*512 };
  jobs.j[4]  = { Wq,   WQT,  64,  64,  2,  4,  64*64,   4*2*512 };
  jobs.j[5]  = { Wk,   WKT,  64,  64,  2,  4,  64*64,   4*2*512 };
  jobs.j[6]  = { Wv,   WVT,  64,  64,  2,  4,  64*64,   4*2*512 };
  jobs.j[7]  = { Wfc,  WFCT, 512, 512, 16, 32, 512*512, 32*16*512 };
  jobs.j[8]  = { Wff1, WF1T, 512, 256, 16, 16, 512*256, 16*16*512 };
  jobs.j[9]  = { Wff2, WF2T, 256, 512, 8,  32, 256*512, 32*8*512 };
  jobs.j[10] = { adj,  ADJT, 207, 207, 7,  13, Nn*Nn,   3*13*7*512 };
  int totalW = 2*(24*4*2*512) + 2*(24*8*2*512) + 3*(4*2*512) + 32*16*512 + 16*16*512 + 32*8*512 + 3*13*7*512;
  k_wfrag_all<<<(totalW+TPB-1)/TPB,TPB,0,stream>>>(jobs);

  // GCN chain: 3 independent layers batched into 4 wide dispatches
  k_gcs_mfma<64,0><<<dim3(169,3,Bx),TPB,0,stream>>>(HT, WQ1B, WV1B, RAx, 0, RSLOT);
  k_agg_mfma<1><<<dim3(64,Bx*3),TPB,0,stream>>>(RAx, ADJT, bias1, S1x, S1x+S1SLOT, S1x+2*S1SLOT, 64, RSLOT);
  k_gcs_mfma<128,1><<<dim3(169,6,Bx),TPB,0,stream>>>(S1x, WQ2B, WV2B, RAx, S1SLOT, RSLOT);
  k_agg_mfma<0><<<dim3(128,Bx*3),TPB,0,stream>>>(RAx, ADJT, bias2, RB0, RB1, RB2, 128, RSLOT);
  k_mlp_all<<<dim3(Nn,Bx),TPB,0,stream>>>(RB0, RB1, RB2, WTMF, bmlp, GG);
  k_xe<<<(Bx*1271808)/TPB,TPB,0,stream>>>(GG, embT, XE);
  k_attn<<<dim3(Nn,Bx),TPA,0,stream>>>(XE, RESID, WQT,bq, WKT,bk, WVT,bv, WFCT,bfc,
                                       g1,b1n,g2,b2n, WF1T,bff1, WF2T,bff2, Wrp,brp, Y);
  k_bnstats<<<64,TPB,0,stream>>>(Y, BNST);
  k_bnout<<<(Bx*Cc*Nn*Tout)/TPB,TPB,0,stream>>>(Y, BNST, gbn, bbn, (float*)d_out);
}